// Round 7
// baseline (332.660 us; speedup 1.0000x reference)
//
#include <hip/hip_runtime.h>
#include <hip/hip_bf16.h>
#include <cstdint>
#include <cstddef>

#define DEVINL __device__ __forceinline__

typedef __attribute__((ext_vector_type(8))) short bf16x8;
typedef __attribute__((ext_vector_type(4))) float f32x4;

// ---------- helpers ----------
DEVINL float bf2f(unsigned short u){
  union { unsigned u32; float f; } cv; cv.u32 = ((unsigned)u) << 16; return cv.f;
}
DEVINL unsigned short f2bf(float f){
  union { float f; unsigned u32; } cv; cv.f = f;
  unsigned u = cv.u32;
  return (unsigned short)((u + 0x7FFFu + ((u >> 16) & 1u)) >> 16);  // RNE
}
DEVINL float softplusf(float x){ return x > 20.f ? x : log1pf(expf(x)); }

DEVINL void g2l16(const void* gptr, void* ldsptr){
  __builtin_amdgcn_global_load_lds(
      (const __attribute__((address_space(1))) unsigned int*)gptr,
      (__attribute__((address_space(3))) unsigned int*)(uintptr_t)ldsptr,
      16, 0, 0);
}

// swizzled LDS access for 256-byte-row tiles (128 bf16 cols)
DEVINL int swzb(int row, int col){ return row*256 + ((col*2) ^ ((row&7)<<4)); }
DEVINL void ldsw_write8(unsigned short* b, int row, int col, bf16x8 v){
  *(bf16x8*)((char*)b + swzb(row,col)) = v;
}
DEVINL bf16x8 ldsw_read8(const unsigned short* b, int row, int col){
  return *(const bf16x8*)((const char*)b + swzb(row,col));
}
DEVINL void ldsw_write1(unsigned short* b, int row, int col, unsigned short v){
  *(unsigned short*)((char*)b + swzb(row,col)) = v;
}
DEVINL unsigned short ldsw_read1(const unsigned short* b, int row, int col){
  return *(const unsigned short*)((const char*)b + swzb(row,col));
}

// ---------- fused f32 -> bf16 conversion of two buffers ----------
__global__ __launch_bounds__(256) void k_conv2(
    const float* __restrict__ a, unsigned short* __restrict__ oa, long na, int nba,
    const float* __restrict__ b, unsigned short* __restrict__ ob, long nb)
{
  const float* in; unsigned short* out; long n; long blk;
  if ((int)blockIdx.x < nba){ in = a; out = oa; n = na; blk = blockIdx.x; }
  else                      { in = b; out = ob; n = nb; blk = blockIdx.x - nba; }
  long i = (blk * 256 + threadIdx.x) * 4;
  if (i + 3 < n){
    float4 v = *(const float4*)(in + i);
    unsigned long long pk =
        (unsigned long long)f2bf(v.x)
      | ((unsigned long long)f2bf(v.y) << 16)
      | ((unsigned long long)f2bf(v.z) << 32)
      | ((unsigned long long)f2bf(v.w) << 48);
    *(unsigned long long*)(out + i) = pk;
  }
}

// ---------- single f32 -> bf16 conversion ----------
__global__ __launch_bounds__(256) void k_f32_to_bf16(
    const float* __restrict__ in, unsigned short* __restrict__ out, long n)
{
  long i = ((long)blockIdx.x * 256 + threadIdx.x) * 4;
  if (i + 3 < n){
    float4 v = *(const float4*)(in + i);
    unsigned long long pk =
        (unsigned long long)f2bf(v.x)
      | ((unsigned long long)f2bf(v.y) << 16)
      | ((unsigned long long)f2bf(v.z) << 32)
      | ((unsigned long long)f2bf(v.w) << 48);
    *(unsigned long long*)(out + i) = pk;
  }
}

// ---------- bf16 GEMM, both operands K-major, C = A * Bt^T ----------
// 128x128 tile, BK=64, swizzled LDS (slot ^= row&7), 2D XCD-local tile partition.
template<bool OUT_BF16>
__global__ __launch_bounds__(256) void k_gemm_bt(
    const unsigned short* __restrict__ A,
    const unsigned short* __restrict__ Bt,
    void* __restrict__ Cout,
    int K, int Nrows, int Npad, int xm, int tmx, int tnx)
{
  __shared__ unsigned short Asub[128*64];
  __shared__ unsigned short Bsub[128*64];
  const int tid = threadIdx.x;
  // bijective 2D XCD partition: requires gridDim.x == 8*tmx*tnx
  const int x = blockIdx.x & 7, i = blockIdx.x >> 3;
  const int rt = (x % xm) * tmx + (i % tmx);
  const int ct = (x / xm) * tnx + (i / tmx);
  const int lane = tid & 63, wave = tid >> 6;
  const int wr = wave >> 1, wc = wave & 1;
  const int fr = lane & 15;
  const int fq = lane >> 4;

  const int srow0 = tid >> 3;
  const int sgrp  = (tid & 7) ^ ((tid >> 3) & 7);
  size_t aoff[4], boff[4];
  #pragma unroll
  for (int j = 0; j < 4; j++){
    int row = j*32 + srow0;
    aoff[j] = (size_t)(rt*128 + row) * K + sgrp*8;
    int brow = ct*128 + row; if (brow > Nrows-1) brow = Nrows-1;
    boff[j] = (size_t)brow * K + sgrp*8;
  }

  f32x4 acc[4][4] = {};

  for (int k0 = 0; k0 < K; k0 += 64){
    #pragma unroll
    for (int j = 0; j < 4; j++){
      g2l16(A  + aoff[j] + k0, (char*)Asub + (j*256 + tid)*16);
      g2l16(Bt + boff[j] + k0, (char*)Bsub + (j*256 + tid)*16);
    }
    asm volatile("s_waitcnt vmcnt(0)" ::: "memory");
    __syncthreads();

    #pragma unroll
    for (int kk = 0; kk < 2; kk++){
      bf16x8 af[4], bfr[4];
      const int slot = (kk*4 + fq) ^ (fr & 7);
      #pragma unroll
      for (int j = 0; j < 4; j++){
        int ra = wr*64 + j*16 + fr;
        int rb = wc*64 + j*16 + fr;
        af[j]  = *(const bf16x8*)((const char*)Asub + ra*128 + slot*16);
        bfr[j] = *(const bf16x8*)((const char*)Bsub + rb*128 + slot*16);
      }
      #pragma unroll
      for (int mi = 0; mi < 4; mi++)
        #pragma unroll
        for (int ni = 0; ni < 4; ni++)
          acc[mi][ni] = __builtin_amdgcn_mfma_f32_16x16x32_bf16(af[mi], bfr[ni], acc[mi][ni], 0, 0, 0);
    }
    __syncthreads();
  }

  const int er = (lane >> 4) * 4;
  const int ec = lane & 15;
  #pragma unroll
  for (int mi = 0; mi < 4; mi++){
    #pragma unroll
    for (int ni = 0; ni < 4; ni++){
      const int row = rt*128 + wr*64 + mi*16 + er;
      const int col = ct*128 + wc*64 + ni*16 + ec;
      #pragma unroll
      for (int r = 0; r < 4; r++){
        if (OUT_BF16)
          ((unsigned short*)Cout)[(size_t)(row+r)*Npad + col] = f2bf(acc[mi][ni][r]);
        else
          ((float*)Cout)[(size_t)(row+r)*Npad + col] = acc[mi][ni][r];
      }
    }
  }
}

// ---------- fused: rmsnorm of Braw/Craw (N=128) -> bf16  +  per-(b,l,h) scalars ----------
__global__ __launch_bounds__(128) void k_rmsprep(
    const unsigned short* __restrict__ proj, const float* __restrict__ Bw,
    const float* __restrict__ Cw, const float* __restrict__ dt_bias,
    unsigned short* __restrict__ Bb2, unsigned short* __restrict__ Cb2,
    float* __restrict__ DTt, float* __restrict__ logdec, float* __restrict__ lamt)
{
  int row = blockIdx.x, n = threadIdx.x;
  size_t base = (size_t)row * 8704;
  float bv = bf2f(proj[base + 8192 + n]);
  float cv = bf2f(proj[base + 8320 + n]);
  float sb = bv*bv, sc = cv*cv;
  #pragma unroll
  for (int m = 1; m < 64; m <<= 1){ sb += __shfl_xor(sb, m, 64); sc += __shfl_xor(sc, m, 64); }
  __shared__ float red[4];
  if ((n & 63) == 0){ red[(n>>6)*2] = sb; red[(n>>6)*2+1] = sc; }
  __syncthreads();
  sb = red[0] + red[2];
  sc = red[1] + red[3];
  float rb = rsqrtf(sb*(1.f/128.f) + 1e-5f);
  float rc = rsqrtf(sc*(1.f/128.f) + 1e-5f);
  Bb2[row*128 + n] = f2bf(bv*rb*Bw[n]);
  Cb2[row*128 + n] = f2bf(cv*rc*Cw[n]);
  if (n < 64){
    int h = n, b = row >> 10, l = row & 1023;
    float dd_dt = bf2f(proj[base + 8448 + h]);
    float dd_A  = bf2f(proj[base + 8512 + h]);
    float trap  = bf2f(proj[base + 8576 + h]);
    float DT = softplusf(dd_dt + dt_bias[h]);
    float A  = -fmaxf(softplusf(dd_A), 1e-4f);
    size_t o = ((size_t)(b*64 + h))*1024 + l;
    DTt[o]    = DT;
    logdec[o] = A * DT;
    lamt[o]   = 1.f / (1.f + expf(-trap));
  }
}

// ---------- fused: per-chunk cumsum of logdec + g  THEN  phase cumsum + cos/sin ----------
__global__ __launch_bounds__(256) void k_phase(
    const unsigned short* __restrict__ proj, const float* __restrict__ DTt,
    const float* __restrict__ logdec, const float* __restrict__ lamt,
    float* __restrict__ clcb, float* __restrict__ gb,
    unsigned short* __restrict__ cosb, unsigned short* __restrict__ sinb)
{
  int bh = blockIdx.x, b = bh >> 6, h = bh & 63;
  int tid = threadIdx.x;
  size_t sbase = (size_t)bh * 1024;
  {
    int e0 = tid * 4;
    float v0 = logdec[sbase+e0], v1 = logdec[sbase+e0+1],
          v2 = logdec[sbase+e0+2], v3 = logdec[sbase+e0+3];
    float p0 = v0, p1 = p0+v1, p2 = p1+v2, p3 = p2+v3;
    float tot = p3;
    int sub = tid & 31;
    float incl = tot;
    #pragma unroll
    for (int off = 1; off < 32; off <<= 1){
      float u = __shfl_up(incl, off, 32);
      if (sub >= off) incl += u;
    }
    float excl = incl - tot;
    clcb[sbase+e0]   = excl + p0;
    clcb[sbase+e0+1] = excl + p1;
    clcb[sbase+e0+2] = excl + p2;
    clcb[sbase+e0+3] = excl + p3;
    #pragma unroll
    for (int q = 0; q < 4; q++){
      int l = e0 + q;
      int ln = (l == 1023) ? 1023 : l + 1;
      gb[sbase+l] = 1.f - lamt[sbase+l] + lamt[sbase+ln];
    }
  }
  int na = tid & 31, c = tid >> 5;
  __shared__ float part[8][32];
  const float* dtr = DTt + sbase;
  float s = 0.f;
  for (int q = 0; q < 128; q++){
    int l = c*128 + q; int row = b*1024 + l;
    float ang = bf2f(proj[(size_t)row*8704 + 8640 + na]);
    s = fmaf(ang, dtr[l], s);
  }
  part[c][na] = s;
  __syncthreads();
  float off = 0.f;
  for (int cc = 0; cc < c; cc++) off += part[cc][na];
  float ph = off;
  for (int q = 0; q < 128; q++){
    int l = c*128 + q; int row = b*1024 + l;
    float ang = bf2f(proj[(size_t)row*8704 + 8640 + na]);
    ph = fmaf(ang, dtr[l], ph);
    float sn, cs;
    __sincosf(ph, &sn, &cs);
    size_t o = ((size_t)row*64 + h)*32 + na;
    cosb[o] = f2bf(cs); sinb[o] = f2bf(sn);
  }
}

// ---------- pass A: intra-chunk y + chunk state increment G (512 threads, 8 waves) ----------
// wave w: MFMA1 (scores 128x128): rows wr=w>>2 (64), cols wc=w&3 (32)
//         MFMA2 (y 128x64):      rows wr (64),      cols wc (16)
//         MFMA4 (G 64x128):      rows w>>2 (32),    cols w&3 (32)
__global__ __launch_bounds__(512, 1) void k_intra(
    const unsigned short* __restrict__ proj,
    const unsigned short* __restrict__ Bb2, const unsigned short* __restrict__ Cb2,
    const float* __restrict__ Bbias, const float* __restrict__ Cbias,
    const unsigned short* __restrict__ cosb, const unsigned short* __restrict__ sinb,
    const float* __restrict__ DTt, const float* __restrict__ clcb,
    const float* __restrict__ gb, const float* __restrict__ lamt,
    const float* __restrict__ Dv, unsigned short* __restrict__ ybf,
    unsigned short* __restrict__ Gbuf)
{
  const int c = blockIdx.x & 7, bh = blockIdx.x >> 3;
  const int b = bh >> 6, h = bh & 63;
  const int tid = threadIdx.x, lane = tid & 63, wave = tid >> 6;
  const int wr = wave >> 2, wc = wave & 3;
  const int fr = lane & 15, fq = lane >> 4;

  __shared__ __align__(16) unsigned short Cs[128*128];
  __shared__ __align__(16) unsigned short Bs[128*128];   // aliased as P after barrier
  __shared__ __align__(16) unsigned short BTs[128*128];
  __shared__ __align__(16) unsigned short Uts[64*128];   // U^T: [p][j]
  __shared__ float clcs[128], lams[128], gs[128], wUs[128], dts[128];
  __shared__ float biasB[128], biasC[128];

  const int base = b*1024 + c*128;
  const size_t shbase = (size_t)bh * 1024;
  const float Dh = Dv[h];

  // phase 0: scalars
  if (tid < 128){
    int l = c*128 + tid;
    clcs[tid] = clcb[shbase + l];
    dts[tid]  = DTt[shbase + l];
    lams[tid] = lamt[shbase + l];
    gs[tid]   = gb[shbase + l];
    biasB[tid] = Bbias[h*128 + tid];
  } else if (tid < 256){
    biasC[tid-128] = Cbias[h*128 + tid-128];
  }
  __syncthreads();
  if (tid < 128) wUs[tid] = __expf(clcs[127] - clcs[tid]) * gs[tid];

  // phase 1: stage C/B (bias+rope), B^T, U^T  — quarters per row t
  {
    const int t = tid >> 2, q = tid & 3;
    const int grow = base + t;
    const size_t roff = (size_t)grow*128;
    if (q == 0){
      bf16x8 cc[4], sv[4];
      #pragma unroll
      for (int j = 0; j < 4; j++){
        cc[j] = *(const bf16x8*)(cosb + ((size_t)grow*64 + h)*32 + j*8);
        sv[j] = *(const bf16x8*)(sinb + ((size_t)grow*64 + h)*32 + j*8);
      }
      #pragma unroll
      for (int j = 0; j < 4; j++){
        bf16x8 vlo = *(const bf16x8*)(Cb2 + roff + j*8);
        bf16x8 vhi = *(const bf16x8*)(Cb2 + roff + 32 + j*8);
        bf16x8 olo, ohi;
        #pragma unroll
        for (int e = 0; e < 8; e++){
          float a = bf2f((unsigned short)vlo[e]) + biasC[j*8+e];
          float d = bf2f((unsigned short)vhi[e]) + biasC[32+j*8+e];
          float cf = bf2f((unsigned short)cc[j][e]);
          float sf = bf2f((unsigned short)sv[j][e]);
          olo[e] = (short)f2bf(a*cf - d*sf);
          ohi[e] = (short)f2bf(a*sf + d*cf);
        }
        ldsw_write8(Cs, t, j*8, olo);
        ldsw_write8(Cs, t, 32 + j*8, ohi);
      }
    } else if (q == 1){
      #pragma unroll
      for (int j = 0; j < 8; j++){
        bf16x8 v = *(const bf16x8*)(Cb2 + roff + 64 + j*8);
        bf16x8 o;
        #pragma unroll
        for (int e = 0; e < 8; e++) o[e] = (short)f2bf(bf2f((unsigned short)v[e]) + biasC[64+j*8+e]);
        ldsw_write8(Cs, t, 64 + j*8, o);
      }
    } else if (q == 2){
      bf16x8 cc[4], sv[4];
      #pragma unroll
      for (int j = 0; j < 4; j++){
        cc[j] = *(const bf16x8*)(cosb + ((size_t)grow*64 + h)*32 + j*8);
        sv[j] = *(const bf16x8*)(sinb + ((size_t)grow*64 + h)*32 + j*8);
      }
      #pragma unroll
      for (int j = 0; j < 4; j++){
        bf16x8 vlo = *(const bf16x8*)(Bb2 + roff + j*8);
        bf16x8 vhi = *(const bf16x8*)(Bb2 + roff + 32 + j*8);
        bf16x8 olo, ohi;
        #pragma unroll
        for (int e = 0; e < 8; e++){
          float a = bf2f((unsigned short)vlo[e]) + biasB[j*8+e];
          float d = bf2f((unsigned short)vhi[e]) + biasB[32+j*8+e];
          float cf = bf2f((unsigned short)cc[j][e]);
          float sf = bf2f((unsigned short)sv[j][e]);
          olo[e] = (short)f2bf(a*cf - d*sf);
          ohi[e] = (short)f2bf(a*sf + d*cf);
        }
        ldsw_write8(Bs, t, j*8, olo);
        ldsw_write8(Bs, t, 32 + j*8, ohi);
        #pragma unroll
        for (int e = 0; e < 8; e++){
          ldsw_write1(BTs, j*8+e, t, (unsigned short)olo[e]);
          ldsw_write1(BTs, 32+j*8+e, t, (unsigned short)ohi[e]);
        }
      }
    } else {
      #pragma unroll
      for (int j = 0; j < 8; j++){
        bf16x8 v = *(const bf16x8*)(Bb2 + roff + 64 + j*8);
        bf16x8 o;
        #pragma unroll
        for (int e = 0; e < 8; e++) o[e] = (short)f2bf(bf2f((unsigned short)v[e]) + biasB[64+j*8+e]);
        ldsw_write8(Bs, t, 64 + j*8, o);
        #pragma unroll
        for (int e = 0; e < 8; e++) ldsw_write1(BTs, 64+j*8+e, t, (unsigned short)o[e]);
      }
    }
  }
  // U^T staging: 8 groups of 64 lanes, 16 j each
  {
    const int p = tid & 63, jg = tid >> 6;
    #pragma unroll 4
    for (int q = 0; q < 16; q++){
      int j = jg*16 + q;
      size_t pb = (size_t)(base + j) * 8704;
      float xx = bf2f(proj[pb + 4096 + h*64 + p]);
      ldsw_write1(Uts, p, j, f2bf(xx * dts[j]));
    }
  }
  __syncthreads();

  // MFMA1: scores[t][j] = C . B^T   (per wave: 64 t x 32 j)
  f32x4 acc1[4][2];
  #pragma unroll
  for (int mi = 0; mi < 4; mi++)
    #pragma unroll
    for (int ni = 0; ni < 2; ni++)
      acc1[mi][ni] = (f32x4){0.f,0.f,0.f,0.f};
  #pragma unroll
  for (int ks = 0; ks < 4; ks++){
    bf16x8 af[4], bj[2];
    #pragma unroll
    for (int mi = 0; mi < 4; mi++) af[mi] = ldsw_read8(Cs, wr*64+mi*16+fr, ks*32+fq*8);
    #pragma unroll
    for (int ni = 0; ni < 2; ni++) bj[ni] = ldsw_read8(Bs, wc*32+ni*16+fr, ks*32+fq*8);
    #pragma unroll
    for (int mi = 0; mi < 4; mi++)
      #pragma unroll
      for (int ni = 0; ni < 2; ni++)
        acc1[mi][ni] = __builtin_amdgcn_mfma_f32_16x16x32_bf16(af[mi], bj[ni], acc1[mi][ni], 0,0,0);
  }
  // weight epilogue: P = W o scores
  unsigned short pr[4][2][4];
  int jj[2]; float clcj[2], gj[2];
  #pragma unroll
  for (int ni = 0; ni < 2; ni++){ jj[ni] = wc*32+ni*16+fr; clcj[ni] = clcs[jj[ni]]; gj[ni] = gs[jj[ni]]; }
  #pragma unroll
  for (int mi = 0; mi < 4; mi++){
    #pragma unroll
    for (int r = 0; r < 4; r++){
      int t = wr*64+mi*16+fq*4+r;
      float ct_ = clcs[t], lt = lams[t];
      #pragma unroll
      for (int ni = 0; ni < 2; ni++){
        int j = jj[ni];
        float w = (j < t) ? __expf(ct_ - clcj[ni])*gj[ni] : ((j == t) ? (1.f - lt) : 0.f);
        pr[mi][ni][r] = f2bf(acc1[mi][ni][r] * w);
      }
    }
  }
  __syncthreads();                     // all MFMA1 reads of Bs complete
  #pragma unroll
  for (int mi = 0; mi < 4; mi++)
    #pragma unroll
    for (int ni = 0; ni < 2; ni++)
      #pragma unroll
      for (int r = 0; r < 4; r++)
        ldsw_write1(Bs, wr*64+mi*16+fq*4+r, wc*32+ni*16+fr, pr[mi][ni][r]);
  __syncthreads();

  // MFMA2: y_intra[t][p] = P . U   (per wave: 64 t x 16 p)
  f32x4 acc2[4];
  #pragma unroll
  for (int mi = 0; mi < 4; mi++) acc2[mi] = (f32x4){0.f,0.f,0.f,0.f};
  #pragma unroll
  for (int ks = 0; ks < 4; ks++){
    bf16x8 af[4], uj;
    #pragma unroll
    for (int mi = 0; mi < 4; mi++) af[mi] = ldsw_read8(Bs, wr*64+mi*16+fr, ks*32+fq*8);
    uj = ldsw_read8(Uts, wc*16+fr, ks*32+fq*8);
    #pragma unroll
    for (int mi = 0; mi < 4; mi++)
      acc2[mi] = __builtin_amdgcn_mfma_f32_16x16x32_bf16(af[mi], uj, acc2[mi], 0,0,0);
  }
  // MFMA4: G[p][n] = (wU o U) . B   (per wave: 32 p x 32 n)
  f32x4 accS[2][2];
  #pragma unroll
  for (int mi = 0; mi < 2; mi++)
    #pragma unroll
    for (int ni = 0; ni < 2; ni++)
      accS[mi][ni] = (f32x4){0.f,0.f,0.f,0.f};
  #pragma unroll
  for (int ks = 0; ks < 4; ks++){
    bf16x8 au[2], bn[2];
    #pragma unroll
    for (int mi = 0; mi < 2; mi++){
      bf16x8 raw = ldsw_read8(Uts, wr*32+mi*16+fr, ks*32+fq*8);
      #pragma unroll
      for (int e = 0; e < 8; e++){
        float f = bf2f((unsigned short)raw[e]) * wUs[ks*32+fq*8+e];
        au[mi][e] = (short)f2bf(f);
      }
    }
    #pragma unroll
    for (int ni = 0; ni < 2; ni++) bn[ni] = ldsw_read8(BTs, wc*32+ni*16+fr, ks*32+fq*8);
    #pragma unroll
    for (int mi = 0; mi < 2; mi++)
      #pragma unroll
      for (int ni = 0; ni < 2; ni++)
        accS[mi][ni] = __builtin_amdgcn_mfma_f32_16x16x32_bf16(au[mi], bn[ni], accS[mi][ni], 0,0,0);
  }

  // stores: y_intra + D*x (ungated) and G
  #pragma unroll
  for (int mi = 0; mi < 4; mi++){
    #pragma unroll
    for (int r = 0; r < 4; r++){
      int t = wr*64+mi*16+fq*4+r;
      int p = wc*16+fr;
      float xv = bf2f(ldsw_read1(Uts, p, t)) / fmaxf(dts[t], 1e-30f);
      float o = acc2[mi][r] + Dh*xv;
      ybf[(size_t)(base + t)*4096 + h*64 + p] = f2bf(o);
    }
  }
  #pragma unroll
  for (int mi = 0; mi < 2; mi++)
    #pragma unroll
    for (int ni = 0; ni < 2; ni++)
      #pragma unroll
      for (int r = 0; r < 4; r++){
        int p = wr*32+mi*16+fq*4+r;
        int n = wc*32+ni*16+fr;
        Gbuf[(size_t)blockIdx.x*8192 + p*128 + n] = f2bf(accS[mi][ni][r]);
      }
}

// ---------- pass B: scan over 8 chunks; Gbuf[c] <- S_prev(c), S = decEnd*S + G ----------
__global__ __launch_bounds__(256) void k_scanstate(
    const float* __restrict__ clcb, unsigned short* __restrict__ Gbuf)
{
  const int bh = blockIdx.x, tid = threadIdx.x;
  float S[32];
  #pragma unroll
  for (int q = 0; q < 32; q++) S[q] = 0.f;
  const size_t gbase = (size_t)bh*65536 + (size_t)tid*32;
  for (int c = 0; c < 8; c++){
    float decEnd = __expf(clcb[(size_t)bh*1024 + c*128 + 127]);
    unsigned short* p = Gbuf + gbase + (size_t)c*8192;
    bf16x8 g[4], s[4];
    #pragma unroll
    for (int q = 0; q < 4; q++) g[q] = *(const bf16x8*)(p + q*8);
    #pragma unroll
    for (int q = 0; q < 4; q++)
      #pragma unroll
      for (int e = 0; e < 8; e++) s[q][e] = (short)f2bf(S[q*8+e]);
    #pragma unroll
    for (int q = 0; q < 4; q++) *(bf16x8*)(p + q*8) = s[q];
    #pragma unroll
    for (int q = 0; q < 4; q++)
      #pragma unroll
      for (int e = 0; e < 8; e++)
        S[q*8+e] = decEnd*S[q*8+e] + bf2f((unsigned short)g[q][e]);
  }
}

// ---------- pass C: y = (y_intra + exp(clc_t) * C_t . S_prev^T) * silu(z) ----------
__global__ __launch_bounds__(256) void k_inter(
    const unsigned short* __restrict__ proj,
    const unsigned short* __restrict__ Cb2, const float* __restrict__ Cbias,
    const unsigned short* __restrict__ cosb, const unsigned short* __restrict__ sinb,
    const float* __restrict__ clcb, const unsigned short* __restrict__ Sprev,
    unsigned short* __restrict__ ybf)
{
  const int c = blockIdx.x & 7, bh = blockIdx.x >> 3;
  const int b = bh >> 6, h = bh & 63;
  const int tid = threadIdx.x, lane = tid & 63, wave = tid >> 6;
  const int wr = wave >> 1, wc = wave & 1;
  const int fr = lane & 15, fq = lane >> 4;

  __shared__ __align__(16) unsigned short Cs[128*128];
  __shared__ __align__(16) unsigned short Ss[64*128];
  __shared__ float expclcs[128], biasC[128];

  const int base = b*1024 + c*128;

  if (tid < 128){
    expclcs[tid] = __expf(clcb[(size_t)bh*1024 + c*128 + tid]);
    biasC[tid] = Cbias[h*128 + tid];
  }
  __syncthreads();

  // stage C (bias+rope)
  {
    const int t = tid >> 1, half = tid & 1;
    const int grow = base + t;
    const size_t roff = (size_t)grow*128 + half*64;
    if (half == 0){
      bf16x8 cc[4], sv[4];
      #pragma unroll
      for (int j = 0; j < 4; j++){
        cc[j] = *(const bf16x8*)(cosb + ((size_t)grow*64 + h)*32 + j*8);
        sv[j] = *(const bf16x8*)(sinb + ((size_t)grow*64 + h)*32 + j*8);
      }
      #pragma unroll
      for (int j = 0; j < 4; j++){
        bf16x8 vlo = *(const bf16x8*)(Cb2 + roff + j*8);
        bf16x8 vhi = *(const bf16x8*)(Cb2 + roff + 32 + j*8);
        bf16x8 olo, ohi;
        #pragma unroll
        for (int e = 0; e < 8; e++){
          float a = bf2f((unsigned short)vlo[e]) + biasC[j*8+e];
          float d = bf2f((unsigned short)vhi[e]) + biasC[32+j*8+e];
          float cf = bf2f((unsigned short)cc[j][e]);
          float sf = bf2f((unsigned short)sv[j][e]);
          olo[e] = (short)f2bf(a*cf - d*sf);
          ohi[e] = (short)f2bf(a*sf + d*cf);
        }
        ldsw_write8(Cs, t, j*8, olo);
        ldsw_write8(Cs, t, 32 + j*8, ohi);
      }
    } else {
      #pragma unroll
      for (int j = 0; j < 8; j++){
        bf16x8 v = *(const bf16x8*)(Cb2 + roff + j*8);
        bf16x8 o;
        #pragma unroll
        for (int e = 0; e < 8; e++) o[e] = (short)f2bf(bf2f((unsigned short)v[e]) + biasC[64+j*8+e]);
        ldsw_write8(Cs, t, 64 + j*8, o);
      }
    }
  }
  // stage S_prev (reg -> swizzled LDS)
  {
    const unsigned short* src = Sprev + (size_t)blockIdx.x*8192 + (size_t)tid*32;
    #pragma unroll
    for (int j = 0; j < 4; j++){
      bf16x8 v = *(const bf16x8*)(src + j*8);
      int f = tid*32 + j*8;
      ldsw_write8(Ss, f >> 7, f & 127, v);
    }
  }
  __syncthreads();

  // MFMA: Yinter[t][p] = C . S_prev^T
  f32x4 acc[4][2];
  #pragma unroll
  for (int mi = 0; mi < 4; mi++)
    #pragma unroll
    for (int ni = 0; ni < 2; ni++)
      acc[mi][ni] = (f32x4){0.f,0.f,0.f,0.f};
  #pragma unroll
  for (int ks = 0; ks < 4; ks++){
    bf16x8 af[4], sj[2];
    #pragma unroll
    for (int mi = 0; mi < 4; mi++) af[mi] = ldsw_read8(Cs, wr*64+mi*16+fr, ks*32+fq*8);
    #pragma unroll
    for (int ni = 0; ni < 2; ni++) sj[ni] = ldsw_read8(Ss, wc*32+ni*16+fr, ks*32+fq*8);
    #pragma unroll
    for (int mi = 0; mi < 4; mi++)
      #pragma unroll
      for (int ni = 0; ni < 2; ni++)
        acc[mi][ni] = __builtin_amdgcn_mfma_f32_16x16x32_bf16(af[mi], sj[ni], acc[mi][ni], 0,0,0);
  }

  // epilogue: y = (y_intra + expclc*Yinter) * silu(z)
  #pragma unroll
  for (int mi = 0; mi < 4; mi++){
    #pragma unroll
    for (int ni = 0; ni < 2; ni++){
      #pragma unroll
      for (int r = 0; r < 4; r++){
        int t = wr*64+mi*16+fq*4+r;
        int p = wc*32+ni*16+fr;
        size_t yoff = (size_t)(base + t)*4096 + h*64 + p;
        float y = bf2f(ybf[yoff]) + expclcs[t]*acc[mi][ni][r];
        float zv = bf2f(proj[(size_t)(base + t)*8704 + h*64 + p]);
        float sl = zv / (1.f + __expf(-zv));
        ybf[yoff] = f2bf(y * sl);
      }
    }
  }
}

// ---------- launch ----------
extern "C" void kernel_launch(void* const* d_in, const int* in_sizes, int n_in,
                              void* d_out, int out_size, void* d_ws, size_t ws_size,
                              hipStream_t stream)
{
  const float* hs    = (const float*)d_in[0];
  const float* w1    = (const float*)d_in[1];
  const float* dtb   = (const float*)d_in[2];
  const float* Bbias = (const float*)d_in[3];
  const float* Cbias = (const float*)d_in[4];
  const float* Bw    = (const float*)d_in[5];
  const float* Cw    = (const float*)d_in[6];
  const float* Dv    = (const float*)d_in[7];
  const float* wo    = (const float*)d_in[8];
  float* out = (float*)d_out;
  char* ws = (char*)d_ws;

  unsigned short* projbf = (unsigned short*)(ws + 0UL);
  unsigned short* W1bf   = (unsigned short*)(ws + 35651584UL);
  unsigned short* Gbuf   = W1bf;                                  // post-GEMM1
  unsigned short* Wobf   = W1bf;                                  // post-k_inter
  unsigned short* ybf    = (unsigned short*)(ws + 52428800UL);
  unsigned short* hsbf   = (unsigned short*)(ws + 71172096UL);
  unsigned short* cosb   = hsbf;                                  // post-GEMM1
  unsigned short* sinb   = (unsigned short*)(ws + 79560704UL);
  float* DTt    = (float*)(ws + 87949312UL);
  float* logdec = (float*)(ws + 88473600UL);
  float* lamt   = (float*)(ws + 88997888UL);
  float* clcb   = (float*)(ws + 89522176UL);
  float* gb     = (float*)(ws + 90046464UL);
  unsigned short* Bb2 = (unsigned short*)(ws + 90570752UL);
  unsigned short* Cb2 = (unsigned short*)(ws + 91095040UL);
  if (ws_size < 91619328UL) return;

  (void)in_sizes; (void)n_in; (void)out_size;

  // fused conversion of w1 (17344 blocks) + hs (4096 blocks)
  k_conv2<<<21440, 256, 0, stream>>>(w1, W1bf, 17760256L, 17344, hs, hsbf, 4194304L);
  // GEMM1: tiles 16x68; XCD partition 2x4 -> per-XCD 8rt x 17ct
  k_gemm_bt<true><<<1088, 256, 0, stream>>>(hsbf, W1bf, projbf, 2048, 8672, 8704, 2, 8, 17);
  k_rmsprep<<<2048, 128, 0, stream>>>(projbf, Bw, Cw, dtb, Bb2, Cb2, DTt, logdec, lamt);
  k_phase<<<128, 256, 0, stream>>>(projbf, DTt, logdec, lamt, clcb, gb, cosb, sinb);
  k_intra<<<1024, 512, 0, stream>>>(projbf, Bb2, Cb2, Bbias, Cbias,
                                    cosb, sinb, DTt, clcb, gb, lamt, Dv, ybf, Gbuf);
  k_scanstate<<<128, 256, 0, stream>>>(clcb, Gbuf);
  k_inter<<<1024, 256, 0, stream>>>(projbf, Cb2, Cbias, cosb, sinb, clcb, Gbuf, ybf);
  k_f32_to_bf16<<<8192, 256, 0, stream>>>(wo, Wobf, 8388608L);
  // GEMM2: tiles 16x16; XCD partition 4x2 -> per-XCD 4rt x 8ct
  k_gemm_bt<false><<<256, 256, 0, stream>>>(ybf, Wobf, out, 4096, 2048, 2048, 4, 4, 8);
}

// Round 8
// 324.337 us; speedup vs baseline: 1.0257x; 1.0257x over previous
//
#include <hip/hip_runtime.h>
#include <hip/hip_bf16.h>
#include <cstdint>
#include <cstddef>

#define DEVINL __device__ __forceinline__

typedef __attribute__((ext_vector_type(8))) short bf16x8;
typedef __attribute__((ext_vector_type(4))) float f32x4;

// ---------- helpers ----------
DEVINL float bf2f(unsigned short u){
  union { unsigned u32; float f; } cv; cv.u32 = ((unsigned)u) << 16; return cv.f;
}
DEVINL unsigned short f2bf(float f){
  union { float f; unsigned u32; } cv; cv.f = f;
  unsigned u = cv.u32;
  return (unsigned short)((u + 0x7FFFu + ((u >> 16) & 1u)) >> 16);  // RNE
}
DEVINL float softplusf(float x){ return x > 20.f ? x : log1pf(expf(x)); }

DEVINL void g2l16(const void* gptr, void* ldsptr){
  __builtin_amdgcn_global_load_lds(
      (const __attribute__((address_space(1))) unsigned int*)gptr,
      (__attribute__((address_space(3))) unsigned int*)(uintptr_t)ldsptr,
      16, 0, 0);
}

// swizzled LDS access for 256-byte-row tiles (128 bf16 cols)
DEVINL int swzb(int row, int col){ return row*256 + ((col*2) ^ ((row&7)<<4)); }
DEVINL void ldsw_write8(unsigned short* b, int row, int col, bf16x8 v){
  *(bf16x8*)((char*)b + swzb(row,col)) = v;
}
DEVINL bf16x8 ldsw_read8(const unsigned short* b, int row, int col){
  return *(const bf16x8*)((const char*)b + swzb(row,col));
}
DEVINL void ldsw_write1(unsigned short* b, int row, int col, unsigned short v){
  *(unsigned short*)((char*)b + swzb(row,col)) = v;
}
DEVINL unsigned short ldsw_read1(const unsigned short* b, int row, int col){
  return *(const unsigned short*)((const char*)b + swzb(row,col));
}

// ---------- fused f32 -> bf16 conversion of up to three buffers ----------
__global__ __launch_bounds__(256) void k_conv3(
    const float* __restrict__ a, unsigned short* __restrict__ oa, long na, int nba,
    const float* __restrict__ b, unsigned short* __restrict__ ob, long nb, int nbb,
    const float* __restrict__ c, unsigned short* __restrict__ oc, long nc)
{
  const float* in; unsigned short* out; long n; long blk;
  if ((int)blockIdx.x < nba)            { in = a; out = oa; n = na; blk = blockIdx.x; }
  else if ((int)blockIdx.x < nba + nbb) { in = b; out = ob; n = nb; blk = blockIdx.x - nba; }
  else                                  { in = c; out = oc; n = nc; blk = blockIdx.x - nba - nbb; }
  long i = (blk * 256 + threadIdx.x) * 4;
  if (i + 3 < n){
    float4 v = *(const float4*)(in + i);
    unsigned long long pk =
        (unsigned long long)f2bf(v.x)
      | ((unsigned long long)f2bf(v.y) << 16)
      | ((unsigned long long)f2bf(v.z) << 32)
      | ((unsigned long long)f2bf(v.w) << 48);
    *(unsigned long long*)(out + i) = pk;
  }
}

// ---------- single f32 -> bf16 conversion (fallback path) ----------
__global__ __launch_bounds__(256) void k_f32_to_bf16(
    const float* __restrict__ in, unsigned short* __restrict__ out, long n)
{
  long i = ((long)blockIdx.x * 256 + threadIdx.x) * 4;
  if (i + 3 < n){
    float4 v = *(const float4*)(in + i);
    unsigned long long pk =
        (unsigned long long)f2bf(v.x)
      | ((unsigned long long)f2bf(v.y) << 16)
      | ((unsigned long long)f2bf(v.z) << 32)
      | ((unsigned long long)f2bf(v.w) << 48);
    *(unsigned long long*)(out + i) = pk;
  }
}

// ---------- bf16 GEMM, both operands K-major, C = A * Bt^T ----------
// 128x128 tile, BK=64, swizzled LDS (slot ^= row&7), 2D XCD-local tile partition.
template<bool OUT_BF16>
__global__ __launch_bounds__(256) void k_gemm_bt(
    const unsigned short* __restrict__ A,
    const unsigned short* __restrict__ Bt,
    void* __restrict__ Cout,
    int K, int Nrows, int Npad, int xm, int tmx, int tnx)
{
  __shared__ unsigned short Asub[128*64];
  __shared__ unsigned short Bsub[128*64];
  const int tid = threadIdx.x;
  // bijective 2D XCD partition: requires gridDim.x == 8*tmx*tnx
  const int x = blockIdx.x & 7, i = blockIdx.x >> 3;
  const int rt = (x % xm) * tmx + (i % tmx);
  const int ct = (x / xm) * tnx + (i / tmx);
  const int lane = tid & 63, wave = tid >> 6;
  const int wr = wave >> 1, wc = wave & 1;
  const int fr = lane & 15;
  const int fq = lane >> 4;

  const int srow0 = tid >> 3;
  const int sgrp  = (tid & 7) ^ ((tid >> 3) & 7);
  size_t aoff[4], boff[4];
  #pragma unroll
  for (int j = 0; j < 4; j++){
    int row = j*32 + srow0;
    aoff[j] = (size_t)(rt*128 + row) * K + sgrp*8;
    int brow = ct*128 + row; if (brow > Nrows-1) brow = Nrows-1;
    boff[j] = (size_t)brow * K + sgrp*8;
  }

  f32x4 acc[4][4] = {};

  for (int k0 = 0; k0 < K; k0 += 64){
    #pragma unroll
    for (int j = 0; j < 4; j++){
      g2l16(A  + aoff[j] + k0, (char*)Asub + (j*256 + tid)*16);
      g2l16(Bt + boff[j] + k0, (char*)Bsub + (j*256 + tid)*16);
    }
    asm volatile("s_waitcnt vmcnt(0)" ::: "memory");
    __syncthreads();

    #pragma unroll
    for (int kk = 0; kk < 2; kk++){
      bf16x8 af[4], bfr[4];
      const int slot = (kk*4 + fq) ^ (fr & 7);
      #pragma unroll
      for (int j = 0; j < 4; j++){
        int ra = wr*64 + j*16 + fr;
        int rb = wc*64 + j*16 + fr;
        af[j]  = *(const bf16x8*)((const char*)Asub + ra*128 + slot*16);
        bfr[j] = *(const bf16x8*)((const char*)Bsub + rb*128 + slot*16);
      }
      #pragma unroll
      for (int mi = 0; mi < 4; mi++)
        #pragma unroll
        for (int ni = 0; ni < 4; ni++)
          acc[mi][ni] = __builtin_amdgcn_mfma_f32_16x16x32_bf16(af[mi], bfr[ni], acc[mi][ni], 0, 0, 0);
    }
    __syncthreads();
  }

  const int er = (lane >> 4) * 4;
  const int ec = lane & 15;
  #pragma unroll
  for (int mi = 0; mi < 4; mi++){
    #pragma unroll
    for (int ni = 0; ni < 4; ni++){
      const int row = rt*128 + wr*64 + mi*16 + er;
      const int col = ct*128 + wc*64 + ni*16 + ec;
      #pragma unroll
      for (int r = 0; r < 4; r++){
        if (OUT_BF16)
          ((unsigned short*)Cout)[(size_t)(row+r)*Npad + col] = f2bf(acc[mi][ni][r]);
        else
          ((float*)Cout)[(size_t)(row+r)*Npad + col] = acc[mi][ni][r];
      }
    }
  }
}

// ---------- merged prep: phase pipeline (blocks 0..127) + rmsnorm (blocks 128..1151) ----------
// phase block (b,h): scalars (DT/logdec/lam) -> LDS, chunk cumsum -> clcb/gb, phase cumsum -> cos/sin
// rmsnorm block: 2 rows of Braw/Craw rmsnorm -> bf16
__global__ __launch_bounds__(256) void k_prep(
    const unsigned short* __restrict__ proj, const float* __restrict__ Bw,
    const float* __restrict__ Cw, const float* __restrict__ dtb,
    unsigned short* __restrict__ Bb2, unsigned short* __restrict__ Cb2,
    float* __restrict__ DTt, float* __restrict__ lamt,
    float* __restrict__ clcb, float* __restrict__ gb,
    unsigned short* __restrict__ cosb, unsigned short* __restrict__ sinb)
{
  const int tid = threadIdx.x;
  __shared__ float dtL[1024], ldL[1024], lamL[1024];
  __shared__ float part[8][32];
  __shared__ float red[8];

  if (blockIdx.x >= 128){
    // ---- rmsnorm path: rows 2*(blockIdx-128) and +1 ----
    int row = (int)(blockIdx.x - 128)*2 + (tid >> 7);
    int n = tid & 127;
    size_t base = (size_t)row * 8704;
    float bv = bf2f(proj[base + 8192 + n]);
    float cv = bf2f(proj[base + 8320 + n]);
    float sb = bv*bv, sc = cv*cv;
    #pragma unroll
    for (int m = 1; m < 64; m <<= 1){ sb += __shfl_xor(sb, m, 64); sc += __shfl_xor(sc, m, 64); }
    int w = tid >> 6;
    if ((tid & 63) == 0){ red[w*2] = sb; red[w*2+1] = sc; }
    __syncthreads();
    int rw = (tid >> 7) * 2;          // first wave of this row: 0 or 2
    sb = red[rw*2]   + red[rw*2+2];
    sc = red[rw*2+1] + red[rw*2+3];
    float rb = rsqrtf(sb*(1.f/128.f) + 1e-5f);
    float rc = rsqrtf(sc*(1.f/128.f) + 1e-5f);
    Bb2[row*128 + n] = f2bf(bv*rb*Bw[n]);
    Cb2[row*128 + n] = f2bf(cv*rc*Cw[n]);
    return;
  }

  // ---- phase path: block per (b,h) ----
  const int bh = blockIdx.x, b = bh >> 6, h = bh & 63;
  const size_t sbase = (size_t)bh * 1024;
  // step 1: per-l scalars
  #pragma unroll
  for (int q = 0; q < 4; q++){
    int l = tid*4 + q;
    size_t pb = (size_t)(b*1024 + l) * 8704;
    float dd_dt = bf2f(proj[pb + 8448 + h]);
    float dd_A  = bf2f(proj[pb + 8512 + h]);
    float trap  = bf2f(proj[pb + 8576 + h]);
    float DT  = softplusf(dd_dt + dtb[h]);
    float A   = -fmaxf(softplusf(dd_A), 1e-4f);
    float lam = 1.f / (1.f + expf(-trap));
    dtL[l] = DT; ldL[l] = A*DT; lamL[l] = lam;
    DTt[sbase+l] = DT; lamt[sbase+l] = lam;
  }
  __syncthreads();
  // step 2: per-chunk(128) inclusive cumsum of logdec; g = 1-lam+lam_next
  {
    int e0 = tid * 4;
    float v0 = ldL[e0], v1 = ldL[e0+1], v2 = ldL[e0+2], v3 = ldL[e0+3];
    float p0 = v0, p1 = p0+v1, p2 = p1+v2, p3 = p2+v3;
    float tot = p3;
    int sub = tid & 31;
    float incl = tot;
    #pragma unroll
    for (int off = 1; off < 32; off <<= 1){
      float u = __shfl_up(incl, off, 32);
      if (sub >= off) incl += u;
    }
    float excl = incl - tot;
    clcb[sbase+e0]   = excl + p0;
    clcb[sbase+e0+1] = excl + p1;
    clcb[sbase+e0+2] = excl + p2;
    clcb[sbase+e0+3] = excl + p3;
    #pragma unroll
    for (int q = 0; q < 4; q++){
      int l = e0 + q;
      int ln = (l == 1023) ? 1023 : l + 1;
      gb[sbase+l] = 1.f - lamL[l] + lamL[ln];
    }
  }
  // step 3: phase cumsum + cos/sin (32 na x 8 chunks)
  int na = tid & 31, c = tid >> 5;
  float s = 0.f;
  for (int q = 0; q < 128; q++){
    int l = c*128 + q; int row = b*1024 + l;
    float ang = bf2f(proj[(size_t)row*8704 + 8640 + na]);
    s = fmaf(ang, dtL[l], s);
  }
  part[c][na] = s;
  __syncthreads();
  float off = 0.f;
  for (int cc = 0; cc < c; cc++) off += part[cc][na];
  float ph = off;
  for (int q = 0; q < 128; q++){
    int l = c*128 + q; int row = b*1024 + l;
    float ang = bf2f(proj[(size_t)row*8704 + 8640 + na]);
    ph = fmaf(ang, dtL[l], ph);
    float sn, cs;
    __sincosf(ph, &sn, &cs);
    size_t o = ((size_t)row*64 + h)*32 + na;
    cosb[o] = f2bf(cs); sinb[o] = f2bf(sn);
  }
}

// ---------- pass A: intra-chunk y + chunk state increment G (512 threads, 8 waves) ----------
__global__ __launch_bounds__(512, 1) void k_intra(
    const unsigned short* __restrict__ proj,
    const unsigned short* __restrict__ Bb2, const unsigned short* __restrict__ Cb2,
    const float* __restrict__ Bbias, const float* __restrict__ Cbias,
    const unsigned short* __restrict__ cosb, const unsigned short* __restrict__ sinb,
    const float* __restrict__ DTt, const float* __restrict__ clcb,
    const float* __restrict__ gb, const float* __restrict__ lamt,
    const float* __restrict__ Dv, unsigned short* __restrict__ ybf,
    unsigned short* __restrict__ Gbuf)
{
  const int c = blockIdx.x & 7, bh = blockIdx.x >> 3;
  const int b = bh >> 6, h = bh & 63;
  const int tid = threadIdx.x, lane = tid & 63, wave = tid >> 6;
  const int wr = wave >> 2, wc = wave & 3;
  const int fr = lane & 15, fq = lane >> 4;

  __shared__ __align__(16) unsigned short Cs[128*128];
  __shared__ __align__(16) unsigned short Bs[128*128];   // aliased as P after barrier
  __shared__ __align__(16) unsigned short BTs[128*128];
  __shared__ __align__(16) unsigned short Uts[64*128];   // U^T: [p][j]
  __shared__ float clcs[128], lams[128], gs[128], wUs[128], dts[128];
  __shared__ float biasB[128], biasC[128];

  const int base = b*1024 + c*128;
  const size_t shbase = (size_t)bh * 1024;
  const float Dh = Dv[h];

  // phase 0: scalars
  if (tid < 128){
    int l = c*128 + tid;
    clcs[tid] = clcb[shbase + l];
    dts[tid]  = DTt[shbase + l];
    lams[tid] = lamt[shbase + l];
    gs[tid]   = gb[shbase + l];
    biasB[tid] = Bbias[h*128 + tid];
  } else if (tid < 256){
    biasC[tid-128] = Cbias[h*128 + tid-128];
  }
  __syncthreads();
  if (tid < 128) wUs[tid] = __expf(clcs[127] - clcs[tid]) * gs[tid];

  // phase 1: stage C/B (bias+rope), B^T, U^T  — quarters per row t
  {
    const int t = tid >> 2, q = tid & 3;
    const int grow = base + t;
    const size_t roff = (size_t)grow*128;
    if (q == 0){
      bf16x8 cc[4], sv[4];
      #pragma unroll
      for (int j = 0; j < 4; j++){
        cc[j] = *(const bf16x8*)(cosb + ((size_t)grow*64 + h)*32 + j*8);
        sv[j] = *(const bf16x8*)(sinb + ((size_t)grow*64 + h)*32 + j*8);
      }
      #pragma unroll
      for (int j = 0; j < 4; j++){
        bf16x8 vlo = *(const bf16x8*)(Cb2 + roff + j*8);
        bf16x8 vhi = *(const bf16x8*)(Cb2 + roff + 32 + j*8);
        bf16x8 olo, ohi;
        #pragma unroll
        for (int e = 0; e < 8; e++){
          float a = bf2f((unsigned short)vlo[e]) + biasC[j*8+e];
          float d = bf2f((unsigned short)vhi[e]) + biasC[32+j*8+e];
          float cf = bf2f((unsigned short)cc[j][e]);
          float sf = bf2f((unsigned short)sv[j][e]);
          olo[e] = (short)f2bf(a*cf - d*sf);
          ohi[e] = (short)f2bf(a*sf + d*cf);
        }
        ldsw_write8(Cs, t, j*8, olo);
        ldsw_write8(Cs, t, 32 + j*8, ohi);
      }
    } else if (q == 1){
      #pragma unroll
      for (int j = 0; j < 8; j++){
        bf16x8 v = *(const bf16x8*)(Cb2 + roff + 64 + j*8);
        bf16x8 o;
        #pragma unroll
        for (int e = 0; e < 8; e++) o[e] = (short)f2bf(bf2f((unsigned short)v[e]) + biasC[64+j*8+e]);
        ldsw_write8(Cs, t, 64 + j*8, o);
      }
    } else if (q == 2){
      bf16x8 cc[4], sv[4];
      #pragma unroll
      for (int j = 0; j < 4; j++){
        cc[j] = *(const bf16x8*)(cosb + ((size_t)grow*64 + h)*32 + j*8);
        sv[j] = *(const bf16x8*)(sinb + ((size_t)grow*64 + h)*32 + j*8);
      }
      #pragma unroll
      for (int j = 0; j < 4; j++){
        bf16x8 vlo = *(const bf16x8*)(Bb2 + roff + j*8);
        bf16x8 vhi = *(const bf16x8*)(Bb2 + roff + 32 + j*8);
        bf16x8 olo, ohi;
        #pragma unroll
        for (int e = 0; e < 8; e++){
          float a = bf2f((unsigned short)vlo[e]) + biasB[j*8+e];
          float d = bf2f((unsigned short)vhi[e]) + biasB[32+j*8+e];
          float cf = bf2f((unsigned short)cc[j][e]);
          float sf = bf2f((unsigned short)sv[j][e]);
          olo[e] = (short)f2bf(a*cf - d*sf);
          ohi[e] = (short)f2bf(a*sf + d*cf);
        }
        ldsw_write8(Bs, t, j*8, olo);
        ldsw_write8(Bs, t, 32 + j*8, ohi);
        #pragma unroll
        for (int e = 0; e < 8; e++){
          ldsw_write1(BTs, j*8+e, t, (unsigned short)olo[e]);
          ldsw_write1(BTs, 32+j*8+e, t, (unsigned short)ohi[e]);
        }
      }
    } else {
      #pragma unroll
      for (int j = 0; j < 8; j++){
        bf16x8 v = *(const bf16x8*)(Bb2 + roff + 64 + j*8);
        bf16x8 o;
        #pragma unroll
        for (int e = 0; e < 8; e++) o[e] = (short)f2bf(bf2f((unsigned short)v[e]) + biasB[64+j*8+e]);
        ldsw_write8(Bs, t, 64 + j*8, o);
        #pragma unroll
        for (int e = 0; e < 8; e++) ldsw_write1(BTs, 64+j*8+e, t, (unsigned short)o[e]);
      }
    }
  }
  // U^T staging: 8 groups of 64 lanes, 16 j each
  {
    const int p = tid & 63, jg = tid >> 6;
    #pragma unroll 4
    for (int q = 0; q < 16; q++){
      int j = jg*16 + q;
      size_t pb = (size_t)(base + j) * 8704;
      float xx = bf2f(proj[pb + 4096 + h*64 + p]);
      ldsw_write1(Uts, p, j, f2bf(xx * dts[j]));
    }
  }
  __syncthreads();

  // MFMA1: scores[t][j] = C . B^T   (per wave: 64 t x 32 j)
  f32x4 acc1[4][2];
  #pragma unroll
  for (int mi = 0; mi < 4; mi++)
    #pragma unroll
    for (int ni = 0; ni < 2; ni++)
      acc1[mi][ni] = (f32x4){0.f,0.f,0.f,0.f};
  #pragma unroll
  for (int ks = 0; ks < 4; ks++){
    bf16x8 af[4], bj[2];
    #pragma unroll
    for (int mi = 0; mi < 4; mi++) af[mi] = ldsw_read8(Cs, wr*64+mi*16+fr, ks*32+fq*8);
    #pragma unroll
    for (int ni = 0; ni < 2; ni++) bj[ni] = ldsw_read8(Bs, wc*32+ni*16+fr, ks*32+fq*8);
    #pragma unroll
    for (int mi = 0; mi < 4; mi++)
      #pragma unroll
      for (int ni = 0; ni < 2; ni++)
        acc1[mi][ni] = __builtin_amdgcn_mfma_f32_16x16x32_bf16(af[mi], bj[ni], acc1[mi][ni], 0,0,0);
  }
  // weight epilogue: P = W o scores
  unsigned short pr[4][2][4];
  int jj[2]; float clcj[2], gj[2];
  #pragma unroll
  for (int ni = 0; ni < 2; ni++){ jj[ni] = wc*32+ni*16+fr; clcj[ni] = clcs[jj[ni]]; gj[ni] = gs[jj[ni]]; }
  #pragma unroll
  for (int mi = 0; mi < 4; mi++){
    #pragma unroll
    for (int r = 0; r < 4; r++){
      int t = wr*64+mi*16+fq*4+r;
      float ct_ = clcs[t], lt = lams[t];
      #pragma unroll
      for (int ni = 0; ni < 2; ni++){
        int j = jj[ni];
        float w = (j < t) ? __expf(ct_ - clcj[ni])*gj[ni] : ((j == t) ? (1.f - lt) : 0.f);
        pr[mi][ni][r] = f2bf(acc1[mi][ni][r] * w);
      }
    }
  }
  __syncthreads();                     // all MFMA1 reads of Bs complete
  #pragma unroll
  for (int mi = 0; mi < 4; mi++)
    #pragma unroll
    for (int ni = 0; ni < 2; ni++)
      #pragma unroll
      for (int r = 0; r < 4; r++)
        ldsw_write1(Bs, wr*64+mi*16+fq*4+r, wc*32+ni*16+fr, pr[mi][ni][r]);
  __syncthreads();

  // MFMA2: y_intra[t][p] = P . U   (per wave: 64 t x 16 p)
  f32x4 acc2[4];
  #pragma unroll
  for (int mi = 0; mi < 4; mi++) acc2[mi] = (f32x4){0.f,0.f,0.f,0.f};
  #pragma unroll
  for (int ks = 0; ks < 4; ks++){
    bf16x8 af[4], uj;
    #pragma unroll
    for (int mi = 0; mi < 4; mi++) af[mi] = ldsw_read8(Bs, wr*64+mi*16+fr, ks*32+fq*8);
    uj = ldsw_read8(Uts, wc*16+fr, ks*32+fq*8);
    #pragma unroll
    for (int mi = 0; mi < 4; mi++)
      acc2[mi] = __builtin_amdgcn_mfma_f32_16x16x32_bf16(af[mi], uj, acc2[mi], 0,0,0);
  }
  // MFMA4: G[p][n] = (wU o U) . B   (per wave: 32 p x 32 n)
  f32x4 accS[2][2];
  #pragma unroll
  for (int mi = 0; mi < 2; mi++)
    #pragma unroll
    for (int ni = 0; ni < 2; ni++)
      accS[mi][ni] = (f32x4){0.f,0.f,0.f,0.f};
  #pragma unroll
  for (int ks = 0; ks < 4; ks++){
    bf16x8 au[2], bn[2];
    #pragma unroll
    for (int mi = 0; mi < 2; mi++){
      bf16x8 raw = ldsw_read8(Uts, wr*32+mi*16+fr, ks*32+fq*8);
      #pragma unroll
      for (int e = 0; e < 8; e++){
        float f = bf2f((unsigned short)raw[e]) * wUs[ks*32+fq*8+e];
        au[mi][e] = (short)f2bf(f);
      }
    }
    #pragma unroll
    for (int ni = 0; ni < 2; ni++) bn[ni] = ldsw_read8(BTs, wc*32+ni*16+fr, ks*32+fq*8);
    #pragma unroll
    for (int mi = 0; mi < 2; mi++)
      #pragma unroll
      for (int ni = 0; ni < 2; ni++)
        accS[mi][ni] = __builtin_amdgcn_mfma_f32_16x16x32_bf16(au[mi], bn[ni], accS[mi][ni], 0,0,0);
  }

  // stores: y_intra + D*x (ungated) and G
  #pragma unroll
  for (int mi = 0; mi < 4; mi++){
    #pragma unroll
    for (int r = 0; r < 4; r++){
      int t = wr*64+mi*16+fq*4+r;
      int p = wc*16+fr;
      float xv = bf2f(ldsw_read1(Uts, p, t)) / fmaxf(dts[t], 1e-30f);
      float o = acc2[mi][r] + Dh*xv;
      ybf[(size_t)(base + t)*4096 + h*64 + p] = f2bf(o);
    }
  }
  #pragma unroll
  for (int mi = 0; mi < 2; mi++)
    #pragma unroll
    for (int ni = 0; ni < 2; ni++)
      #pragma unroll
      for (int r = 0; r < 4; r++){
        int p = wr*32+mi*16+fq*4+r;
        int n = wc*32+ni*16+fr;
        Gbuf[(size_t)blockIdx.x*8192 + p*128 + n] = f2bf(accS[mi][ni][r]);
      }
}

// ---------- pass B: scan over 8 chunks; Gbuf[c] <- S_prev(c), S = decEnd*S + G ----------
__global__ __launch_bounds__(256) void k_scanstate(
    const float* __restrict__ clcb, unsigned short* __restrict__ Gbuf)
{
  const int bh = blockIdx.x, tid = threadIdx.x;
  float S[32];
  #pragma unroll
  for (int q = 0; q < 32; q++) S[q] = 0.f;
  const size_t gbase = (size_t)bh*65536 + (size_t)tid*32;
  for (int c = 0; c < 8; c++){
    float decEnd = __expf(clcb[(size_t)bh*1024 + c*128 + 127]);
    unsigned short* p = Gbuf + gbase + (size_t)c*8192;
    bf16x8 g[4], s[4];
    #pragma unroll
    for (int q = 0; q < 4; q++) g[q] = *(const bf16x8*)(p + q*8);
    #pragma unroll
    for (int q = 0; q < 4; q++)
      #pragma unroll
      for (int e = 0; e < 8; e++) s[q][e] = (short)f2bf(S[q*8+e]);
    #pragma unroll
    for (int q = 0; q < 4; q++) *(bf16x8*)(p + q*8) = s[q];
    #pragma unroll
    for (int q = 0; q < 4; q++)
      #pragma unroll
      for (int e = 0; e < 8; e++)
        S[q*8+e] = decEnd*S[q*8+e] + bf2f((unsigned short)g[q][e]);
  }
}

// ---------- pass C: y = (y_intra + exp(clc_t) * C_t . S_prev^T) * silu(z) ----------
__global__ __launch_bounds__(256) void k_inter(
    const unsigned short* __restrict__ proj,
    const unsigned short* __restrict__ Cb2, const float* __restrict__ Cbias,
    const unsigned short* __restrict__ cosb, const unsigned short* __restrict__ sinb,
    const float* __restrict__ clcb, const unsigned short* __restrict__ Sprev,
    unsigned short* __restrict__ ybf)
{
  const int c = blockIdx.x & 7, bh = blockIdx.x >> 3;
  const int b = bh >> 6, h = bh & 63;
  const int tid = threadIdx.x, lane = tid & 63, wave = tid >> 6;
  const int wr = wave >> 1, wc = wave & 1;
  const int fr = lane & 15, fq = lane >> 4;

  __shared__ __align__(16) unsigned short Cs[128*128];
  __shared__ __align__(16) unsigned short Ss[64*128];
  __shared__ float expclcs[128], biasC[128];

  const int base = b*1024 + c*128;

  if (tid < 128){
    expclcs[tid] = __expf(clcb[(size_t)bh*1024 + c*128 + tid]);
    biasC[tid] = Cbias[h*128 + tid];
  }
  __syncthreads();

  // stage C (bias+rope)
  {
    const int t = tid >> 1, half = tid & 1;
    const int grow = base + t;
    const size_t roff = (size_t)grow*128 + half*64;
    if (half == 0){
      bf16x8 cc[4], sv[4];
      #pragma unroll
      for (int j = 0; j < 4; j++){
        cc[j] = *(const bf16x8*)(cosb + ((size_t)grow*64 + h)*32 + j*8);
        sv[j] = *(const bf16x8*)(sinb + ((size_t)grow*64 + h)*32 + j*8);
      }
      #pragma unroll
      for (int j = 0; j < 4; j++){
        bf16x8 vlo = *(const bf16x8*)(Cb2 + roff + j*8);
        bf16x8 vhi = *(const bf16x8*)(Cb2 + roff + 32 + j*8);
        bf16x8 olo, ohi;
        #pragma unroll
        for (int e = 0; e < 8; e++){
          float a = bf2f((unsigned short)vlo[e]) + biasC[j*8+e];
          float d = bf2f((unsigned short)vhi[e]) + biasC[32+j*8+e];
          float cf = bf2f((unsigned short)cc[j][e]);
          float sf = bf2f((unsigned short)sv[j][e]);
          olo[e] = (short)f2bf(a*cf - d*sf);
          ohi[e] = (short)f2bf(a*sf + d*cf);
        }
        ldsw_write8(Cs, t, j*8, olo);
        ldsw_write8(Cs, t, 32 + j*8, ohi);
      }
    } else {
      #pragma unroll
      for (int j = 0; j < 8; j++){
        bf16x8 v = *(const bf16x8*)(Cb2 + roff + j*8);
        bf16x8 o;
        #pragma unroll
        for (int e = 0; e < 8; e++) o[e] = (short)f2bf(bf2f((unsigned short)v[e]) + biasC[64+j*8+e]);
        ldsw_write8(Cs, t, 64 + j*8, o);
      }
    }
  }
  // stage S_prev (reg -> swizzled LDS)
  {
    const unsigned short* src = Sprev + (size_t)blockIdx.x*8192 + (size_t)tid*32;
    #pragma unroll
    for (int j = 0; j < 4; j++){
      bf16x8 v = *(const bf16x8*)(src + j*8);
      int f = tid*32 + j*8;
      ldsw_write8(Ss, f >> 7, f & 127, v);
    }
  }
  __syncthreads();

  // MFMA: Yinter[t][p] = C . S_prev^T
  f32x4 acc[4][2];
  #pragma unroll
  for (int mi = 0; mi < 4; mi++)
    #pragma unroll
    for (int ni = 0; ni < 2; ni++)
      acc[mi][ni] = (f32x4){0.f,0.f,0.f,0.f};
  #pragma unroll
  for (int ks = 0; ks < 4; ks++){
    bf16x8 af[4], sj[2];
    #pragma unroll
    for (int mi = 0; mi < 4; mi++) af[mi] = ldsw_read8(Cs, wr*64+mi*16+fr, ks*32+fq*8);
    #pragma unroll
    for (int ni = 0; ni < 2; ni++) sj[ni] = ldsw_read8(Ss, wc*32+ni*16+fr, ks*32+fq*8);
    #pragma unroll
    for (int mi = 0; mi < 4; mi++)
      #pragma unroll
      for (int ni = 0; ni < 2; ni++)
        acc[mi][ni] = __builtin_amdgcn_mfma_f32_16x16x32_bf16(af[mi], sj[ni], acc[mi][ni], 0,0,0);
  }

  // epilogue: y = (y_intra + expclc*Yinter) * silu(z)
  #pragma unroll
  for (int mi = 0; mi < 4; mi++){
    #pragma unroll
    for (int ni = 0; ni < 2; ni++){
      #pragma unroll
      for (int r = 0; r < 4; r++){
        int t = wr*64+mi*16+fq*4+r;
        int p = wc*32+ni*16+fr;
        size_t yoff = (size_t)(base + t)*4096 + h*64 + p;
        float y = bf2f(ybf[yoff]) + expclcs[t]*acc[mi][ni][r];
        float zv = bf2f(proj[(size_t)(base + t)*8704 + h*64 + p]);
        float sl = zv / (1.f + __expf(-zv));
        ybf[yoff] = f2bf(y * sl);
      }
    }
  }
}

// ---------- launch ----------
extern "C" void kernel_launch(void* const* d_in, const int* in_sizes, int n_in,
                              void* d_out, int out_size, void* d_ws, size_t ws_size,
                              hipStream_t stream)
{
  const float* hs    = (const float*)d_in[0];
  const float* w1    = (const float*)d_in[1];
  const float* dtb   = (const float*)d_in[2];
  const float* Bbias = (const float*)d_in[3];
  const float* Cbias = (const float*)d_in[4];
  const float* Bw    = (const float*)d_in[5];
  const float* Cw    = (const float*)d_in[6];
  const float* Dv    = (const float*)d_in[7];
  const float* wo    = (const float*)d_in[8];
  float* out = (float*)d_out;
  char* ws = (char*)d_ws;

  unsigned short* projbf = (unsigned short*)(ws + 0UL);
  unsigned short* W1bf   = (unsigned short*)(ws + 35651584UL);
  unsigned short* Gbuf   = W1bf;                                  // post-GEMM1
  unsigned short* ybf    = (unsigned short*)(ws + 52428800UL);
  unsigned short* hsbf   = (unsigned short*)(ws + 71172096UL);
  unsigned short* cosb   = hsbf;                                  // post-GEMM1
  unsigned short* sinb   = (unsigned short*)(ws + 79560704UL);
  float* DTt    = (float*)(ws + 87949312UL);
  float* lamt   = (float*)(ws + 88997888UL);
  float* clcb   = (float*)(ws + 89522176UL);
  float* gb     = (float*)(ws + 90046464UL);
  unsigned short* Bb2 = (unsigned short*)(ws + 90570752UL);
  unsigned short* Cb2 = (unsigned short*)(ws + 91095040UL);
  if (ws_size < 91619328UL) return;

  // optional dedicated Wo region: convert early, skip the late conversion launch
  const bool bigws = (ws_size >= 91619328UL + 16777216UL);
  unsigned short* Wobf = bigws ? (unsigned short*)(ws + 91619328UL) : W1bf;

  (void)in_sizes; (void)n_in; (void)out_size;

  // conversions: w1 (17344 blocks) + hs (4096) [+ wo (8192) if bigws]
  k_conv3<<<bigws ? 29632 : 21440, 256, 0, stream>>>(
      w1, W1bf, 17760256L, 17344, hs, hsbf, 4194304L, 4096, wo, Wobf, 8388608L);
  // GEMM1: tiles 16x68; XCD partition 2x4 -> per-XCD 8rt x 17ct
  k_gemm_bt<true><<<1088, 256, 0, stream>>>(hsbf, W1bf, projbf, 2048, 8672, 8704, 2, 8, 17);
  // merged prep: 128 phase blocks + 1024 rmsnorm blocks
  k_prep<<<1152, 256, 0, stream>>>(projbf, Bw, Cw, dtb, Bb2, Cb2,
                                   DTt, lamt, clcb, gb, cosb, sinb);
  k_intra<<<1024, 512, 0, stream>>>(projbf, Bb2, Cb2, Bbias, Cbias,
                                    cosb, sinb, DTt, clcb, gb, lamt, Dv, ybf, Gbuf);
  k_scanstate<<<128, 256, 0, stream>>>(clcb, Gbuf);
  k_inter<<<1024, 256, 0, stream>>>(projbf, Cb2, Cbias, cosb, sinb, clcb, Gbuf, ybf);
  if (!bigws)
    k_f32_to_bf16<<<8192, 256, 0, stream>>>(wo, Wobf, 8388608L);
  // GEMM2: tiles 16x16; XCD partition 4x2 -> per-XCD 4rt x 8ct
  k_gemm_bt<false><<<256, 256, 0, stream>>>(ybf, Wobf, out, 4096, 2048, 2048, 4, 4, 8);
}

// Round 10
// 324.167 us; speedup vs baseline: 1.0262x; 1.0005x over previous
//
#include <hip/hip_runtime.h>
#include <hip/hip_bf16.h>
#include <cstdint>
#include <cstddef>

#define DEVINL __device__ __forceinline__

typedef __attribute__((ext_vector_type(8))) short bf16x8;
typedef __attribute__((ext_vector_type(4))) float f32x4;

// ---------- helpers ----------
DEVINL float bf2f(unsigned short u){
  union { unsigned u32; float f; } cv; cv.u32 = ((unsigned)u) << 16; return cv.f;
}
DEVINL unsigned short f2bf(float f){
  union { float f; unsigned u32; } cv; cv.f = f;
  unsigned u = cv.u32;
  return (unsigned short)((u + 0x7FFFu + ((u >> 16) & 1u)) >> 16);  // RNE
}
DEVINL float softplusf(float x){ return x > 20.f ? x : log1pf(expf(x)); }

DEVINL void g2l16(const void* gptr, void* ldsptr){
  __builtin_amdgcn_global_load_lds(
      (const __attribute__((address_space(1))) unsigned int*)gptr,
      (__attribute__((address_space(3))) unsigned int*)(uintptr_t)ldsptr,
      16, 0, 0);
}

// swizzled LDS access for 256-byte-row tiles (128 bf16 cols)
DEVINL int swzb(int row, int col){ return row*256 + ((col*2) ^ ((row&7)<<4)); }
DEVINL void ldsw_write8(unsigned short* b, int row, int col, bf16x8 v){
  *(bf16x8*)((char*)b + swzb(row,col)) = v;
}
DEVINL bf16x8 ldsw_read8(const unsigned short* b, int row, int col){
  return *(const bf16x8*)((const char*)b + swzb(row,col));
}
DEVINL void ldsw_write1(unsigned short* b, int row, int col, unsigned short v){
  *(unsigned short*)((char*)b + swzb(row,col)) = v;
}
DEVINL unsigned short ldsw_read1(const unsigned short* b, int row, int col){
  return *(const unsigned short*)((const char*)b + swzb(row,col));
}

DEVINL unsigned long long pack4(float4 v){
  return (unsigned long long)f2bf(v.x)
       | ((unsigned long long)f2bf(v.y) << 16)
       | ((unsigned long long)f2bf(v.z) << 32)
       | ((unsigned long long)f2bf(v.w) << 48);
}

// ---------- fused f32 -> bf16 conversion of up to three buffers (32B/thread) ----------
// all element counts must be multiples of 2048
__global__ __launch_bounds__(256) void k_conv3(
    const float* __restrict__ a, unsigned short* __restrict__ oa, int nba,
    const float* __restrict__ b, unsigned short* __restrict__ ob, int nbb,
    const float* __restrict__ c, unsigned short* __restrict__ oc)
{
  const float* in; unsigned short* out; long blk;
  if ((int)blockIdx.x < nba)            { in = a; out = oa; blk = blockIdx.x; }
  else if ((int)blockIdx.x < nba + nbb) { in = b; out = ob; blk = blockIdx.x - nba; }
  else                                  { in = c; out = oc; blk = blockIdx.x - nba - nbb; }
  long i = (blk * 256 + threadIdx.x) * 8;
  float4 v0 = *(const float4*)(in + i);
  float4 v1 = *(const float4*)(in + i + 4);
  unsigned long long pk[2] = { pack4(v0), pack4(v1) };
  *(bf16x8*)(out + i) = *(const bf16x8*)pk;
}

// ---------- bf16 GEMM, both operands K-major, C = A * Bt^T ----------
// 128x128 tile, BK=64, swizzled LDS (slot ^= row&7), 2D XCD-local tile partition.
template<bool OUT_BF16>
__global__ __launch_bounds__(256) void k_gemm_bt(
    const unsigned short* __restrict__ A,
    const unsigned short* __restrict__ Bt,
    void* __restrict__ Cout,
    int K, int Nrows, int Npad, int xm, int tmx, int tnx)
{
  __shared__ unsigned short Asub[128*64];
  __shared__ unsigned short Bsub[128*64];
  const int tid = threadIdx.x;
  // bijective 2D XCD partition: requires gridDim.x == 8*tmx*tnx
  const int x = blockIdx.x & 7, i = blockIdx.x >> 3;
  const int rt = (x % xm) * tmx + (i % tmx);
  const int ct = (x / xm) * tnx + (i / tmx);
  const int lane = tid & 63, wave = tid >> 6;
  const int wr = wave >> 1, wc = wave & 1;
  const int fr = lane & 15;
  const int fq = lane >> 4;

  const int srow0 = tid >> 3;
  const int sgrp  = (tid & 7) ^ ((tid >> 3) & 7);
  size_t aoff[4], boff[4];
  #pragma unroll
  for (int j = 0; j < 4; j++){
    int row = j*32 + srow0;
    aoff[j] = (size_t)(rt*128 + row) * K + sgrp*8;
    int brow = ct*128 + row; if (brow > Nrows-1) brow = Nrows-1;
    boff[j] = (size_t)brow * K + sgrp*8;
  }

  f32x4 acc[4][4] = {};

  for (int k0 = 0; k0 < K; k0 += 64){
    #pragma unroll
    for (int j = 0; j < 4; j++){
      g2l16(A  + aoff[j] + k0, (char*)Asub + (j*256 + tid)*16);
      g2l16(Bt + boff[j] + k0, (char*)Bsub + (j*256 + tid)*16);
    }
    asm volatile("s_waitcnt vmcnt(0)" ::: "memory");
    __syncthreads();

    #pragma unroll
    for (int kk = 0; kk < 2; kk++){
      bf16x8 af[4], bfr[4];
      const int slot = (kk*4 + fq) ^ (fr & 7);
      #pragma unroll
      for (int j = 0; j < 4; j++){
        int ra = wr*64 + j*16 + fr;
        int rb = wc*64 + j*16 + fr;
        af[j]  = *(const bf16x8*)((const char*)Asub + ra*128 + slot*16);
        bfr[j] = *(const bf16x8*)((const char*)Bsub + rb*128 + slot*16);
      }
      #pragma unroll
      for (int mi = 0; mi < 4; mi++)
        #pragma unroll
        for (int ni = 0; ni < 4; ni++)
          acc[mi][ni] = __builtin_amdgcn_mfma_f32_16x16x32_bf16(af[mi], bfr[ni], acc[mi][ni], 0, 0, 0);
    }
    __syncthreads();
  }

  const int er = (lane >> 4) * 4;
  const int ec = lane & 15;
  #pragma unroll
  for (int mi = 0; mi < 4; mi++){
    #pragma unroll
    for (int ni = 0; ni < 4; ni++){
      const int row = rt*128 + wr*64 + mi*16 + er;
      const int col = ct*128 + wc*64 + ni*16 + ec;
      #pragma unroll
      for (int r = 0; r < 4; r++){
        if (OUT_BF16)
          ((unsigned short*)Cout)[(size_t)(row+r)*Npad + col] = f2bf(acc[mi][ni][r]);
        else
          ((float*)Cout)[(size_t)(row+r)*Npad + col] = acc[mi][ni][r];
      }
    }
  }
}

// ---------- merged prep (512 threads): phase pipeline (blocks 0..127) + rmsnorm (128..639) ----------
// phase block (b,h): scalars -> regs/LDS, per-128 chunk cumsum (1 wave = 1 chunk),
// phase cumsum in 16 sub-chunks of 64 -> cos/sin
// rmsnorm block: 4 rows of Braw/Craw rmsnorm -> bf16
__global__ __launch_bounds__(512) void k_prep(
    const unsigned short* __restrict__ proj, const float* __restrict__ Bw,
    const float* __restrict__ Cw, const float* __restrict__ dtb,
    unsigned short* __restrict__ Bb2, unsigned short* __restrict__ Cb2,
    float* __restrict__ DTt, float* __restrict__ lamt,
    float* __restrict__ clcb, float* __restrict__ gb,
    unsigned short* __restrict__ cosb, unsigned short* __restrict__ sinb)
{
  const int tid = threadIdx.x;
  __shared__ float dtL[1024], lamL[1024];
  __shared__ float part[16][32];
  __shared__ float red[16];

  if (blockIdx.x >= 128){
    // ---- rmsnorm path: 4 rows per block ----
    int row = (int)(blockIdx.x - 128)*4 + (tid >> 7);
    int n = tid & 127;
    size_t base = (size_t)row * 8704;
    float bv = bf2f(proj[base + 8192 + n]);
    float cv = bf2f(proj[base + 8320 + n]);
    float sb = bv*bv, sc = cv*cv;
    #pragma unroll
    for (int m = 1; m < 64; m <<= 1){ sb += __shfl_xor(sb, m, 64); sc += __shfl_xor(sc, m, 64); }
    int w = tid >> 6;
    if ((tid & 63) == 0){ red[w*2] = sb; red[w*2+1] = sc; }
    __syncthreads();
    int rw = (tid >> 7) * 2;          // first wave index of this row
    sb = red[rw*2]   + red[rw*2+2];
    sc = red[rw*2+1] + red[rw*2+3];
    float rb = rsqrtf(sb*(1.f/128.f) + 1e-5f);
    float rc = rsqrtf(sc*(1.f/128.f) + 1e-5f);
    Bb2[row*128 + n] = f2bf(bv*rb*Bw[n]);
    Cb2[row*128 + n] = f2bf(cv*rc*Cw[n]);
    return;
  }

  // ---- phase path: block per (b,h) ----
  const int bh = blockIdx.x, b = bh >> 6, h = bh & 63;
  const size_t sbase = (size_t)bh * 1024;
  const int lane = tid & 63;
  // step 1: per-l scalars (2 per thread, contiguous), logdec kept in regs
  float ld0, ld1;
  {
    int l0 = tid*2;
    #pragma unroll
    for (int q = 0; q < 2; q++){
      int l = l0 + q;
      size_t pb = (size_t)(b*1024 + l) * 8704;
      float dd_dt = bf2f(proj[pb + 8448 + h]);
      float dd_A  = bf2f(proj[pb + 8512 + h]);
      float trap  = bf2f(proj[pb + 8576 + h]);
      float DT  = softplusf(dd_dt + dtb[h]);
      float A   = -fmaxf(softplusf(dd_A), 1e-4f);
      float lam = 1.f / (1.f + expf(-trap));
      dtL[l] = DT; lamL[l] = lam;
      if (q == 0) ld0 = A*DT; else ld1 = A*DT;
      DTt[sbase+l] = DT; lamt[sbase+l] = lam;
    }
  }
  __syncthreads();
  // step 2: per-chunk(128) inclusive cumsum of logdec — one wave per chunk
  {
    float p1 = ld0 + ld1;
    float tot = p1;
    float incl = tot;
    #pragma unroll
    for (int off = 1; off < 64; off <<= 1){
      float u = __shfl_up(incl, off, 64);
      if (lane >= off) incl += u;
    }
    float excl = incl - tot;
    int l0 = tid*2;
    clcb[sbase+l0]   = excl + ld0;
    clcb[sbase+l0+1] = excl + p1;
    #pragma unroll
    for (int q = 0; q < 2; q++){
      int l = l0 + q;
      int ln = (l == 1023) ? 1023 : l + 1;
      gb[sbase+l] = 1.f - lamL[l] + lamL[ln];
    }
  }
  // step 3: phase cumsum + cos/sin (32 na x 16 sub-chunks of 64)
  int na = tid & 31, c = tid >> 5;
  float s = 0.f;
  for (int q = 0; q < 64; q++){
    int l = c*64 + q; int row = b*1024 + l;
    float ang = bf2f(proj[(size_t)row*8704 + 8640 + na]);
    s = fmaf(ang, dtL[l], s);
  }
  part[c][na] = s;
  __syncthreads();
  float off = 0.f;
  for (int cc = 0; cc < c; cc++) off += part[cc][na];
  float ph = off;
  for (int q = 0; q < 64; q++){
    int l = c*64 + q; int row = b*1024 + l;
    float ang = bf2f(proj[(size_t)row*8704 + 8640 + na]);
    ph = fmaf(ang, dtL[l], ph);
    float sn, cs;
    __sincosf(ph, &sn, &cs);
    size_t o = ((size_t)row*64 + h)*32 + na;
    cosb[o] = f2bf(cs); sinb[o] = f2bf(sn);
  }
}

// ---------- pass A: intra-chunk y + chunk state increment G (512 threads, 8 waves) ----------
__global__ __launch_bounds__(512, 1) void k_intra(
    const unsigned short* __restrict__ proj,
    const unsigned short* __restrict__ Bb2, const unsigned short* __restrict__ Cb2,
    const float* __restrict__ Bbias, const float* __restrict__ Cbias,
    const unsigned short* __restrict__ cosb, const unsigned short* __restrict__ sinb,
    const float* __restrict__ DTt, const float* __restrict__ clcb,
    const float* __restrict__ gb, const float* __restrict__ lamt,
    const float* __restrict__ Dv, unsigned short* __restrict__ ybf,
    unsigned short* __restrict__ Gbuf)
{
  const int c = blockIdx.x & 7, bh = blockIdx.x >> 3;
  const int b = bh >> 6, h = bh & 63;
  const int tid = threadIdx.x, lane = tid & 63, wave = tid >> 6;
  const int wr = wave >> 2, wc = wave & 3;
  const int fr = lane & 15, fq = lane >> 4;

  __shared__ __align__(16) unsigned short Cs[128*128];
  __shared__ __align__(16) unsigned short Bs[128*128];   // aliased as P after barrier
  __shared__ __align__(16) unsigned short BTs[128*128];
  __shared__ __align__(16) unsigned short Uts[64*128];   // U^T: [p][j]
  __shared__ float clcs[128], lams[128], gs[128], wUs[128], dts[128];
  __shared__ float biasB[128], biasC[128];

  const int base = b*1024 + c*128;
  const size_t shbase = (size_t)bh * 1024;
  const float Dh = Dv[h];

  // phase 0: scalars
  if (tid < 128){
    int l = c*128 + tid;
    clcs[tid] = clcb[shbase + l];
    dts[tid]  = DTt[shbase + l];
    lams[tid] = lamt[shbase + l];
    gs[tid]   = gb[shbase + l];
    biasB[tid] = Bbias[h*128 + tid];
  } else if (tid < 256){
    biasC[tid-128] = Cbias[h*128 + tid-128];
  }
  __syncthreads();
  if (tid < 128) wUs[tid] = __expf(clcs[127] - clcs[tid]) * gs[tid];

  // phase 1: stage C/B (bias+rope), B^T, U^T  — quarters per row t
  {
    const int t = tid >> 2, q = tid & 3;
    const int grow = base + t;
    const size_t roff = (size_t)grow*128;
    if (q == 0){
      bf16x8 cc[4], sv[4];
      #pragma unroll
      for (int j = 0; j < 4; j++){
        cc[j] = *(const bf16x8*)(cosb + ((size_t)grow*64 + h)*32 + j*8);
        sv[j] = *(const bf16x8*)(sinb + ((size_t)grow*64 + h)*32 + j*8);
      }
      #pragma unroll
      for (int j = 0; j < 4; j++){
        bf16x8 vlo = *(const bf16x8*)(Cb2 + roff + j*8);
        bf16x8 vhi = *(const bf16x8*)(Cb2 + roff + 32 + j*8);
        bf16x8 olo, ohi;
        #pragma unroll
        for (int e = 0; e < 8; e++){
          float a = bf2f((unsigned short)vlo[e]) + biasC[j*8+e];
          float d = bf2f((unsigned short)vhi[e]) + biasC[32+j*8+e];
          float cf = bf2f((unsigned short)cc[j][e]);
          float sf = bf2f((unsigned short)sv[j][e]);
          olo[e] = (short)f2bf(a*cf - d*sf);
          ohi[e] = (short)f2bf(a*sf + d*cf);
        }
        ldsw_write8(Cs, t, j*8, olo);
        ldsw_write8(Cs, t, 32 + j*8, ohi);
      }
    } else if (q == 1){
      #pragma unroll
      for (int j = 0; j < 8; j++){
        bf16x8 v = *(const bf16x8*)(Cb2 + roff + 64 + j*8);
        bf16x8 o;
        #pragma unroll
        for (int e = 0; e < 8; e++) o[e] = (short)f2bf(bf2f((unsigned short)v[e]) + biasC[64+j*8+e]);
        ldsw_write8(Cs, t, 64 + j*8, o);
      }
    } else if (q == 2){
      bf16x8 cc[4], sv[4];
      #pragma unroll
      for (int j = 0; j < 4; j++){
        cc[j] = *(const bf16x8*)(cosb + ((size_t)grow*64 + h)*32 + j*8);
        sv[j] = *(const bf16x8*)(sinb + ((size_t)grow*64 + h)*32 + j*8);
      }
      #pragma unroll
      for (int j = 0; j < 4; j++){
        bf16x8 vlo = *(const bf16x8*)(Bb2 + roff + j*8);
        bf16x8 vhi = *(const bf16x8*)(Bb2 + roff + 32 + j*8);
        bf16x8 olo, ohi;
        #pragma unroll
        for (int e = 0; e < 8; e++){
          float a = bf2f((unsigned short)vlo[e]) + biasB[j*8+e];
          float d = bf2f((unsigned short)vhi[e]) + biasB[32+j*8+e];
          float cf = bf2f((unsigned short)cc[j][e]);
          float sf = bf2f((unsigned short)sv[j][e]);
          olo[e] = (short)f2bf(a*cf - d*sf);
          ohi[e] = (short)f2bf(a*sf + d*cf);
        }
        ldsw_write8(Bs, t, j*8, olo);
        ldsw_write8(Bs, t, 32 + j*8, ohi);
        #pragma unroll
        for (int e = 0; e < 8; e++){
          ldsw_write1(BTs, j*8+e, t, (unsigned short)olo[e]);
          ldsw_write1(BTs, 32+j*8+e, t, (unsigned short)ohi[e]);
        }
      }
    } else {
      #pragma unroll
      for (int j = 0; j < 8; j++){
        bf16x8 v = *(const bf16x8*)(Bb2 + roff + 64 + j*8);
        bf16x8 o;
        #pragma unroll
        for (int e = 0; e < 8; e++) o[e] = (short)f2bf(bf2f((unsigned short)v[e]) + biasB[64+j*8+e]);
        ldsw_write8(Bs, t, 64 + j*8, o);
        #pragma unroll
        for (int e = 0; e < 8; e++) ldsw_write1(BTs, 64+j*8+e, t, (unsigned short)o[e]);
      }
    }
  }
  // U^T staging: 8 groups of 64 lanes, 16 j each
  {
    const int p = tid & 63, jg = tid >> 6;
    #pragma unroll 4
    for (int q = 0; q < 16; q++){
      int j = jg*16 + q;
      size_t pb = (size_t)(base + j) * 8704;
      float xx = bf2f(proj[pb + 4096 + h*64 + p]);
      ldsw_write1(Uts, p, j, f2bf(xx * dts[j]));
    }
  }
  __syncthreads();

  // MFMA1: scores[t][j] = C . B^T   (per wave: 64 t x 32 j)
  f32x4 acc1[4][2];
  #pragma unroll
  for (int mi = 0; mi < 4; mi++)
    #pragma unroll
    for (int ni = 0; ni < 2; ni++)
      acc1[mi][ni] = (f32x4){0.f,0.f,0.f,0.f};
  #pragma unroll
  for (int ks = 0; ks < 4; ks++){
    bf16x8 af[4], bj[2];
    #pragma unroll
    for (int mi = 0; mi < 4; mi++) af[mi] = ldsw_read8(Cs, wr*64+mi*16+fr, ks*32+fq*8);
    #pragma unroll
    for (int ni = 0; ni < 2; ni++) bj[ni] = ldsw_read8(Bs, wc*32+ni*16+fr, ks*32+fq*8);
    #pragma unroll
    for (int mi = 0; mi < 4; mi++)
      #pragma unroll
      for (int ni = 0; ni < 2; ni++)
        acc1[mi][ni] = __builtin_amdgcn_mfma_f32_16x16x32_bf16(af[mi], bj[ni], acc1[mi][ni], 0,0,0);
  }
  // weight epilogue: P = W o scores
  unsigned short pr[4][2][4];
  int jj[2]; float clcj[2], gj[2];
  #pragma unroll
  for (int ni = 0; ni < 2; ni++){ jj[ni] = wc*32+ni*16+fr; clcj[ni] = clcs[jj[ni]]; gj[ni] = gs[jj[ni]]; }
  #pragma unroll
  for (int mi = 0; mi < 4; mi++){
    #pragma unroll
    for (int r = 0; r < 4; r++){
      int t = wr*64+mi*16+fq*4+r;
      float ct_ = clcs[t], lt = lams[t];
      #pragma unroll
      for (int ni = 0; ni < 2; ni++){
        int j = jj[ni];
        float w = (j < t) ? __expf(ct_ - clcj[ni])*gj[ni] : ((j == t) ? (1.f - lt) : 0.f);
        pr[mi][ni][r] = f2bf(acc1[mi][ni][r] * w);
      }
    }
  }
  __syncthreads();                     // all MFMA1 reads of Bs complete
  #pragma unroll
  for (int mi = 0; mi < 4; mi++)
    #pragma unroll
    for (int ni = 0; ni < 2; ni++)
      #pragma unroll
      for (int r = 0; r < 4; r++)
        ldsw_write1(Bs, wr*64+mi*16+fq*4+r, wc*32+ni*16+fr, pr[mi][ni][r]);
  __syncthreads();

  // MFMA2: y_intra[t][p] = P . U   (per wave: 64 t x 16 p)
  f32x4 acc2[4];
  #pragma unroll
  for (int mi = 0; mi < 4; mi++) acc2[mi] = (f32x4){0.f,0.f,0.f,0.f};
  #pragma unroll
  for (int ks = 0; ks < 4; ks++){
    bf16x8 af[4], uj;
    #pragma unroll
    for (int mi = 0; mi < 4; mi++) af[mi] = ldsw_read8(Bs, wr*64+mi*16+fr, ks*32+fq*8);
    uj = ldsw_read8(Uts, wc*16+fr, ks*32+fq*8);
    #pragma unroll
    for (int mi = 0; mi < 4; mi++)
      acc2[mi] = __builtin_amdgcn_mfma_f32_16x16x32_bf16(af[mi], uj, acc2[mi], 0,0,0);
  }
  // MFMA4: G[p][n] = (wU o U) . B   (per wave: 32 p x 32 n)
  f32x4 accS[2][2];
  #pragma unroll
  for (int mi = 0; mi < 2; mi++)
    #pragma unroll
    for (int ni = 0; ni < 2; ni++)
      accS[mi][ni] = (f32x4){0.f,0.f,0.f,0.f};
  #pragma unroll
  for (int ks = 0; ks < 4; ks++){
    bf16x8 au[2], bn[2];
    #pragma unroll
    for (int mi = 0; mi < 2; mi++){
      bf16x8 raw = ldsw_read8(Uts, wr*32+mi*16+fr, ks*32+fq*8);
      #pragma unroll
      for (int e = 0; e < 8; e++){
        float f = bf2f((unsigned short)raw[e]) * wUs[ks*32+fq*8+e];
        au[mi][e] = (short)f2bf(f);
      }
    }
    #pragma unroll
    for (int ni = 0; ni < 2; ni++) bn[ni] = ldsw_read8(BTs, wc*32+ni*16+fr, ks*32+fq*8);
    #pragma unroll
    for (int mi = 0; mi < 2; mi++)
      #pragma unroll
      for (int ni = 0; ni < 2; ni++)
        accS[mi][ni] = __builtin_amdgcn_mfma_f32_16x16x32_bf16(au[mi], bn[ni], accS[mi][ni], 0,0,0);
  }

  // stores: y_intra + D*x (ungated) and G
  #pragma unroll
  for (int mi = 0; mi < 4; mi++){
    #pragma unroll
    for (int r = 0; r < 4; r++){
      int t = wr*64+mi*16+fq*4+r;
      int p = wc*16+fr;
      float xv = bf2f(ldsw_read1(Uts, p, t)) / fmaxf(dts[t], 1e-30f);
      float o = acc2[mi][r] + Dh*xv;
      ybf[(size_t)(base + t)*4096 + h*64 + p] = f2bf(o);
    }
  }
  #pragma unroll
  for (int mi = 0; mi < 2; mi++)
    #pragma unroll
    for (int ni = 0; ni < 2; ni++)
      #pragma unroll
      for (int r = 0; r < 4; r++){
        int p = wr*32+mi*16+fq*4+r;
        int n = wc*32+ni*16+fr;
        Gbuf[(size_t)blockIdx.x*8192 + p*128 + n] = f2bf(accS[mi][ni][r]);
      }
}

// ---------- pass B: scan over 8 chunks; Gbuf[c] <- S_prev(c), S = decEnd*S + G ----------
__global__ __launch_bounds__(256) void k_scanstate(
    const float* __restrict__ clcb, unsigned short* __restrict__ Gbuf)
{
  const int bh = blockIdx.x, tid = threadIdx.x;
  float S[32];
  #pragma unroll
  for (int q = 0; q < 32; q++) S[q] = 0.f;
  const size_t gbase = (size_t)bh*65536 + (size_t)tid*32;
  for (int c = 0; c < 8; c++){
    float decEnd = __expf(clcb[(size_t)bh*1024 + c*128 + 127]);
    unsigned short* p = Gbuf + gbase + (size_t)c*8192;
    bf16x8 g[4], s[4];
    #pragma unroll
    for (int q = 0; q < 4; q++) g[q] = *(const bf16x8*)(p + q*8);
    #pragma unroll
    for (int q = 0; q < 4; q++)
      #pragma unroll
      for (int e = 0; e < 8; e++) s[q][e] = (short)f2bf(S[q*8+e]);
    #pragma unroll
    for (int q = 0; q < 4; q++) *(bf16x8*)(p + q*8) = s[q];
    #pragma unroll
    for (int q = 0; q < 4; q++)
      #pragma unroll
      for (int e = 0; e < 8; e++)
        S[q*8+e] = decEnd*S[q*8+e] + bf2f((unsigned short)g[q][e]);
  }
}

// ---------- pass C: y = (y_intra + exp(clc_t) * C_t . S_prev^T) * silu(z) ----------
// hybrid: blocks >= 1024 convert wo f32->bf16 (small-ws path)
__global__ __launch_bounds__(256) void k_inter(
    const unsigned short* __restrict__ proj,
    const unsigned short* __restrict__ Cb2, const float* __restrict__ Cbias,
    const unsigned short* __restrict__ cosb, const unsigned short* __restrict__ sinb,
    const float* __restrict__ clcb, const unsigned short* __restrict__ Sprev,
    unsigned short* __restrict__ ybf,
    const float* __restrict__ wo, unsigned short* __restrict__ wobf)
{
  if (blockIdx.x >= 1024){
    long i = (((long)blockIdx.x - 1024) * 256 + threadIdx.x) * 4;
    float4 v = *(const float4*)(wo + i);
    *(unsigned long long*)(wobf + i) = pack4(v);
    return;
  }
  const int c = blockIdx.x & 7, bh = blockIdx.x >> 3;
  const int b = bh >> 6, h = bh & 63;
  const int tid = threadIdx.x, lane = tid & 63, wave = tid >> 6;
  const int wr = wave >> 1, wc = wave & 1;
  const int fr = lane & 15, fq = lane >> 4;

  __shared__ __align__(16) unsigned short Cs[128*128];
  __shared__ __align__(16) unsigned short Ss[64*128];
  __shared__ float expclcs[128], biasC[128];

  const int base = b*1024 + c*128;

  if (tid < 128){
    expclcs[tid] = __expf(clcb[(size_t)bh*1024 + c*128 + tid]);
    biasC[tid] = Cbias[h*128 + tid];
  }
  __syncthreads();

  // stage C (bias+rope)
  {
    const int t = tid >> 1, half = tid & 1;
    const int grow = base + t;
    const size_t roff = (size_t)grow*128 + half*64;
    if (half == 0){
      bf16x8 cc[4], sv[4];
      #pragma unroll
      for (int j = 0; j < 4; j++){
        cc[j] = *(const bf16x8*)(cosb + ((size_t)grow*64 + h)*32 + j*8);
        sv[j] = *(const bf16x8*)(sinb + ((size_t)grow*64 + h)*32 + j*8);
      }
      #pragma unroll
      for (int j = 0; j < 4; j++){
        bf16x8 vlo = *(const bf16x8*)(Cb2 + roff + j*8);
        bf16x8 vhi = *(const bf16x8*)(Cb2 + roff + 32 + j*8);
        bf16x8 olo, ohi;
        #pragma unroll
        for (int e = 0; e < 8; e++){
          float a = bf2f((unsigned short)vlo[e]) + biasC[j*8+e];
          float d = bf2f((unsigned short)vhi[e]) + biasC[32+j*8+e];
          float cf = bf2f((unsigned short)cc[j][e]);
          float sf = bf2f((unsigned short)sv[j][e]);
          olo[e] = (short)f2bf(a*cf - d*sf);
          ohi[e] = (short)f2bf(a*sf + d*cf);
        }
        ldsw_write8(Cs, t, j*8, olo);
        ldsw_write8(Cs, t, 32 + j*8, ohi);
      }
    } else {
      #pragma unroll
      for (int j = 0; j < 8; j++){
        bf16x8 v = *(const bf16x8*)(Cb2 + roff + j*8);
        bf16x8 o;
        #pragma unroll
        for (int e = 0; e < 8; e++) o[e] = (short)f2bf(bf2f((unsigned short)v[e]) + biasC[64+j*8+e]);
        ldsw_write8(Cs, t, 64 + j*8, o);
      }
    }
  }
  // stage S_prev (reg -> swizzled LDS)
  {
    const unsigned short* src = Sprev + (size_t)blockIdx.x*8192 + (size_t)tid*32;
    #pragma unroll
    for (int j = 0; j < 4; j++){
      bf16x8 v = *(const bf16x8*)(src + j*8);
      int f = tid*32 + j*8;
      ldsw_write8(Ss, f >> 7, f & 127, v);
    }
  }
  __syncthreads();

  // MFMA: Yinter[t][p] = C . S_prev^T
  f32x4 acc[4][2];
  #pragma unroll
  for (int mi = 0; mi < 4; mi++)
    #pragma unroll
    for (int ni = 0; ni < 2; ni++)
      acc[mi][ni] = (f32x4){0.f,0.f,0.f,0.f};
  #pragma unroll
  for (int ks = 0; ks < 4; ks++){
    bf16x8 af[4], sj[2];
    #pragma unroll
    for (int mi = 0; mi < 4; mi++) af[mi] = ldsw_read8(Cs, wr*64+mi*16+fr, ks*32+fq*8);
    #pragma unroll
    for (int ni = 0; ni < 2; ni++) sj[ni] = ldsw_read8(Ss, wc*32+ni*16+fr, ks*32+fq*8);
    #pragma unroll
    for (int mi = 0; mi < 4; mi++)
      #pragma unroll
      for (int ni = 0; ni < 2; ni++)
        acc[mi][ni] = __builtin_amdgcn_mfma_f32_16x16x32_bf16(af[mi], sj[ni], acc[mi][ni], 0,0,0);
  }

  // epilogue: y = (y_intra + expclc*Yinter) * silu(z)
  #pragma unroll
  for (int mi = 0; mi < 4; mi++){
    #pragma unroll
    for (int ni = 0; ni < 2; ni++){
      #pragma unroll
      for (int r = 0; r < 4; r++){
        int t = wr*64+mi*16+fq*4+r;
        int p = wc*32+ni*16+fr;
        size_t yoff = (size_t)(base + t)*4096 + h*64 + p;
        float y = bf2f(ybf[yoff]) + expclcs[t]*acc[mi][ni][r];
        float zv = bf2f(proj[(size_t)(base + t)*8704 + h*64 + p]);
        float sl = zv / (1.f + __expf(-zv));
        ybf[yoff] = f2bf(y * sl);
      }
    }
  }
}

// ---------- launch ----------
extern "C" void kernel_launch(void* const* d_in, const int* in_sizes, int n_in,
                              void* d_out, int out_size, void* d_ws, size_t ws_size,
                              hipStream_t stream)
{
  const float* hs    = (const float*)d_in[0];
  const float* w1    = (const float*)d_in[1];
  const float* dtb   = (const float*)d_in[2];
  const float* Bbias = (const float*)d_in[3];
  const float* Cbias = (const float*)d_in[4];
  const float* Bw    = (const float*)d_in[5];
  const float* Cw    = (const float*)d_in[6];
  const float* Dv    = (const float*)d_in[7];
  const float* wo    = (const float*)d_in[8];
  float* out = (float*)d_out;
  char* ws = (char*)d_ws;

  unsigned short* projbf = (unsigned short*)(ws + 0UL);
  unsigned short* W1bf   = (unsigned short*)(ws + 35651584UL);
  unsigned short* Gbuf   = W1bf;                                  // post-GEMM1
  unsigned short* ybf    = (unsigned short*)(ws + 52428800UL);
  unsigned short* hsbf   = (unsigned short*)(ws + 71172096UL);
  unsigned short* cosb   = hsbf;                                  // post-GEMM1
  unsigned short* sinb   = (unsigned short*)(ws + 79560704UL);
  float* DTt    = (float*)(ws + 87949312UL);
  float* lamt   = (float*)(ws + 88997888UL);
  float* clcb   = (float*)(ws + 89522176UL);
  float* gb     = (float*)(ws + 90046464UL);
  unsigned short* Bb2 = (unsigned short*)(ws + 90570752UL);
  unsigned short* Cb2 = (unsigned short*)(ws + 91095040UL);
  if (ws_size < 91619328UL) return;

  // optional dedicated Wo region: convert early, skip the late conversion
  const bool bigws = (ws_size >= 91619328UL + 16777216UL);
  unsigned short* Wobf = bigws ? (unsigned short*)(ws + 91619328UL) : W1bf;

  (void)in_sizes; (void)n_in; (void)out_size;

  // conversions (2048 elems/block): w1 (8672) + hs (2048) [+ wo (4096) if bigws]
  k_conv3<<<bigws ? 14816 : 10720, 256, 0, stream>>>(
      w1, W1bf, 8672, hs, hsbf, 2048, wo, Wobf);
  // GEMM1: tiles 16x68; XCD partition 2x4 -> per-XCD 8rt x 17ct
  k_gemm_bt<true><<<1088, 256, 0, stream>>>(hsbf, W1bf, projbf, 2048, 8672, 8704, 2, 8, 17);
  // merged prep: 128 phase blocks + 512 rmsnorm blocks (512 threads)
  k_prep<<<640, 512, 0, stream>>>(projbf, Bw, Cw, dtb, Bb2, Cb2,
                                  DTt, lamt, clcb, gb, cosb, sinb);
  k_intra<<<1024, 512, 0, stream>>>(projbf, Bb2, Cb2, Bbias, Cbias,
                                    cosb, sinb, DTt, clcb, gb, lamt, Dv, ybf, Gbuf);
  k_scanstate<<<128, 256, 0, stream>>>(clcb, Gbuf);
  // pass C; small-ws path also converts wo in trailing blocks
  k_inter<<<bigws ? 1024 : 9216, 256, 0, stream>>>(
      projbf, Cb2, Cbias, cosb, sinb, clcb, Gbuf, ybf, wo, Wobf);
  // GEMM2: tiles 16x16; XCD partition 4x2 -> per-XCD 4rt x 8ct
  k_gemm_bt<false><<<256, 256, 0, stream>>>(ybf, Wobf, out, 4096, 2048, 2048, 4, 4, 8);
}

// Round 12
// 310.093 us; speedup vs baseline: 1.0728x; 1.0454x over previous
//
#include <hip/hip_runtime.h>
#include <hip/hip_bf16.h>
#include <cstdint>
#include <cstddef>

#define DEVINL __device__ __forceinline__

typedef __attribute__((ext_vector_type(8))) short bf16x8;
typedef __attribute__((ext_vector_type(4))) float f32x4;

// ---------- helpers ----------
DEVINL float bf2f(unsigned short u){
  union { unsigned u32; float f; } cv; cv.u32 = ((unsigned)u) << 16; return cv.f;
}
DEVINL unsigned short f2bf(float f){
  union { float f; unsigned u32; } cv; cv.f = f;
  unsigned u = cv.u32;
  return (unsigned short)((u + 0x7FFFu + ((u >> 16) & 1u)) >> 16);  // RNE
}
DEVINL float softplusf(float x){ return x > 20.f ? x : log1pf(expf(x)); }

DEVINL void g2l16(const void* gptr, void* ldsptr){
  __builtin_amdgcn_global_load_lds(
      (const __attribute__((address_space(1))) unsigned int*)gptr,
      (__attribute__((address_space(3))) unsigned int*)(uintptr_t)ldsptr,
      16, 0, 0);
}

// swizzled LDS access for 256-byte-row tiles (128 bf16 cols)
DEVINL int swzb(int row, int col){ return row*256 + ((col*2) ^ ((row&7)<<4)); }
DEVINL void ldsw_write8(unsigned short* b, int row, int col, bf16x8 v){
  *(bf16x8*)((char*)b + swzb(row,col)) = v;
}
DEVINL bf16x8 ldsw_read8(const unsigned short* b, int row, int col){
  return *(const bf16x8*)((const char*)b + swzb(row,col));
}
DEVINL void ldsw_write1(unsigned short* b, int row, int col, unsigned short v){
  *(unsigned short*)((char*)b + swzb(row,col)) = v;
}
DEVINL unsigned short ldsw_read1(const unsigned short* b, int row, int col){
  return *(const unsigned short*)((const char*)b + swzb(row,col));
}

DEVINL unsigned long long pack4(float4 v){
  return (unsigned long long)f2bf(v.x)
       | ((unsigned long long)f2bf(v.y) << 16)
       | ((unsigned long long)f2bf(v.z) << 32)
       | ((unsigned long long)f2bf(v.w) << 48);
}

// ---------- fused f32 -> bf16 conversion of up to three buffers (32B/thread) ----------
// all element counts must be multiples of 2048
__global__ __launch_bounds__(256) void k_conv3(
    const float* __restrict__ a, unsigned short* __restrict__ oa, int nba,
    const float* __restrict__ b, unsigned short* __restrict__ ob, int nbb,
    const float* __restrict__ c, unsigned short* __restrict__ oc)
{
  const float* in; unsigned short* out; long blk;
  if ((int)blockIdx.x < nba)            { in = a; out = oa; blk = blockIdx.x; }
  else if ((int)blockIdx.x < nba + nbb) { in = b; out = ob; blk = blockIdx.x - nba; }
  else                                  { in = c; out = oc; blk = blockIdx.x - nba - nbb; }
  long i = (blk * 256 + threadIdx.x) * 8;
  float4 v0 = *(const float4*)(in + i);
  float4 v1 = *(const float4*)(in + i + 4);
  unsigned long long pk[2] = { pack4(v0), pack4(v1) };
  *(bf16x8*)(out + i) = *(const bf16x8*)pk;
}

// ---------- bf16 GEMM, both operands K-major, C = A * Bt^T ----------
// 128xBN tile, BK=64, swizzled LDS (slot ^= row&7), 2D XCD-local tile partition.
// BN=128 (4 B-blocks/wave) or BN=64 (2 B-blocks/wave, for small-N latency-bound shapes).
template<bool OUT_BF16, int BN>
__global__ __launch_bounds__(256) void k_gemm_bt(
    const unsigned short* __restrict__ A,
    const unsigned short* __restrict__ Bt,
    void* __restrict__ Cout,
    int K, int Nrows, int Npad, int xm, int tmx, int tnx)
{
  constexpr int NB = BN / 32;          // B fragment blocks per wave
  __shared__ unsigned short Asub[128*64];
  __shared__ unsigned short Bsub[BN*64];
  const int tid = threadIdx.x;
  // bijective 2D XCD partition: requires gridDim.x == 8*tmx*tnx
  const int x = blockIdx.x & 7, i = blockIdx.x >> 3;
  const int rt = (x % xm) * tmx + (i % tmx);
  const int ct = (x / xm) * tnx + (i / tmx);
  const int lane = tid & 63, wave = tid >> 6;
  const int wr = wave >> 1, wc = wave & 1;
  const int fr = lane & 15;
  const int fq = lane >> 4;

  const int srow0 = tid >> 3;
  const int sgrp  = (tid & 7) ^ ((tid >> 3) & 7);
  size_t aoff[4], boff[NB];
  #pragma unroll
  for (int j = 0; j < 4; j++){
    int row = j*32 + srow0;
    aoff[j] = (size_t)(rt*128 + row) * K + sgrp*8;
  }
  #pragma unroll
  for (int j = 0; j < NB; j++){
    int row = j*32 + srow0;
    int brow = ct*BN + row; if (brow > Nrows-1) brow = Nrows-1;
    boff[j] = (size_t)brow * K + sgrp*8;
  }

  f32x4 acc[4][NB] = {};

  for (int k0 = 0; k0 < K; k0 += 64){
    #pragma unroll
    for (int j = 0; j < 4; j++)
      g2l16(A + aoff[j] + k0, (char*)Asub + (j*256 + tid)*16);
    #pragma unroll
    for (int j = 0; j < NB; j++)
      g2l16(Bt + boff[j] + k0, (char*)Bsub + (j*256 + tid)*16);
    asm volatile("s_waitcnt vmcnt(0)" ::: "memory");
    __syncthreads();

    #pragma unroll
    for (int kk = 0; kk < 2; kk++){
      bf16x8 af[4], bfr[NB];
      const int slot = (kk*4 + fq) ^ (fr & 7);
      #pragma unroll
      for (int j = 0; j < 4; j++){
        int ra = wr*64 + j*16 + fr;
        af[j] = *(const bf16x8*)((const char*)Asub + ra*128 + slot*16);
      }
      #pragma unroll
      for (int j = 0; j < NB; j++){
        int rb = wc*(BN/2) + j*16 + fr;
        bfr[j] = *(const bf16x8*)((const char*)Bsub + rb*128 + slot*16);
      }
      #pragma unroll
      for (int mi = 0; mi < 4; mi++)
        #pragma unroll
        for (int ni = 0; ni < NB; ni++)
          acc[mi][ni] = __builtin_amdgcn_mfma_f32_16x16x32_bf16(af[mi], bfr[ni], acc[mi][ni], 0, 0, 0);
    }
    __syncthreads();
  }

  const int er = (lane >> 4) * 4;
  const int ec = lane & 15;
  #pragma unroll
  for (int mi = 0; mi < 4; mi++){
    #pragma unroll
    for (int ni = 0; ni < NB; ni++){
      const int row = rt*128 + wr*64 + mi*16 + er;
      const int col = ct*BN + wc*(BN/2) + ni*16 + ec;
      #pragma unroll
      for (int r = 0; r < 4; r++){
        if (OUT_BF16)
          ((unsigned short*)Cout)[(size_t)(row+r)*Npad + col] = f2bf(acc[mi][ni][r]);
        else
          ((float*)Cout)[(size_t)(row+r)*Npad + col] = acc[mi][ni][r];
      }
    }
  }
}

// ---------- merged prep (512 threads): phase pipeline (blocks 0..127) + rmsnorm (128..639) ----------
__global__ __launch_bounds__(512) void k_prep(
    const unsigned short* __restrict__ proj, const float* __restrict__ Bw,
    const float* __restrict__ Cw, const float* __restrict__ dtb,
    unsigned short* __restrict__ Bb2, unsigned short* __restrict__ Cb2,
    float* __restrict__ DTt, float* __restrict__ lamt,
    float* __restrict__ clcb, float* __restrict__ gb,
    unsigned short* __restrict__ cosb, unsigned short* __restrict__ sinb)
{
  const int tid = threadIdx.x;
  __shared__ float dtL[1024], lamL[1024];
  __shared__ float part[16][32];
  __shared__ float red[16];

  if (blockIdx.x >= 128){
    // ---- rmsnorm path: 4 rows per block ----
    int row = (int)(blockIdx.x - 128)*4 + (tid >> 7);
    int n = tid & 127;
    size_t base = (size_t)row * 8704;
    float bv = bf2f(proj[base + 8192 + n]);
    float cv = bf2f(proj[base + 8320 + n]);
    float sb = bv*bv, sc = cv*cv;
    #pragma unroll
    for (int m = 1; m < 64; m <<= 1){ sb += __shfl_xor(sb, m, 64); sc += __shfl_xor(sc, m, 64); }
    int w = tid >> 6;
    if ((tid & 63) == 0){ red[w*2] = sb; red[w*2+1] = sc; }
    __syncthreads();
    int rw = (tid >> 7) * 2;
    sb = red[rw*2]   + red[rw*2+2];
    sc = red[rw*2+1] + red[rw*2+3];
    float rb = rsqrtf(sb*(1.f/128.f) + 1e-5f);
    float rc = rsqrtf(sc*(1.f/128.f) + 1e-5f);
    Bb2[row*128 + n] = f2bf(bv*rb*Bw[n]);
    Cb2[row*128 + n] = f2bf(cv*rc*Cw[n]);
    return;
  }

  // ---- phase path: block per (b,h) ----
  const int bh = blockIdx.x, b = bh >> 6, h = bh & 63;
  const size_t sbase = (size_t)bh * 1024;
  const int lane = tid & 63;
  float ld0, ld1;
  {
    int l0 = tid*2;
    #pragma unroll
    for (int q = 0; q < 2; q++){
      int l = l0 + q;
      size_t pb = (size_t)(b*1024 + l) * 8704;
      float dd_dt = bf2f(proj[pb + 8448 + h]);
      float dd_A  = bf2f(proj[pb + 8512 + h]);
      float trap  = bf2f(proj[pb + 8576 + h]);
      float DT  = softplusf(dd_dt + dtb[h]);
      float A   = -fmaxf(softplusf(dd_A), 1e-4f);
      float lam = 1.f / (1.f + expf(-trap));
      dtL[l] = DT; lamL[l] = lam;
      if (q == 0) ld0 = A*DT; else ld1 = A*DT;
      DTt[sbase+l] = DT; lamt[sbase+l] = lam;
    }
  }
  __syncthreads();
  {
    float p1 = ld0 + ld1;
    float tot = p1;
    float incl = tot;
    #pragma unroll
    for (int off = 1; off < 64; off <<= 1){
      float u = __shfl_up(incl, off, 64);
      if (lane >= off) incl += u;
    }
    float excl = incl - tot;
    int l0 = tid*2;
    clcb[sbase+l0]   = excl + ld0;
    clcb[sbase+l0+1] = excl + p1;
    #pragma unroll
    for (int q = 0; q < 2; q++){
      int l = l0 + q;
      int ln = (l == 1023) ? 1023 : l + 1;
      gb[sbase+l] = 1.f - lamL[l] + lamL[ln];
    }
  }
  int na = tid & 31, c = tid >> 5;
  float s = 0.f;
  for (int q = 0; q < 64; q++){
    int l = c*64 + q; int row = b*1024 + l;
    float ang = bf2f(proj[(size_t)row*8704 + 8640 + na]);
    s = fmaf(ang, dtL[l], s);
  }
  part[c][na] = s;
  __syncthreads();
  float off = 0.f;
  for (int cc = 0; cc < c; cc++) off += part[cc][na];
  float ph = off;
  for (int q = 0; q < 64; q++){
    int l = c*64 + q; int row = b*1024 + l;
    float ang = bf2f(proj[(size_t)row*8704 + 8640 + na]);
    ph = fmaf(ang, dtL[l], ph);
    float sn, cs;
    __sincosf(ph, &sn, &cs);
    size_t o = ((size_t)row*64 + h)*32 + na;
    cosb[o] = f2bf(cs); sinb[o] = f2bf(sn);
  }
}

// ---------- pass A: intra-chunk y + chunk state increment G (512 threads, 8 waves) ----------
__global__ __launch_bounds__(512, 1) void k_intra(
    const unsigned short* __restrict__ proj,
    const unsigned short* __restrict__ Bb2, const unsigned short* __restrict__ Cb2,
    const float* __restrict__ Bbias, const float* __restrict__ Cbias,
    const unsigned short* __restrict__ cosb, const unsigned short* __restrict__ sinb,
    const float* __restrict__ DTt, const float* __restrict__ clcb,
    const float* __restrict__ gb, const float* __restrict__ lamt,
    const float* __restrict__ Dv, unsigned short* __restrict__ ybf,
    unsigned short* __restrict__ Gbuf)
{
  const int c = blockIdx.x & 7, bh = blockIdx.x >> 3;
  const int b = bh >> 6, h = bh & 63;
  const int tid = threadIdx.x, lane = tid & 63, wave = tid >> 6;
  const int wr = wave >> 2, wc = wave & 3;
  const int fr = lane & 15, fq = lane >> 4;

  __shared__ __align__(16) unsigned short Cs[128*128];
  __shared__ __align__(16) unsigned short Bs[128*128];   // aliased as P after barrier
  __shared__ __align__(16) unsigned short BTs[128*128];
  __shared__ __align__(16) unsigned short Uts[64*128];   // U^T: [p][j]
  __shared__ float clcs[128], lams[128], gs[128], wUs[128], dts[128];
  __shared__ float biasB[128], biasC[128];

  const int base = b*1024 + c*128;
  const size_t shbase = (size_t)bh * 1024;
  const float Dh = Dv[h];

  // phase 0: scalars
  if (tid < 128){
    int l = c*128 + tid;
    clcs[tid] = clcb[shbase + l];
    dts[tid]  = DTt[shbase + l];
    lams[tid] = lamt[shbase + l];
    gs[tid]   = gb[shbase + l];
    biasB[tid] = Bbias[h*128 + tid];
  } else if (tid < 256){
    biasC[tid-128] = Cbias[h*128 + tid-128];
  }
  __syncthreads();
  if (tid < 128) wUs[tid] = __expf(clcs[127] - clcs[tid]) * gs[tid];

  // phase 1: stage C/B (bias+rope), B^T, U^T  — quarters per row t
  {
    const int t = tid >> 2, q = tid & 3;
    const int grow = base + t;
    const size_t roff = (size_t)grow*128;
    if (q == 0){
      bf16x8 cc[4], sv[4];
      #pragma unroll
      for (int j = 0; j < 4; j++){
        cc[j] = *(const bf16x8*)(cosb + ((size_t)grow*64 + h)*32 + j*8);
        sv[j] = *(const bf16x8*)(sinb + ((size_t)grow*64 + h)*32 + j*8);
      }
      #pragma unroll
      for (int j = 0; j < 4; j++){
        bf16x8 vlo = *(const bf16x8*)(Cb2 + roff + j*8);
        bf16x8 vhi = *(const bf16x8*)(Cb2 + roff + 32 + j*8);
        bf16x8 olo, ohi;
        #pragma unroll
        for (int e = 0; e < 8; e++){
          float a = bf2f((unsigned short)vlo[e]) + biasC[j*8+e];
          float d = bf2f((unsigned short)vhi[e]) + biasC[32+j*8+e];
          float cf = bf2f((unsigned short)cc[j][e]);
          float sf = bf2f((unsigned short)sv[j][e]);
          olo[e] = (short)f2bf(a*cf - d*sf);
          ohi[e] = (short)f2bf(a*sf + d*cf);
        }
        ldsw_write8(Cs, t, j*8, olo);
        ldsw_write8(Cs, t, 32 + j*8, ohi);
      }
    } else if (q == 1){
      #pragma unroll
      for (int j = 0; j < 8; j++){
        bf16x8 v = *(const bf16x8*)(Cb2 + roff + 64 + j*8);
        bf16x8 o;
        #pragma unroll
        for (int e = 0; e < 8; e++) o[e] = (short)f2bf(bf2f((unsigned short)v[e]) + biasC[64+j*8+e]);
        ldsw_write8(Cs, t, 64 + j*8, o);
      }
    } else if (q == 2){
      bf16x8 cc[4], sv[4];
      #pragma unroll
      for (int j = 0; j < 4; j++){
        cc[j] = *(const bf16x8*)(cosb + ((size_t)grow*64 + h)*32 + j*8);
        sv[j] = *(const bf16x8*)(sinb + ((size_t)grow*64 + h)*32 + j*8);
      }
      #pragma unroll
      for (int j = 0; j < 4; j++){
        bf16x8 vlo = *(const bf16x8*)(Bb2 + roff + j*8);
        bf16x8 vhi = *(const bf16x8*)(Bb2 + roff + 32 + j*8);
        bf16x8 olo, ohi;
        #pragma unroll
        for (int e = 0; e < 8; e++){
          float a = bf2f((unsigned short)vlo[e]) + biasB[j*8+e];
          float d = bf2f((unsigned short)vhi[e]) + biasB[32+j*8+e];
          float cf = bf2f((unsigned short)cc[j][e]);
          float sf = bf2f((unsigned short)sv[j][e]);
          olo[e] = (short)f2bf(a*cf - d*sf);
          ohi[e] = (short)f2bf(a*sf + d*cf);
        }
        ldsw_write8(Bs, t, j*8, olo);
        ldsw_write8(Bs, t, 32 + j*8, ohi);
        #pragma unroll
        for (int e = 0; e < 8; e++){
          ldsw_write1(BTs, j*8+e, t, (unsigned short)olo[e]);
          ldsw_write1(BTs, 32+j*8+e, t, (unsigned short)ohi[e]);
        }
      }
    } else {
      #pragma unroll
      for (int j = 0; j < 8; j++){
        bf16x8 v = *(const bf16x8*)(Bb2 + roff + 64 + j*8);
        bf16x8 o;
        #pragma unroll
        for (int e = 0; e < 8; e++) o[e] = (short)f2bf(bf2f((unsigned short)v[e]) + biasB[64+j*8+e]);
        ldsw_write8(Bs, t, 64 + j*8, o);
        #pragma unroll
        for (int e = 0; e < 8; e++) ldsw_write1(BTs, 64+j*8+e, t, (unsigned short)o[e]);
      }
    }
  }
  // U^T staging: 8 groups of 64 lanes, 16 j each
  {
    const int p = tid & 63, jg = tid >> 6;
    #pragma unroll 4
    for (int q = 0; q < 16; q++){
      int j = jg*16 + q;
      size_t pb = (size_t)(base + j) * 8704;
      float xx = bf2f(proj[pb + 4096 + h*64 + p]);
      ldsw_write1(Uts, p, j, f2bf(xx * dts[j]));
    }
  }
  __syncthreads();

  // MFMA1: scores[t][j] = C . B^T   (per wave: 64 t x 32 j)
  f32x4 acc1[4][2];
  #pragma unroll
  for (int mi = 0; mi < 4; mi++)
    #pragma unroll
    for (int ni = 0; ni < 2; ni++)
      acc1[mi][ni] = (f32x4){0.f,0.f,0.f,0.f};
  #pragma unroll
  for (int ks = 0; ks < 4; ks++){
    bf16x8 af[4], bj[2];
    #pragma unroll
    for (int mi = 0; mi < 4; mi++) af[mi] = ldsw_read8(Cs, wr*64+mi*16+fr, ks*32+fq*8);
    #pragma unroll
    for (int ni = 0; ni < 2; ni++) bj[ni] = ldsw_read8(Bs, wc*32+ni*16+fr, ks*32+fq*8);
    #pragma unroll
    for (int mi = 0; mi < 4; mi++)
      #pragma unroll
      for (int ni = 0; ni < 2; ni++)
        acc1[mi][ni] = __builtin_amdgcn_mfma_f32_16x16x32_bf16(af[mi], bj[ni], acc1[mi][ni], 0,0,0);
  }
  // weight epilogue: P = W o scores
  unsigned short pr[4][2][4];
  int jj[2]; float clcj[2], gj[2];
  #pragma unroll
  for (int ni = 0; ni < 2; ni++){ jj[ni] = wc*32+ni*16+fr; clcj[ni] = clcs[jj[ni]]; gj[ni] = gs[jj[ni]]; }
  #pragma unroll
  for (int mi = 0; mi < 4; mi++){
    #pragma unroll
    for (int r = 0; r < 4; r++){
      int t = wr*64+mi*16+fq*4+r;
      float ct_ = clcs[t], lt = lams[t];
      #pragma unroll
      for (int ni = 0; ni < 2; ni++){
        int j = jj[ni];
        float w = (j < t) ? __expf(ct_ - clcj[ni])*gj[ni] : ((j == t) ? (1.f - lt) : 0.f);
        pr[mi][ni][r] = f2bf(acc1[mi][ni][r] * w);
      }
    }
  }
  __syncthreads();                     // all MFMA1 reads of Bs complete
  #pragma unroll
  for (int mi = 0; mi < 4; mi++)
    #pragma unroll
    for (int ni = 0; ni < 2; ni++)
      #pragma unroll
      for (int r = 0; r < 4; r++)
        ldsw_write1(Bs, wr*64+mi*16+fq*4+r, wc*32+ni*16+fr, pr[mi][ni][r]);
  __syncthreads();

  // MFMA2: y_intra[t][p] = P . U   (per wave: 64 t x 16 p)
  f32x4 acc2[4];
  #pragma unroll
  for (int mi = 0; mi < 4; mi++) acc2[mi] = (f32x4){0.f,0.f,0.f,0.f};
  #pragma unroll
  for (int ks = 0; ks < 4; ks++){
    bf16x8 af[4], uj;
    #pragma unroll
    for (int mi = 0; mi < 4; mi++) af[mi] = ldsw_read8(Bs, wr*64+mi*16+fr, ks*32+fq*8);
    uj = ldsw_read8(Uts, wc*16+fr, ks*32+fq*8);
    #pragma unroll
    for (int mi = 0; mi < 4; mi++)
      acc2[mi] = __builtin_amdgcn_mfma_f32_16x16x32_bf16(af[mi], uj, acc2[mi], 0,0,0);
  }
  // MFMA4: G[p][n] = (wU o U) . B   (per wave: 32 p x 32 n)
  f32x4 accS[2][2];
  #pragma unroll
  for (int mi = 0; mi < 2; mi++)
    #pragma unroll
    for (int ni = 0; ni < 2; ni++)
      accS[mi][ni] = (f32x4){0.f,0.f,0.f,0.f};
  #pragma unroll
  for (int ks = 0; ks < 4; ks++){
    bf16x8 au[2], bn[2];
    #pragma unroll
    for (int mi = 0; mi < 2; mi++){
      bf16x8 raw = ldsw_read8(Uts, wr*32+mi*16+fr, ks*32+fq*8);
      #pragma unroll
      for (int e = 0; e < 8; e++){
        float f = bf2f((unsigned short)raw[e]) * wUs[ks*32+fq*8+e];
        au[mi][e] = (short)f2bf(f);
      }
    }
    #pragma unroll
    for (int ni = 0; ni < 2; ni++) bn[ni] = ldsw_read8(BTs, wc*32+ni*16+fr, ks*32+fq*8);
    #pragma unroll
    for (int mi = 0; mi < 2; mi++)
      #pragma unroll
      for (int ni = 0; ni < 2; ni++)
        accS[mi][ni] = __builtin_amdgcn_mfma_f32_16x16x32_bf16(au[mi], bn[ni], accS[mi][ni], 0,0,0);
  }

  // stores: y_intra + D*x (ungated) and G
  #pragma unroll
  for (int mi = 0; mi < 4; mi++){
    #pragma unroll
    for (int r = 0; r < 4; r++){
      int t = wr*64+mi*16+fq*4+r;
      int p = wc*16+fr;
      float xv = bf2f(ldsw_read1(Uts, p, t)) / fmaxf(dts[t], 1e-30f);
      float o = acc2[mi][r] + Dh*xv;
      ybf[(size_t)(base + t)*4096 + h*64 + p] = f2bf(o);
    }
  }
  #pragma unroll
  for (int mi = 0; mi < 2; mi++)
    #pragma unroll
    for (int ni = 0; ni < 2; ni++)
      #pragma unroll
      for (int r = 0; r < 4; r++){
        int p = wr*32+mi*16+fq*4+r;
        int n = wc*32+ni*16+fr;
        Gbuf[(size_t)blockIdx.x*8192 + p*128 + n] = f2bf(accS[mi][ni][r]);
      }
}

// ---------- pass B: scan over 8 chunks; Gbuf[c] <- S_prev(c), S = decEnd*S + G ----------
__global__ __launch_bounds__(256) void k_scanstate(
    const float* __restrict__ clcb, unsigned short* __restrict__ Gbuf)
{
  const int bh = blockIdx.x, tid = threadIdx.x;
  float S[32];
  #pragma unroll
  for (int q = 0; q < 32; q++) S[q] = 0.f;
  const size_t gbase = (size_t)bh*65536 + (size_t)tid*32;
  for (int c = 0; c < 8; c++){
    float decEnd = __expf(clcb[(size_t)bh*1024 + c*128 + 127]);
    unsigned short* p = Gbuf + gbase + (size_t)c*8192;
    bf16x8 g[4], s[4];
    #pragma unroll
    for (int q = 0; q < 4; q++) g[q] = *(const bf16x8*)(p + q*8);
    #pragma unroll
    for (int q = 0; q < 4; q++)
      #pragma unroll
      for (int e = 0; e < 8; e++) s[q][e] = (short)f2bf(S[q*8+e]);
    #pragma unroll
    for (int q = 0; q < 4; q++) *(bf16x8*)(p + q*8) = s[q];
    #pragma unroll
    for (int q = 0; q < 4; q++)
      #pragma unroll
      for (int e = 0; e < 8; e++)
        S[q*8+e] = decEnd*S[q*8+e] + bf2f((unsigned short)g[q][e]);
  }
}

// ---------- pass C: y = (y_intra + exp(clc_t) * C_t . S_prev^T) * silu(z) ----------
// hybrid: blocks >= 1024 convert wo f32->bf16 (small-ws path)
__global__ __launch_bounds__(256) void k_inter(
    const unsigned short* __restrict__ proj,
    const unsigned short* __restrict__ Cb2, const float* __restrict__ Cbias,
    const unsigned short* __restrict__ cosb, const unsigned short* __restrict__ sinb,
    const float* __restrict__ clcb, const unsigned short* __restrict__ Sprev,
    unsigned short* __restrict__ ybf,
    const float* __restrict__ wo, unsigned short* __restrict__ wobf)
{
  if (blockIdx.x >= 1024){
    long i = (((long)blockIdx.x - 1024) * 256 + threadIdx.x) * 4;
    float4 v = *(const float4*)(wo + i);
    *(unsigned long long*)(wobf + i) = pack4(v);
    return;
  }
  const int c = blockIdx.x & 7, bh = blockIdx.x >> 3;
  const int b = bh >> 6, h = bh & 63;
  const int tid = threadIdx.x, lane = tid & 63, wave = tid >> 6;
  const int wr = wave >> 1, wc = wave & 1;
  const int fr = lane & 15, fq = lane >> 4;

  __shared__ __align__(16) unsigned short Cs[128*128];
  __shared__ __align__(16) unsigned short Ss[64*128];
  __shared__ float expclcs[128], biasC[128];

  const int base = b*1024 + c*128;

  if (tid < 128){
    expclcs[tid] = __expf(clcb[(size_t)bh*1024 + c*128 + tid]);
    biasC[tid] = Cbias[h*128 + tid];
  }
  __syncthreads();

  // stage C (bias+rope)
  {
    const int t = tid >> 1, half = tid & 1;
    const int grow = base + t;
    const size_t roff = (size_t)grow*128 + half*64;
    if (half == 0){
      bf16x8 cc[4], sv[4];
      #pragma unroll
      for (int j = 0; j < 4; j++){
        cc[j] = *(const bf16x8*)(cosb + ((size_t)grow*64 + h)*32 + j*8);
        sv[j] = *(const bf16x8*)(sinb + ((size_t)grow*64 + h)*32 + j*8);
      }
      #pragma unroll
      for (int j = 0; j < 4; j++){
        bf16x8 vlo = *(const bf16x8*)(Cb2 + roff + j*8);
        bf16x8 vhi = *(const bf16x8*)(Cb2 + roff + 32 + j*8);
        bf16x8 olo, ohi;
        #pragma unroll
        for (int e = 0; e < 8; e++){
          float a = bf2f((unsigned short)vlo[e]) + biasC[j*8+e];
          float d = bf2f((unsigned short)vhi[e]) + biasC[32+j*8+e];
          float cf = bf2f((unsigned short)cc[j][e]);
          float sf = bf2f((unsigned short)sv[j][e]);
          olo[e] = (short)f2bf(a*cf - d*sf);
          ohi[e] = (short)f2bf(a*sf + d*cf);
        }
        ldsw_write8(Cs, t, j*8, olo);
        ldsw_write8(Cs, t, 32 + j*8, ohi);
      }
    } else {
      #pragma unroll
      for (int j = 0; j < 8; j++){
        bf16x8 v = *(const bf16x8*)(Cb2 + roff + j*8);
        bf16x8 o;
        #pragma unroll
        for (int e = 0; e < 8; e++) o[e] = (short)f2bf(bf2f((unsigned short)v[e]) + biasC[64+j*8+e]);
        ldsw_write8(Cs, t, 64 + j*8, o);
      }
    }
  }
  // stage S_prev (reg -> swizzled LDS)
  {
    const unsigned short* src = Sprev + (size_t)blockIdx.x*8192 + (size_t)tid*32;
    #pragma unroll
    for (int j = 0; j < 4; j++){
      bf16x8 v = *(const bf16x8*)(src + j*8);
      int f = tid*32 + j*8;
      ldsw_write8(Ss, f >> 7, f & 127, v);
    }
  }
  __syncthreads();

  // MFMA: Yinter[t][p] = C . S_prev^T
  f32x4 acc[4][2];
  #pragma unroll
  for (int mi = 0; mi < 4; mi++)
    #pragma unroll
    for (int ni = 0; ni < 2; ni++)
      acc[mi][ni] = (f32x4){0.f,0.f,0.f,0.f};
  #pragma unroll
  for (int ks = 0; ks < 4; ks++){
    bf16x8 af[4], sj[2];
    #pragma unroll
    for (int mi = 0; mi < 4; mi++) af[mi] = ldsw_read8(Cs, wr*64+mi*16+fr, ks*32+fq*8);
    #pragma unroll
    for (int ni = 0; ni < 2; ni++) sj[ni] = ldsw_read8(Ss, wc*32+ni*16+fr, ks*32+fq*8);
    #pragma unroll
    for (int mi = 0; mi < 4; mi++)
      #pragma unroll
      for (int ni = 0; ni < 2; ni++)
        acc[mi][ni] = __builtin_amdgcn_mfma_f32_16x16x32_bf16(af[mi], sj[ni], acc[mi][ni], 0,0,0);
  }

  // epilogue: y = (y_intra + expclc*Yinter) * silu(z)
  #pragma unroll
  for (int mi = 0; mi < 4; mi++){
    #pragma unroll
    for (int ni = 0; ni < 2; ni++){
      #pragma unroll
      for (int r = 0; r < 4; r++){
        int t = wr*64+mi*16+fq*4+r;
        int p = wc*32+ni*16+fr;
        size_t yoff = (size_t)(base + t)*4096 + h*64 + p;
        float y = bf2f(ybf[yoff]) + expclcs[t]*acc[mi][ni][r];
        float zv = bf2f(proj[(size_t)(base + t)*8704 + h*64 + p]);
        float sl = zv / (1.f + __expf(-zv));
        ybf[yoff] = f2bf(y * sl);
      }
    }
  }
}

// ---------- launch ----------
extern "C" void kernel_launch(void* const* d_in, const int* in_sizes, int n_in,
                              void* d_out, int out_size, void* d_ws, size_t ws_size,
                              hipStream_t stream)
{
  const float* hs    = (const float*)d_in[0];
  const float* w1    = (const float*)d_in[1];
  const float* dtb   = (const float*)d_in[2];
  const float* Bbias = (const float*)d_in[3];
  const float* Cbias = (const float*)d_in[4];
  const float* Bw    = (const float*)d_in[5];
  const float* Cw    = (const float*)d_in[6];
  const float* Dv    = (const float*)d_in[7];
  const float* wo    = (const float*)d_in[8];
  float* out = (float*)d_out;
  char* ws = (char*)d_ws;

  unsigned short* projbf = (unsigned short*)(ws + 0UL);
  unsigned short* W1bf   = (unsigned short*)(ws + 35651584UL);
  unsigned short* Gbuf   = W1bf;                                  // post-GEMM1
  unsigned short* ybf    = (unsigned short*)(ws + 52428800UL);
  unsigned short* hsbf   = (unsigned short*)(ws + 71172096UL);
  unsigned short* cosb   = hsbf;                                  // post-GEMM1
  unsigned short* sinb   = (unsigned short*)(ws + 79560704UL);
  float* DTt    = (float*)(ws + 87949312UL);
  float* lamt   = (float*)(ws + 88997888UL);
  float* clcb   = (float*)(ws + 89522176UL);
  float* gb     = (float*)(ws + 90046464UL);
  unsigned short* Bb2 = (unsigned short*)(ws + 90570752UL);
  unsigned short* Cb2 = (unsigned short*)(ws + 91095040UL);
  if (ws_size < 91619328UL) return;

  // optional dedicated Wo region: convert early, skip the late conversion
  const bool bigws = (ws_size >= 91619328UL + 16777216UL);
  unsigned short* Wobf = bigws ? (unsigned short*)(ws + 91619328UL) : W1bf;

  (void)in_sizes; (void)n_in; (void)out_size;

  // conversions (2048 elems/block): w1 (8672) + hs (2048) [+ wo (4096) if bigws]
  k_conv3<<<bigws ? 14816 : 10720, 256, 0, stream>>>(
      w1, W1bf, 8672, hs, hsbf, 2048, wo, Wobf);
  // GEMM1: tiles 16x68 @128x128; XCD partition 2x4 -> per-XCD 8rt x 17ct
  k_gemm_bt<true, 128><<<1088, 256, 0, stream>>>(hsbf, W1bf, projbf, 2048, 8672, 8704, 2, 8, 17);
  // merged prep: 128 phase blocks + 512 rmsnorm blocks (512 threads)
  k_prep<<<640, 512, 0, stream>>>(projbf, Bw, Cw, dtb, Bb2, Cb2,
                                  DTt, lamt, clcb, gb, cosb, sinb);
  k_intra<<<1024, 512, 0, stream>>>(projbf, Bb2, Cb2, Bbias, Cbias,
                                    cosb, sinb, DTt, clcb, gb, lamt, Dv, ybf, Gbuf);
  k_scanstate<<<128, 256, 0, stream>>>(clcb, Gbuf);
  // pass C; small-ws path also converts wo in trailing blocks
  k_inter<<<bigws ? 1024 : 9216, 256, 0, stream>>>(
      projbf, Cb2, Cbias, cosb, sinb, clcb, Gbuf, ybf, wo, Wobf);
  // GEMM2: tiles 16x32 @128x64 (512 blocks = 2/CU); XCD partition 4x2 -> per-XCD 4rt x 16ct
  k_gemm_bt<false, 64><<<512, 256, 0, stream>>>(ybf, Wobf, out, 4096, 2048, 2048, 4, 4, 16);
}

// Round 14
// 298.518 us; speedup vs baseline: 1.1144x; 1.0388x over previous
//
#include <hip/hip_runtime.h>
#include <hip/hip_bf16.h>
#include <cstdint>
#include <cstddef>

#define DEVINL __device__ __forceinline__

typedef __attribute__((ext_vector_type(8))) short bf16x8;
typedef __attribute__((ext_vector_type(4))) float f32x4;

// ---------- helpers ----------
DEVINL float bf2f(unsigned short u){
  union { unsigned u32; float f; } cv; cv.u32 = ((unsigned)u) << 16; return cv.f;
}
DEVINL unsigned short f2bf(float f){
  union { float f; unsigned u32; } cv; cv.f = f;
  unsigned u = cv.u32;
  return (unsigned short)((u + 0x7FFFu + ((u >> 16) & 1u)) >> 16);  // RNE
}
DEVINL float softplusf(float x){ return x > 20.f ? x : log1pf(expf(x)); }

DEVINL void g2l16(const void* gptr, void* ldsptr){
  __builtin_amdgcn_global_load_lds(
      (const __attribute__((address_space(1))) unsigned int*)gptr,
      (__attribute__((address_space(3))) unsigned int*)(uintptr_t)ldsptr,
      16, 0, 0);
}

// swizzled LDS access for 256-byte-row tiles (128 bf16 cols)
DEVINL int swzb(int row, int col){ return row*256 + ((col*2) ^ ((row&7)<<4)); }
DEVINL void ldsw_write8(unsigned short* b, int row, int col, bf16x8 v){
  *(bf16x8*)((char*)b + swzb(row,col)) = v;
}
DEVINL bf16x8 ldsw_read8(const unsigned short* b, int row, int col){
  return *(const bf16x8*)((const char*)b + swzb(row,col));
}
DEVINL void ldsw_write1(unsigned short* b, int row, int col, unsigned short v){
  *(unsigned short*)((char*)b + swzb(row,col)) = v;
}
DEVINL unsigned short ldsw_read1(const unsigned short* b, int row, int col){
  return *(const unsigned short*)((const char*)b + swzb(row,col));
}

DEVINL unsigned long long pack4(float4 v){
  return (unsigned long long)f2bf(v.x)
       | ((unsigned long long)f2bf(v.y) << 16)
       | ((unsigned long long)f2bf(v.z) << 32)
       | ((unsigned long long)f2bf(v.w) << 48);
}

// ---------- fused f32 -> bf16 conversion of up to three buffers (32B/thread) ----------
__global__ __launch_bounds__(256) void k_conv3(
    const float* __restrict__ a, unsigned short* __restrict__ oa, int nba,
    const float* __restrict__ b, unsigned short* __restrict__ ob, int nbb,
    const float* __restrict__ c, unsigned short* __restrict__ oc)
{
  const float* in; unsigned short* out; long blk;
  if ((int)blockIdx.x < nba)            { in = a; out = oa; blk = blockIdx.x; }
  else if ((int)blockIdx.x < nba + nbb) { in = b; out = ob; blk = blockIdx.x - nba; }
  else                                  { in = c; out = oc; blk = blockIdx.x - nba - nbb; }
  long i = (blk * 256 + threadIdx.x) * 8;
  float4 v0 = *(const float4*)(in + i);
  float4 v1 = *(const float4*)(in + i + 4);
  unsigned long long pk[2] = { pack4(v0), pack4(v1) };
  *(bf16x8*)(out + i) = *(const bf16x8*)pk;
}

// ---------- bf16 GEMM, both operands K-major, C = A * Bt^T ----------
template<bool OUT_BF16, int BN>
__global__ __launch_bounds__(256) void k_gemm_bt(
    const unsigned short* __restrict__ A,
    const unsigned short* __restrict__ Bt,
    void* __restrict__ Cout,
    int K, int Nrows, int Npad, int xm, int tmx, int tnx)
{
  constexpr int NB = BN / 32;
  __shared__ unsigned short Asub[128*64];
  __shared__ unsigned short Bsub[BN*64];
  const int tid = threadIdx.x;
  const int x = blockIdx.x & 7, i = blockIdx.x >> 3;
  const int rt = (x % xm) * tmx + (i % tmx);
  const int ct = (x / xm) * tnx + (i / tmx);
  const int lane = tid & 63, wave = tid >> 6;
  const int wr = wave >> 1, wc = wave & 1;
  const int fr = lane & 15;
  const int fq = lane >> 4;

  const int srow0 = tid >> 3;
  const int sgrp  = (tid & 7) ^ ((tid >> 3) & 7);
  size_t aoff[4], boff[NB];
  #pragma unroll
  for (int j = 0; j < 4; j++){
    int row = j*32 + srow0;
    aoff[j] = (size_t)(rt*128 + row) * K + sgrp*8;
  }
  #pragma unroll
  for (int j = 0; j < NB; j++){
    int row = j*32 + srow0;
    int brow = ct*BN + row; if (brow > Nrows-1) brow = Nrows-1;
    boff[j] = (size_t)brow * K + sgrp*8;
  }

  f32x4 acc[4][NB] = {};

  for (int k0 = 0; k0 < K; k0 += 64){
    #pragma unroll
    for (int j = 0; j < 4; j++)
      g2l16(A + aoff[j] + k0, (char*)Asub + (j*256 + tid)*16);
    #pragma unroll
    for (int j = 0; j < NB; j++)
      g2l16(Bt + boff[j] + k0, (char*)Bsub + (j*256 + tid)*16);
    asm volatile("s_waitcnt vmcnt(0)" ::: "memory");
    __syncthreads();

    #pragma unroll
    for (int kk = 0; kk < 2; kk++){
      bf16x8 af[4], bfr[NB];
      const int slot = (kk*4 + fq) ^ (fr & 7);
      #pragma unroll
      for (int j = 0; j < 4; j++){
        int ra = wr*64 + j*16 + fr;
        af[j] = *(const bf16x8*)((const char*)Asub + ra*128 + slot*16);
      }
      #pragma unroll
      for (int j = 0; j < NB; j++){
        int rb = wc*(BN/2) + j*16 + fr;
        bfr[j] = *(const bf16x8*)((const char*)Bsub + rb*128 + slot*16);
      }
      #pragma unroll
      for (int mi = 0; mi < 4; mi++)
        #pragma unroll
        for (int ni = 0; ni < NB; ni++)
          acc[mi][ni] = __builtin_amdgcn_mfma_f32_16x16x32_bf16(af[mi], bfr[ni], acc[mi][ni], 0, 0, 0);
    }
    __syncthreads();
  }

  const int er = (lane >> 4) * 4;
  const int ec = lane & 15;
  #pragma unroll
  for (int mi = 0; mi < 4; mi++){
    #pragma unroll
    for (int ni = 0; ni < NB; ni++){
      const int row = rt*128 + wr*64 + mi*16 + er;
      const int col = ct*BN + wc*(BN/2) + ni*16 + ec;
      #pragma unroll
      for (int r = 0; r < 4; r++){
        if (OUT_BF16)
          ((unsigned short*)Cout)[(size_t)(row+r)*Npad + col] = f2bf(acc[mi][ni][r]);
        else
          ((float*)Cout)[(size_t)(row+r)*Npad + col] = acc[mi][ni][r];
      }
    }
  }
}

// ---------- GEMM2 split-K=2: 1024 blocks; half 0 -> out, half 1 -> part ----------
// M=N=2048, K=4096, 128x64 tiles (16x32), per-half XCD partition 4x2 (4rt x 16ct).
__global__ __launch_bounds__(256) void k_gemm2sk(
    const unsigned short* __restrict__ A,
    const unsigned short* __restrict__ Bt,
    float* __restrict__ out, float* __restrict__ part)
{
  constexpr int K = 4096, BN = 64, NB = 2;
  __shared__ unsigned short Asub[128*64];
  __shared__ unsigned short Bsub[BN*64];
  const int tid = threadIdx.x;
  const int half = (int)(blockIdx.x >> 9);
  const int bid  = (int)(blockIdx.x & 511);
  const int kbeg = half * 2048;
  float* dst = half ? part : out;
  const int x = bid & 7, i = bid >> 3;
  const int rt = (x % 4) * 4 + (i % 4);
  const int ct = (x / 4) * 16 + (i / 4);
  const int lane = tid & 63, wave = tid >> 6;
  const int wr = wave >> 1, wc = wave & 1;
  const int fr = lane & 15;
  const int fq = lane >> 4;

  const int srow0 = tid >> 3;
  const int sgrp  = (tid & 7) ^ ((tid >> 3) & 7);
  size_t aoff[4], boff[NB];
  #pragma unroll
  for (int j = 0; j < 4; j++){
    int row = j*32 + srow0;
    aoff[j] = (size_t)(rt*128 + row) * K + sgrp*8;
  }
  #pragma unroll
  for (int j = 0; j < NB; j++){
    int row = j*32 + srow0;
    boff[j] = (size_t)(ct*BN + row) * K + sgrp*8;
  }

  f32x4 acc[4][NB] = {};

  for (int k0 = kbeg; k0 < kbeg + 2048; k0 += 64){
    #pragma unroll
    for (int j = 0; j < 4; j++)
      g2l16(A + aoff[j] + k0, (char*)Asub + (j*256 + tid)*16);
    #pragma unroll
    for (int j = 0; j < NB; j++)
      g2l16(Bt + boff[j] + k0, (char*)Bsub + (j*256 + tid)*16);
    asm volatile("s_waitcnt vmcnt(0)" ::: "memory");
    __syncthreads();

    #pragma unroll
    for (int kk = 0; kk < 2; kk++){
      bf16x8 af[4], bfr[NB];
      const int slot = (kk*4 + fq) ^ (fr & 7);
      #pragma unroll
      for (int j = 0; j < 4; j++){
        int ra = wr*64 + j*16 + fr;
        af[j] = *(const bf16x8*)((const char*)Asub + ra*128 + slot*16);
      }
      #pragma unroll
      for (int j = 0; j < NB; j++){
        int rb = wc*(BN/2) + j*16 + fr;
        bfr[j] = *(const bf16x8*)((const char*)Bsub + rb*128 + slot*16);
      }
      #pragma unroll
      for (int mi = 0; mi < 4; mi++)
        #pragma unroll
        for (int ni = 0; ni < NB; ni++)
          acc[mi][ni] = __builtin_amdgcn_mfma_f32_16x16x32_bf16(af[mi], bfr[ni], acc[mi][ni], 0, 0, 0);
    }
    __syncthreads();
  }

  const int er = (lane >> 4) * 4;
  const int ec = lane & 15;
  #pragma unroll
  for (int mi = 0; mi < 4; mi++){
    #pragma unroll
    for (int ni = 0; ni < NB; ni++){
      const int row = rt*128 + wr*64 + mi*16 + er;
      const int col = ct*BN + wc*(BN/2) + ni*16 + ec;
      #pragma unroll
      for (int r = 0; r < 4; r++)
        dst[(size_t)(row+r)*2048 + col] = acc[mi][ni][r];
    }
  }
}

// ---------- out += part (float4) ----------
__global__ __launch_bounds__(256) void k_addout(
    float* __restrict__ out, const float* __restrict__ part)
{
  long i = ((long)blockIdx.x*256 + threadIdx.x) * 4;
  float4 a = *(const float4*)(out + i);
  float4 b = *(const float4*)(part + i);
  a.x += b.x; a.y += b.y; a.z += b.z; a.w += b.w;
  *(float4*)(out + i) = a;
}

// ---------- merged prep (512 threads): phase pipeline (blocks 0..127) + rmsnorm (128..639) ----------
__global__ __launch_bounds__(512) void k_prep(
    const unsigned short* __restrict__ proj, const float* __restrict__ Bw,
    const float* __restrict__ Cw, const float* __restrict__ dtb,
    unsigned short* __restrict__ Bb2, unsigned short* __restrict__ Cb2,
    float* __restrict__ DTt, float* __restrict__ lamt,
    float* __restrict__ clcb, float* __restrict__ gb,
    unsigned short* __restrict__ cosb, unsigned short* __restrict__ sinb)
{
  const int tid = threadIdx.x;
  __shared__ float dtL[1024], lamL[1024];
  __shared__ float part[16][32];
  __shared__ float red[16];

  if (blockIdx.x >= 128){
    int row = (int)(blockIdx.x - 128)*4 + (tid >> 7);
    int n = tid & 127;
    size_t base = (size_t)row * 8704;
    float bv = bf2f(proj[base + 8192 + n]);
    float cv = bf2f(proj[base + 8320 + n]);
    float sb = bv*bv, sc = cv*cv;
    #pragma unroll
    for (int m = 1; m < 64; m <<= 1){ sb += __shfl_xor(sb, m, 64); sc += __shfl_xor(sc, m, 64); }
    int w = tid >> 6;
    if ((tid & 63) == 0){ red[w*2] = sb; red[w*2+1] = sc; }
    __syncthreads();
    int rw = (tid >> 7) * 2;
    sb = red[rw*2]   + red[rw*2+2];
    sc = red[rw*2+1] + red[rw*2+3];
    float rb = rsqrtf(sb*(1.f/128.f) + 1e-5f);
    float rc = rsqrtf(sc*(1.f/128.f) + 1e-5f);
    Bb2[row*128 + n] = f2bf(bv*rb*Bw[n]);
    Cb2[row*128 + n] = f2bf(cv*rc*Cw[n]);
    return;
  }

  const int bh = blockIdx.x, b = bh >> 6, h = bh & 63;
  const size_t sbase = (size_t)bh * 1024;
  const int lane = tid & 63;
  float ld0, ld1;
  {
    int l0 = tid*2;
    #pragma unroll
    for (int q = 0; q < 2; q++){
      int l = l0 + q;
      size_t pb = (size_t)(b*1024 + l) * 8704;
      float dd_dt = bf2f(proj[pb + 8448 + h]);
      float dd_A  = bf2f(proj[pb + 8512 + h]);
      float trap  = bf2f(proj[pb + 8576 + h]);
      float DT  = softplusf(dd_dt + dtb[h]);
      float A   = -fmaxf(softplusf(dd_A), 1e-4f);
      float lam = 1.f / (1.f + expf(-trap));
      dtL[l] = DT; lamL[l] = lam;
      if (q == 0) ld0 = A*DT; else ld1 = A*DT;
      DTt[sbase+l] = DT; lamt[sbase+l] = lam;
    }
  }
  __syncthreads();
  {
    float p1 = ld0 + ld1;
    float tot = p1;
    float incl = tot;
    #pragma unroll
    for (int off = 1; off < 64; off <<= 1){
      float u = __shfl_up(incl, off, 64);
      if (lane >= off) incl += u;
    }
    float excl = incl - tot;
    int l0 = tid*2;
    clcb[sbase+l0]   = excl + ld0;
    clcb[sbase+l0+1] = excl + p1;
    #pragma unroll
    for (int q = 0; q < 2; q++){
      int l = l0 + q;
      int ln = (l == 1023) ? 1023 : l + 1;
      gb[sbase+l] = 1.f - lamL[l] + lamL[ln];
    }
  }
  int na = tid & 31, c = tid >> 5;
  float s = 0.f;
  for (int q = 0; q < 64; q++){
    int l = c*64 + q; int row = b*1024 + l;
    float ang = bf2f(proj[(size_t)row*8704 + 8640 + na]);
    s = fmaf(ang, dtL[l], s);
  }
  part[c][na] = s;
  __syncthreads();
  float off = 0.f;
  for (int cc = 0; cc < c; cc++) off += part[cc][na];
  float ph = off;
  for (int q = 0; q < 64; q++){
    int l = c*64 + q; int row = b*1024 + l;
    float ang = bf2f(proj[(size_t)row*8704 + 8640 + na]);
    ph = fmaf(ang, dtL[l], ph);
    float sn, cs;
    __sincosf(ph, &sn, &cs);
    size_t o = ((size_t)row*64 + h)*32 + na;
    cosb[o] = f2bf(cs); sinb[o] = f2bf(sn);
  }
}

// ---------- pass A: intra-chunk y + chunk state increment G (512 threads, 8 waves) ----------
__global__ __launch_bounds__(512, 1) void k_intra(
    const unsigned short* __restrict__ proj,
    const unsigned short* __restrict__ Bb2, const unsigned short* __restrict__ Cb2,
    const float* __restrict__ Bbias, const float* __restrict__ Cbias,
    const unsigned short* __restrict__ cosb, const unsigned short* __restrict__ sinb,
    const float* __restrict__ DTt, const float* __restrict__ clcb,
    const float* __restrict__ gb, const float* __restrict__ lamt,
    const float* __restrict__ Dv, unsigned short* __restrict__ ybf,
    unsigned short* __restrict__ Gbuf)
{
  const int c = blockIdx.x & 7, bh = blockIdx.x >> 3;
  const int b = bh >> 6, h = bh & 63;
  const int tid = threadIdx.x, lane = tid & 63, wave = tid >> 6;
  const int wr = wave >> 2, wc = wave & 3;
  const int fr = lane & 15, fq = lane >> 4;

  __shared__ __align__(16) unsigned short Cs[128*128];
  __shared__ __align__(16) unsigned short Bs[128*128];   // aliased as P after barrier
  __shared__ __align__(16) unsigned short BTs[128*128];
  __shared__ __align__(16) unsigned short Uts[64*128];   // U^T: [p][j]
  __shared__ float clcs[128], lams[128], gs[128], wUs[128], dts[128];
  __shared__ float biasB[128], biasC[128];

  const int base = b*1024 + c*128;
  const size_t shbase = (size_t)bh * 1024;
  const float Dh = Dv[h];

  // phase 0: scalars
  if (tid < 128){
    int l = c*128 + tid;
    clcs[tid] = clcb[shbase + l];
    dts[tid]  = DTt[shbase + l];
    lams[tid] = lamt[shbase + l];
    gs[tid]   = gb[shbase + l];
    biasB[tid] = Bbias[h*128 + tid];
  } else if (tid < 256){
    biasC[tid-128] = Cbias[h*128 + tid-128];
  }
  __syncthreads();
  if (tid < 128) wUs[tid] = __expf(clcs[127] - clcs[tid]) * gs[tid];

  // phase 1: stage C/B (bias+rope), B^T, U^T  — quarters per row t
  {
    const int t = tid >> 2, q = tid & 3;
    const int grow = base + t;
    const size_t roff = (size_t)grow*128;
    if (q == 0){
      bf16x8 cc[4], sv[4];
      #pragma unroll
      for (int j = 0; j < 4; j++){
        cc[j] = *(const bf16x8*)(cosb + ((size_t)grow*64 + h)*32 + j*8);
        sv[j] = *(const bf16x8*)(sinb + ((size_t)grow*64 + h)*32 + j*8);
      }
      #pragma unroll
      for (int j = 0; j < 4; j++){
        bf16x8 vlo = *(const bf16x8*)(Cb2 + roff + j*8);
        bf16x8 vhi = *(const bf16x8*)(Cb2 + roff + 32 + j*8);
        bf16x8 olo, ohi;
        #pragma unroll
        for (int e = 0; e < 8; e++){
          float a = bf2f((unsigned short)vlo[e]) + biasC[j*8+e];
          float d = bf2f((unsigned short)vhi[e]) + biasC[32+j*8+e];
          float cf = bf2f((unsigned short)cc[j][e]);
          float sf = bf2f((unsigned short)sv[j][e]);
          olo[e] = (short)f2bf(a*cf - d*sf);
          ohi[e] = (short)f2bf(a*sf + d*cf);
        }
        ldsw_write8(Cs, t, j*8, olo);
        ldsw_write8(Cs, t, 32 + j*8, ohi);
      }
    } else if (q == 1){
      #pragma unroll
      for (int j = 0; j < 8; j++){
        bf16x8 v = *(const bf16x8*)(Cb2 + roff + 64 + j*8);
        bf16x8 o;
        #pragma unroll
        for (int e = 0; e < 8; e++) o[e] = (short)f2bf(bf2f((unsigned short)v[e]) + biasC[64+j*8+e]);
        ldsw_write8(Cs, t, 64 + j*8, o);
      }
    } else if (q == 2){
      bf16x8 cc[4], sv[4];
      #pragma unroll
      for (int j = 0; j < 4; j++){
        cc[j] = *(const bf16x8*)(cosb + ((size_t)grow*64 + h)*32 + j*8);
        sv[j] = *(const bf16x8*)(sinb + ((size_t)grow*64 + h)*32 + j*8);
      }
      #pragma unroll
      for (int j = 0; j < 4; j++){
        bf16x8 vlo = *(const bf16x8*)(Bb2 + roff + j*8);
        bf16x8 vhi = *(const bf16x8*)(Bb2 + roff + 32 + j*8);
        bf16x8 olo, ohi;
        #pragma unroll
        for (int e = 0; e < 8; e++){
          float a = bf2f((unsigned short)vlo[e]) + biasB[j*8+e];
          float d = bf2f((unsigned short)vhi[e]) + biasB[32+j*8+e];
          float cf = bf2f((unsigned short)cc[j][e]);
          float sf = bf2f((unsigned short)sv[j][e]);
          olo[e] = (short)f2bf(a*cf - d*sf);
          ohi[e] = (short)f2bf(a*sf + d*cf);
        }
        ldsw_write8(Bs, t, j*8, olo);
        ldsw_write8(Bs, t, 32 + j*8, ohi);
        #pragma unroll
        for (int e = 0; e < 8; e++){
          ldsw_write1(BTs, j*8+e, t, (unsigned short)olo[e]);
          ldsw_write1(BTs, 32+j*8+e, t, (unsigned short)ohi[e]);
        }
      }
    } else {
      #pragma unroll
      for (int j = 0; j < 8; j++){
        bf16x8 v = *(const bf16x8*)(Bb2 + roff + 64 + j*8);
        bf16x8 o;
        #pragma unroll
        for (int e = 0; e < 8; e++) o[e] = (short)f2bf(bf2f((unsigned short)v[e]) + biasB[64+j*8+e]);
        ldsw_write8(Bs, t, 64 + j*8, o);
        #pragma unroll
        for (int e = 0; e < 8; e++) ldsw_write1(BTs, 64+j*8+e, t, (unsigned short)o[e]);
      }
    }
  }
  // U^T staging: vectorized — thread handles (j = q*64 + tid>>3, p0 = (tid&7)*8)
  {
    const int jr = tid >> 3;
    const int p0 = (tid & 7) * 8;
    #pragma unroll
    for (int q = 0; q < 2; q++){
      int j = q*64 + jr;
      size_t pb = (size_t)(base + j) * 8704;
      bf16x8 v = *(const bf16x8*)(proj + pb + 4096 + h*64 + p0);
      float dj = dts[j];
      #pragma unroll
      for (int e = 0; e < 8; e++)
        ldsw_write1(Uts, p0+e, j, f2bf(bf2f((unsigned short)v[e]) * dj));
    }
  }
  __syncthreads();

  // MFMA1: scores[t][j] = C . B^T   (per wave: 64 t x 32 j)
  f32x4 acc1[4][2];
  #pragma unroll
  for (int mi = 0; mi < 4; mi++)
    #pragma unroll
    for (int ni = 0; ni < 2; ni++)
      acc1[mi][ni] = (f32x4){0.f,0.f,0.f,0.f};
  #pragma unroll
  for (int ks = 0; ks < 4; ks++){
    bf16x8 af[4], bj[2];
    #pragma unroll
    for (int mi = 0; mi < 4; mi++) af[mi] = ldsw_read8(Cs, wr*64+mi*16+fr, ks*32+fq*8);
    #pragma unroll
    for (int ni = 0; ni < 2; ni++) bj[ni] = ldsw_read8(Bs, wc*32+ni*16+fr, ks*32+fq*8);
    #pragma unroll
    for (int mi = 0; mi < 4; mi++)
      #pragma unroll
      for (int ni = 0; ni < 2; ni++)
        acc1[mi][ni] = __builtin_amdgcn_mfma_f32_16x16x32_bf16(af[mi], bj[ni], acc1[mi][ni], 0,0,0);
  }
  // weight epilogue: P = W o scores
  unsigned short pr[4][2][4];
  int jj[2]; float clcj[2], gj[2];
  #pragma unroll
  for (int ni = 0; ni < 2; ni++){ jj[ni] = wc*32+ni*16+fr; clcj[ni] = clcs[jj[ni]]; gj[ni] = gs[jj[ni]]; }
  #pragma unroll
  for (int mi = 0; mi < 4; mi++){
    #pragma unroll
    for (int r = 0; r < 4; r++){
      int t = wr*64+mi*16+fq*4+r;
      float ct_ = clcs[t], lt = lams[t];
      #pragma unroll
      for (int ni = 0; ni < 2; ni++){
        int j = jj[ni];
        float w = (j < t) ? __expf(ct_ - clcj[ni])*gj[ni] : ((j == t) ? (1.f - lt) : 0.f);
        pr[mi][ni][r] = f2bf(acc1[mi][ni][r] * w);
      }
    }
  }
  __syncthreads();                     // all MFMA1 reads of Bs complete
  #pragma unroll
  for (int mi = 0; mi < 4; mi++)
    #pragma unroll
    for (int ni = 0; ni < 2; ni++)
      #pragma unroll
      for (int r = 0; r < 4; r++)
        ldsw_write1(Bs, wr*64+mi*16+fq*4+r, wc*32+ni*16+fr, pr[mi][ni][r]);
  __syncthreads();

  // MFMA2: y_intra[t][p] = P . U   (per wave: 64 t x 16 p)
  f32x4 acc2[4];
  #pragma unroll
  for (int mi = 0; mi < 4; mi++) acc2[mi] = (f32x4){0.f,0.f,0.f,0.f};
  #pragma unroll
  for (int ks = 0; ks < 4; ks++){
    bf16x8 af[4], uj;
    #pragma unroll
    for (int mi = 0; mi < 4; mi++) af[mi] = ldsw_read8(Bs, wr*64+mi*16+fr, ks*32+fq*8);
    uj = ldsw_read8(Uts, wc*16+fr, ks*32+fq*8);
    #pragma unroll
    for (int mi = 0; mi < 4; mi++)
      acc2[mi] = __builtin_amdgcn_mfma_f32_16x16x32_bf16(af[mi], uj, acc2[mi], 0,0,0);
  }
  // MFMA4: G[p][n] = (wU o U) . B   (per wave: 32 p x 32 n)
  f32x4 accS[2][2];
  #pragma unroll
  for (int mi = 0; mi < 2; mi++)
    #pragma unroll
    for (int ni = 0; ni < 2; ni++)
      accS[mi][ni] = (f32x4){0.f,0.f,0.f,0.f};
  #pragma unroll
  for (int ks = 0; ks < 4; ks++){
    bf16x8 au[2], bn[2];
    #pragma unroll
    for (int mi = 0; mi < 2; mi++){
      bf16x8 raw = ldsw_read8(Uts, wr*32+mi*16+fr, ks*32+fq*8);
      #pragma unroll
      for (int e = 0; e < 8; e++){
        float f = bf2f((unsigned short)raw[e]) * wUs[ks*32+fq*8+e];
        au[mi][e] = (short)f2bf(f);
      }
    }
    #pragma unroll
    for (int ni = 0; ni < 2; ni++) bn[ni] = ldsw_read8(BTs, wc*32+ni*16+fr, ks*32+fq*8);
    #pragma unroll
    for (int mi = 0; mi < 2; mi++)
      #pragma unroll
      for (int ni = 0; ni < 2; ni++)
        accS[mi][ni] = __builtin_amdgcn_mfma_f32_16x16x32_bf16(au[mi], bn[ni], accS[mi][ni], 0,0,0);
  }

  // stores: y_intra + D*x (ungated) and G
  #pragma unroll
  for (int mi = 0; mi < 4; mi++){
    #pragma unroll
    for (int r = 0; r < 4; r++){
      int t = wr*64+mi*16+fq*4+r;
      int p = wc*16+fr;
      float xv = bf2f(ldsw_read1(Uts, p, t)) / fmaxf(dts[t], 1e-30f);
      float o = acc2[mi][r] + Dh*xv;
      ybf[(size_t)(base + t)*4096 + h*64 + p] = f2bf(o);
    }
  }
  #pragma unroll
  for (int mi = 0; mi < 2; mi++)
    #pragma unroll
    for (int ni = 0; ni < 2; ni++)
      #pragma unroll
      for (int r = 0; r < 4; r++){
        int p = wr*32+mi*16+fq*4+r;
        int n = wc*32+ni*16+fr;
        Gbuf[(size_t)blockIdx.x*8192 + p*128 + n] = f2bf(accS[mi][ni][r]);
      }
}

// ---------- pass B: scan over 8 chunks; Gbuf[c] <- S_prev(c), S = decEnd*S + G ----------
__global__ __launch_bounds__(256) void k_scanstate(
    const float* __restrict__ clcb, unsigned short* __restrict__ Gbuf)
{
  const int bh = blockIdx.x, tid = threadIdx.x;
  float S[32];
  #pragma unroll
  for (int q = 0; q < 32; q++) S[q] = 0.f;
  const size_t gbase = (size_t)bh*65536 + (size_t)tid*32;
  for (int c = 0; c < 8; c++){
    float decEnd = __expf(clcb[(size_t)bh*1024 + c*128 + 127]);
    unsigned short* p = Gbuf + gbase + (size_t)c*8192;
    bf16x8 g[4], s[4];
    #pragma unroll
    for (int q = 0; q < 4; q++) g[q] = *(const bf16x8*)(p + q*8);
    #pragma unroll
    for (int q = 0; q < 4; q++)
      #pragma unroll
      for (int e = 0; e < 8; e++) s[q][e] = (short)f2bf(S[q*8+e]);
    #pragma unroll
    for (int q = 0; q < 4; q++) *(bf16x8*)(p + q*8) = s[q];
    #pragma unroll
    for (int q = 0; q < 4; q++)
      #pragma unroll
      for (int e = 0; e < 8; e++)
        S[q*8+e] = decEnd*S[q*8+e] + bf2f((unsigned short)g[q][e]);
  }
}

// ---------- pass C: y = (y_intra + exp(clc_t) * C_t . S_prev^T) * silu(z) ----------
// hybrid: blocks >= 1024 convert wo f32->bf16 (small-ws path)
__global__ __launch_bounds__(256) void k_inter(
    const unsigned short* __restrict__ proj,
    const unsigned short* __restrict__ Cb2, const float* __restrict__ Cbias,
    const unsigned short* __restrict__ cosb, const unsigned short* __restrict__ sinb,
    const float* __restrict__ clcb, const unsigned short* __restrict__ Sprev,
    unsigned short* __restrict__ ybf,
    const float* __restrict__ wo, unsigned short* __restrict__ wobf)
{
  if (blockIdx.x >= 1024){
    long i = (((long)blockIdx.x - 1024) * 256 + threadIdx.x) * 4;
    float4 v = *(const float4*)(wo + i);
    *(unsigned long long*)(wobf + i) = pack4(v);
    return;
  }
  const int c = blockIdx.x & 7, bh = blockIdx.x >> 3;
  const int b = bh >> 6, h = bh & 63;
  const int tid = threadIdx.x, lane = tid & 63, wave = tid >> 6;
  const int wr = wave >> 1, wc = wave & 1;
  const int fr = lane & 15, fq = lane >> 4;

  __shared__ __align__(16) unsigned short Cs[128*128];
  __shared__ __align__(16) unsigned short Ss[64*128];
  __shared__ float expclcs[128], biasC[128];

  const int base = b*1024 + c*128;

  if (tid < 128){
    expclcs[tid] = __expf(clcb[(size_t)bh*1024 + c*128 + tid]);
    biasC[tid] = Cbias[h*128 + tid];
  }
  __syncthreads();

  // stage C (bias+rope)
  {
    const int t = tid >> 1, half = tid & 1;
    const int grow = base + t;
    const size_t roff = (size_t)grow*128 + half*64;
    if (half == 0){
      bf16x8 cc[4], sv[4];
      #pragma unroll
      for (int j = 0; j < 4; j++){
        cc[j] = *(const bf16x8*)(cosb + ((size_t)grow*64 + h)*32 + j*8);
        sv[j] = *(const bf16x8*)(sinb + ((size_t)grow*64 + h)*32 + j*8);
      }
      #pragma unroll
      for (int j = 0; j < 4; j++){
        bf16x8 vlo = *(const bf16x8*)(Cb2 + roff + j*8);
        bf16x8 vhi = *(const bf16x8*)(Cb2 + roff + 32 + j*8);
        bf16x8 olo, ohi;
        #pragma unroll
        for (int e = 0; e < 8; e++){
          float a = bf2f((unsigned short)vlo[e]) + biasC[j*8+e];
          float d = bf2f((unsigned short)vhi[e]) + biasC[32+j*8+e];
          float cf = bf2f((unsigned short)cc[j][e]);
          float sf = bf2f((unsigned short)sv[j][e]);
          olo[e] = (short)f2bf(a*cf - d*sf);
          ohi[e] = (short)f2bf(a*sf + d*cf);
        }
        ldsw_write8(Cs, t, j*8, olo);
        ldsw_write8(Cs, t, 32 + j*8, ohi);
      }
    } else {
      #pragma unroll
      for (int j = 0; j < 8; j++){
        bf16x8 v = *(const bf16x8*)(Cb2 + roff + j*8);
        bf16x8 o;
        #pragma unroll
        for (int e = 0; e < 8; e++) o[e] = (short)f2bf(bf2f((unsigned short)v[e]) + biasC[64+j*8+e]);
        ldsw_write8(Cs, t, 64 + j*8, o);
      }
    }
  }
  // stage S_prev (reg -> swizzled LDS)
  {
    const unsigned short* src = Sprev + (size_t)blockIdx.x*8192 + (size_t)tid*32;
    #pragma unroll
    for (int j = 0; j < 4; j++){
      bf16x8 v = *(const bf16x8*)(src + j*8);
      int f = tid*32 + j*8;
      ldsw_write8(Ss, f >> 7, f & 127, v);
    }
  }
  __syncthreads();

  // MFMA: Yinter[t][p] = C . S_prev^T
  f32x4 acc[4][2];
  #pragma unroll
  for (int mi = 0; mi < 4; mi++)
    #pragma unroll
    for (int ni = 0; ni < 2; ni++)
      acc[mi][ni] = (f32x4){0.f,0.f,0.f,0.f};
  #pragma unroll
  for (int ks = 0; ks < 4; ks++){
    bf16x8 af[4], sj[2];
    #pragma unroll
    for (int mi = 0; mi < 4; mi++) af[mi] = ldsw_read8(Cs, wr*64+mi*16+fr, ks*32+fq*8);
    #pragma unroll
    for (int ni = 0; ni < 2; ni++) sj[ni] = ldsw_read8(Ss, wc*32+ni*16+fr, ks*32+fq*8);
    #pragma unroll
    for (int mi = 0; mi < 4; mi++)
      #pragma unroll
      for (int ni = 0; ni < 2; ni++)
        acc[mi][ni] = __builtin_amdgcn_mfma_f32_16x16x32_bf16(af[mi], sj[ni], acc[mi][ni], 0,0,0);
  }

  // epilogue: y = (y_intra + expclc*Yinter) * silu(z)
  #pragma unroll
  for (int mi = 0; mi < 4; mi++){
    #pragma unroll
    for (int ni = 0; ni < 2; ni++){
      #pragma unroll
      for (int r = 0; r < 4; r++){
        int t = wr*64+mi*16+fq*4+r;
        int p = wc*32+ni*16+fr;
        size_t yoff = (size_t)(base + t)*4096 + h*64 + p;
        float y = bf2f(ybf[yoff]) + expclcs[t]*acc[mi][ni][r];
        float zv = bf2f(proj[(size_t)(base + t)*8704 + h*64 + p]);
        float sl = zv / (1.f + __expf(-zv));
        ybf[yoff] = f2bf(y * sl);
      }
    }
  }
}

// ---------- launch ----------
extern "C" void kernel_launch(void* const* d_in, const int* in_sizes, int n_in,
                              void* d_out, int out_size, void* d_ws, size_t ws_size,
                              hipStream_t stream)
{
  const float* hs    = (const float*)d_in[0];
  const float* w1    = (const float*)d_in[1];
  const float* dtb   = (const float*)d_in[2];
  const float* Bbias = (const float*)d_in[3];
  const float* Cbias = (const float*)d_in[4];
  const float* Bw    = (const float*)d_in[5];
  const float* Cw    = (const float*)d_in[6];
  const float* Dv    = (const float*)d_in[7];
  const float* wo    = (const float*)d_in[8];
  float* out = (float*)d_out;
  char* ws = (char*)d_ws;

  unsigned short* projbf = (unsigned short*)(ws + 0UL);
  float* gemm2part       = (float*)(ws + 0UL);                    // post-k_inter (proj dead)
  unsigned short* W1bf   = (unsigned short*)(ws + 35651584UL);
  unsigned short* Gbuf   = W1bf;                                  // post-GEMM1
  unsigned short* ybf    = (unsigned short*)(ws + 52428800UL);
  unsigned short* hsbf   = (unsigned short*)(ws + 71172096UL);
  unsigned short* cosb   = hsbf;                                  // post-GEMM1
  unsigned short* sinb   = (unsigned short*)(ws + 79560704UL);
  float* DTt    = (float*)(ws + 87949312UL);
  float* lamt   = (float*)(ws + 88997888UL);
  float* clcb   = (float*)(ws + 89522176UL);
  float* gb     = (float*)(ws + 90046464UL);
  unsigned short* Bb2 = (unsigned short*)(ws + 90570752UL);
  unsigned short* Cb2 = (unsigned short*)(ws + 91095040UL);
  if (ws_size < 91619328UL) return;

  const bool bigws = (ws_size >= 91619328UL + 16777216UL);
  unsigned short* Wobf = bigws ? (unsigned short*)(ws + 91619328UL) : W1bf;

  (void)in_sizes; (void)n_in; (void)out_size;

  // conversions (2048 elems/block): w1 (8672) + hs (2048) [+ wo (4096) if bigws]
  k_conv3<<<bigws ? 14816 : 10720, 256, 0, stream>>>(
      w1, W1bf, 8672, hs, hsbf, 2048, wo, Wobf);
  // GEMM1: tiles 16x68 @128x128; XCD partition 2x4 -> per-XCD 8rt x 17ct
  k_gemm_bt<true, 128><<<1088, 256, 0, stream>>>(hsbf, W1bf, projbf, 2048, 8672, 8704, 2, 8, 17);
  // merged prep: 128 phase blocks + 512 rmsnorm blocks (512 threads)
  k_prep<<<640, 512, 0, stream>>>(projbf, Bw, Cw, dtb, Bb2, Cb2,
                                  DTt, lamt, clcb, gb, cosb, sinb);
  k_intra<<<1024, 512, 0, stream>>>(projbf, Bb2, Cb2, Bbias, Cbias,
                                    cosb, sinb, DTt, clcb, gb, lamt, Dv, ybf, Gbuf);
  k_scanstate<<<128, 256, 0, stream>>>(clcb, Gbuf);
  // pass C; small-ws path also converts wo in trailing blocks
  k_inter<<<bigws ? 1024 : 9216, 256, 0, stream>>>(
      projbf, Cb2, Cbias, cosb, sinb, clcb, Gbuf, ybf, wo, Wobf);
  // GEMM2 split-K=2: 1024 blocks (both halves co-resident), then out += partial
  k_gemm2sk<<<1024, 256, 0, stream>>>(ybf, Wobf, out, gemm2part);
  k_addout<<<4096, 256, 0, stream>>>(out, gemm2part);
}

// Round 15
// 298.465 us; speedup vs baseline: 1.1146x; 1.0002x over previous
//
#include <hip/hip_runtime.h>
#include <hip/hip_bf16.h>
#include <cstdint>
#include <cstddef>

#define DEVINL __device__ __forceinline__

typedef __attribute__((ext_vector_type(8))) short bf16x8;
typedef __attribute__((ext_vector_type(4))) float f32x4;

// ---------- helpers ----------
DEVINL float bf2f(unsigned short u){
  union { unsigned u32; float f; } cv; cv.u32 = ((unsigned)u) << 16; return cv.f;
}
DEVINL unsigned short f2bf(float f){
  union { float f; unsigned u32; } cv; cv.f = f;
  unsigned u = cv.u32;
  return (unsigned short)((u + 0x7FFFu + ((u >> 16) & 1u)) >> 16);  // RNE
}
DEVINL float softplusf(float x){ return x > 20.f ? x : log1pf(expf(x)); }

DEVINL void g2l16(const void* gptr, void* ldsptr){
  __builtin_amdgcn_global_load_lds(
      (const __attribute__((address_space(1))) unsigned int*)gptr,
      (__attribute__((address_space(3))) unsigned int*)(uintptr_t)ldsptr,
      16, 0, 0);
}

// swizzled LDS access for 256-byte-row tiles (128 bf16 cols)
DEVINL int swzb(int row, int col){ return row*256 + ((col*2) ^ ((row&7)<<4)); }
DEVINL void ldsw_write8(unsigned short* b, int row, int col, bf16x8 v){
  *(bf16x8*)((char*)b + swzb(row,col)) = v;
}
DEVINL bf16x8 ldsw_read8(const unsigned short* b, int row, int col){
  return *(const bf16x8*)((const char*)b + swzb(row,col));
}
DEVINL void ldsw_write1(unsigned short* b, int row, int col, unsigned short v){
  *(unsigned short*)((char*)b + swzb(row,col)) = v;
}
DEVINL unsigned short ldsw_read1(const unsigned short* b, int row, int col){
  return *(const unsigned short*)((const char*)b + swzb(row,col));
}

DEVINL unsigned long long pack4(float4 v){
  return (unsigned long long)f2bf(v.x)
       | ((unsigned long long)f2bf(v.y) << 16)
       | ((unsigned long long)f2bf(v.z) << 32)
       | ((unsigned long long)f2bf(v.w) << 48);
}

// ---------- fused f32 -> bf16 conversion of up to three buffers (32B/thread) ----------
__global__ __launch_bounds__(256) void k_conv3(
    const float* __restrict__ a, unsigned short* __restrict__ oa, int nba,
    const float* __restrict__ b, unsigned short* __restrict__ ob, int nbb,
    const float* __restrict__ c, unsigned short* __restrict__ oc)
{
  const float* in; unsigned short* out; long blk;
  if ((int)blockIdx.x < nba)            { in = a; out = oa; blk = blockIdx.x; }
  else if ((int)blockIdx.x < nba + nbb) { in = b; out = ob; blk = blockIdx.x - nba; }
  else                                  { in = c; out = oc; blk = blockIdx.x - nba - nbb; }
  long i = (blk * 256 + threadIdx.x) * 8;
  float4 v0 = *(const float4*)(in + i);
  float4 v1 = *(const float4*)(in + i + 4);
  unsigned long long pk[2] = { pack4(v0), pack4(v1) };
  *(bf16x8*)(out + i) = *(const bf16x8*)pk;
}

// ---------- bf16 GEMM, both operands K-major, C = A * Bt^T ----------
template<bool OUT_BF16, int BN>
__global__ __launch_bounds__(256) void k_gemm_bt(
    const unsigned short* __restrict__ A,
    const unsigned short* __restrict__ Bt,
    void* __restrict__ Cout,
    int K, int Nrows, int Npad, int xm, int tmx, int tnx)
{
  constexpr int NB = BN / 32;
  __shared__ unsigned short Asub[128*64];
  __shared__ unsigned short Bsub[BN*64];
  const int tid = threadIdx.x;
  const int x = blockIdx.x & 7, i = blockIdx.x >> 3;
  const int rt = (x % xm) * tmx + (i % tmx);
  const int ct = (x / xm) * tnx + (i / tmx);
  const int lane = tid & 63, wave = tid >> 6;
  const int wr = wave >> 1, wc = wave & 1;
  const int fr = lane & 15;
  const int fq = lane >> 4;

  const int srow0 = tid >> 3;
  const int sgrp  = (tid & 7) ^ ((tid >> 3) & 7);
  size_t aoff[4], boff[NB];
  #pragma unroll
  for (int j = 0; j < 4; j++){
    int row = j*32 + srow0;
    aoff[j] = (size_t)(rt*128 + row) * K + sgrp*8;
  }
  #pragma unroll
  for (int j = 0; j < NB; j++){
    int row = j*32 + srow0;
    int brow = ct*BN + row; if (brow > Nrows-1) brow = Nrows-1;
    boff[j] = (size_t)brow * K + sgrp*8;
  }

  f32x4 acc[4][NB] = {};

  for (int k0 = 0; k0 < K; k0 += 64){
    #pragma unroll
    for (int j = 0; j < 4; j++)
      g2l16(A + aoff[j] + k0, (char*)Asub + (j*256 + tid)*16);
    #pragma unroll
    for (int j = 0; j < NB; j++)
      g2l16(Bt + boff[j] + k0, (char*)Bsub + (j*256 + tid)*16);
    asm volatile("s_waitcnt vmcnt(0)" ::: "memory");
    __syncthreads();

    #pragma unroll
    for (int kk = 0; kk < 2; kk++){
      bf16x8 af[4], bfr[NB];
      const int slot = (kk*4 + fq) ^ (fr & 7);
      #pragma unroll
      for (int j = 0; j < 4; j++){
        int ra = wr*64 + j*16 + fr;
        af[j] = *(const bf16x8*)((const char*)Asub + ra*128 + slot*16);
      }
      #pragma unroll
      for (int j = 0; j < NB; j++){
        int rb = wc*(BN/2) + j*16 + fr;
        bfr[j] = *(const bf16x8*)((const char*)Bsub + rb*128 + slot*16);
      }
      #pragma unroll
      for (int mi = 0; mi < 4; mi++)
        #pragma unroll
        for (int ni = 0; ni < NB; ni++)
          acc[mi][ni] = __builtin_amdgcn_mfma_f32_16x16x32_bf16(af[mi], bfr[ni], acc[mi][ni], 0, 0, 0);
    }
    __syncthreads();
  }

  const int er = (lane >> 4) * 4;
  const int ec = lane & 15;
  #pragma unroll
  for (int mi = 0; mi < 4; mi++){
    #pragma unroll
    for (int ni = 0; ni < NB; ni++){
      const int row = rt*128 + wr*64 + mi*16 + er;
      const int col = ct*BN + wc*(BN/2) + ni*16 + ec;
      #pragma unroll
      for (int r = 0; r < 4; r++){
        if (OUT_BF16)
          ((unsigned short*)Cout)[(size_t)(row+r)*Npad + col] = f2bf(acc[mi][ni][r]);
        else
          ((float*)Cout)[(size_t)(row+r)*Npad + col] = acc[mi][ni][r];
      }
    }
  }
}

// ---------- GEMM2 split-K=2: 1024 blocks; half 0 -> out, half 1 -> part ----------
__global__ __launch_bounds__(256) void k_gemm2sk(
    const unsigned short* __restrict__ A,
    const unsigned short* __restrict__ Bt,
    float* __restrict__ out, float* __restrict__ part)
{
  constexpr int K = 4096, BN = 64, NB = 2;
  __shared__ unsigned short Asub[128*64];
  __shared__ unsigned short Bsub[BN*64];
  const int tid = threadIdx.x;
  const int half = (int)(blockIdx.x >> 9);
  const int bid  = (int)(blockIdx.x & 511);
  const int kbeg = half * 2048;
  float* dst = half ? part : out;
  const int x = bid & 7, i = bid >> 3;
  const int rt = (x % 4) * 4 + (i % 4);
  const int ct = (x / 4) * 16 + (i / 4);
  const int lane = tid & 63, wave = tid >> 6;
  const int wr = wave >> 1, wc = wave & 1;
  const int fr = lane & 15;
  const int fq = lane >> 4;

  const int srow0 = tid >> 3;
  const int sgrp  = (tid & 7) ^ ((tid >> 3) & 7);
  size_t aoff[4], boff[NB];
  #pragma unroll
  for (int j = 0; j < 4; j++){
    int row = j*32 + srow0;
    aoff[j] = (size_t)(rt*128 + row) * K + sgrp*8;
  }
  #pragma unroll
  for (int j = 0; j < NB; j++){
    int row = j*32 + srow0;
    boff[j] = (size_t)(ct*BN + row) * K + sgrp*8;
  }

  f32x4 acc[4][NB] = {};

  for (int k0 = kbeg; k0 < kbeg + 2048; k0 += 64){
    #pragma unroll
    for (int j = 0; j < 4; j++)
      g2l16(A + aoff[j] + k0, (char*)Asub + (j*256 + tid)*16);
    #pragma unroll
    for (int j = 0; j < NB; j++)
      g2l16(Bt + boff[j] + k0, (char*)Bsub + (j*256 + tid)*16);
    asm volatile("s_waitcnt vmcnt(0)" ::: "memory");
    __syncthreads();

    #pragma unroll
    for (int kk = 0; kk < 2; kk++){
      bf16x8 af[4], bfr[NB];
      const int slot = (kk*4 + fq) ^ (fr & 7);
      #pragma unroll
      for (int j = 0; j < 4; j++){
        int ra = wr*64 + j*16 + fr;
        af[j] = *(const bf16x8*)((const char*)Asub + ra*128 + slot*16);
      }
      #pragma unroll
      for (int j = 0; j < NB; j++){
        int rb = wc*(BN/2) + j*16 + fr;
        bfr[j] = *(const bf16x8*)((const char*)Bsub + rb*128 + slot*16);
      }
      #pragma unroll
      for (int mi = 0; mi < 4; mi++)
        #pragma unroll
        for (int ni = 0; ni < NB; ni++)
          acc[mi][ni] = __builtin_amdgcn_mfma_f32_16x16x32_bf16(af[mi], bfr[ni], acc[mi][ni], 0, 0, 0);
    }
    __syncthreads();
  }

  const int er = (lane >> 4) * 4;
  const int ec = lane & 15;
  #pragma unroll
  for (int mi = 0; mi < 4; mi++){
    #pragma unroll
    for (int ni = 0; ni < NB; ni++){
      const int row = rt*128 + wr*64 + mi*16 + er;
      const int col = ct*BN + wc*(BN/2) + ni*16 + ec;
      #pragma unroll
      for (int r = 0; r < 4; r++)
        dst[(size_t)(row+r)*2048 + col] = acc[mi][ni][r];
    }
  }
}

// ---------- out += part (float4) ----------
__global__ __launch_bounds__(256) void k_addout(
    float* __restrict__ out, const float* __restrict__ part)
{
  long i = ((long)blockIdx.x*256 + threadIdx.x) * 4;
  float4 a = *(const float4*)(out + i);
  float4 b = *(const float4*)(part + i);
  a.x += b.x; a.y += b.y; a.z += b.z; a.w += b.w;
  *(float4*)(out + i) = a;
}

// ---------- merged prep (512 threads): phase pipeline (blocks 0..127) + rmsnorm (128..639) ----------
__global__ __launch_bounds__(512) void k_prep(
    const unsigned short* __restrict__ proj, const float* __restrict__ Bw,
    const float* __restrict__ Cw, const float* __restrict__ dtb,
    unsigned short* __restrict__ Bb2, unsigned short* __restrict__ Cb2,
    float* __restrict__ DTt, float* __restrict__ lamt,
    float* __restrict__ clcb, float* __restrict__ gb,
    unsigned short* __restrict__ cosb, unsigned short* __restrict__ sinb)
{
  const int tid = threadIdx.x;
  __shared__ float dtL[1024], lamL[1024];
  __shared__ float part[16][32];
  __shared__ float red[16];

  if (blockIdx.x >= 128){
    int row = (int)(blockIdx.x - 128)*4 + (tid >> 7);
    int n = tid & 127;
    size_t base = (size_t)row * 8704;
    float bv = bf2f(proj[base + 8192 + n]);
    float cv = bf2f(proj[base + 8320 + n]);
    float sb = bv*bv, sc = cv*cv;
    #pragma unroll
    for (int m = 1; m < 64; m <<= 1){ sb += __shfl_xor(sb, m, 64); sc += __shfl_xor(sc, m, 64); }
    int w = tid >> 6;
    if ((tid & 63) == 0){ red[w*2] = sb; red[w*2+1] = sc; }
    __syncthreads();
    int rw = (tid >> 7) * 2;
    sb = red[rw*2]   + red[rw*2+2];
    sc = red[rw*2+1] + red[rw*2+3];
    float rb = rsqrtf(sb*(1.f/128.f) + 1e-5f);
    float rc = rsqrtf(sc*(1.f/128.f) + 1e-5f);
    Bb2[row*128 + n] = f2bf(bv*rb*Bw[n]);
    Cb2[row*128 + n] = f2bf(cv*rc*Cw[n]);
    return;
  }

  const int bh = blockIdx.x, b = bh >> 6, h = bh & 63;
  const size_t sbase = (size_t)bh * 1024;
  const int lane = tid & 63;
  float ld0, ld1;
  {
    int l0 = tid*2;
    #pragma unroll
    for (int q = 0; q < 2; q++){
      int l = l0 + q;
      size_t pb = (size_t)(b*1024 + l) * 8704;
      float dd_dt = bf2f(proj[pb + 8448 + h]);
      float dd_A  = bf2f(proj[pb + 8512 + h]);
      float trap  = bf2f(proj[pb + 8576 + h]);
      float DT  = softplusf(dd_dt + dtb[h]);
      float A   = -fmaxf(softplusf(dd_A), 1e-4f);
      float lam = 1.f / (1.f + expf(-trap));
      dtL[l] = DT; lamL[l] = lam;
      if (q == 0) ld0 = A*DT; else ld1 = A*DT;
      DTt[sbase+l] = DT; lamt[sbase+l] = lam;
    }
  }
  __syncthreads();
  {
    float p1 = ld0 + ld1;
    float tot = p1;
    float incl = tot;
    #pragma unroll
    for (int off = 1; off < 64; off <<= 1){
      float u = __shfl_up(incl, off, 64);
      if (lane >= off) incl += u;
    }
    float excl = incl - tot;
    int l0 = tid*2;
    clcb[sbase+l0]   = excl + ld0;
    clcb[sbase+l0+1] = excl + p1;
    #pragma unroll
    for (int q = 0; q < 2; q++){
      int l = l0 + q;
      int ln = (l == 1023) ? 1023 : l + 1;
      gb[sbase+l] = 1.f - lamL[l] + lamL[ln];
    }
  }
  int na = tid & 31, c = tid >> 5;
  float s = 0.f;
  for (int q = 0; q < 64; q++){
    int l = c*64 + q; int row = b*1024 + l;
    float ang = bf2f(proj[(size_t)row*8704 + 8640 + na]);
    s = fmaf(ang, dtL[l], s);
  }
  part[c][na] = s;
  __syncthreads();
  float off = 0.f;
  for (int cc = 0; cc < c; cc++) off += part[cc][na];
  float ph = off;
  for (int q = 0; q < 64; q++){
    int l = c*64 + q; int row = b*1024 + l;
    float ang = bf2f(proj[(size_t)row*8704 + 8640 + na]);
    ph = fmaf(ang, dtL[l], ph);
    float sn, cs;
    __sincosf(ph, &sn, &cs);
    size_t o = ((size_t)row*64 + h)*32 + na;
    cosb[o] = f2bf(cs); sinb[o] = f2bf(sn);
  }
}

// ---------- pass A: intra-chunk y + chunk state increment G (512 threads, 8 waves) ----------
__global__ __launch_bounds__(512, 1) void k_intra(
    const unsigned short* __restrict__ proj,
    const unsigned short* __restrict__ Bb2, const unsigned short* __restrict__ Cb2,
    const float* __restrict__ Bbias, const float* __restrict__ Cbias,
    const unsigned short* __restrict__ cosb, const unsigned short* __restrict__ sinb,
    const float* __restrict__ DTt, const float* __restrict__ clcb,
    const float* __restrict__ gb, const float* __restrict__ lamt,
    const float* __restrict__ Dv, unsigned short* __restrict__ ybf,
    unsigned short* __restrict__ Gbuf)
{
  const int c = blockIdx.x & 7, bh = blockIdx.x >> 3;
  const int b = bh >> 6, h = bh & 63;
  const int tid = threadIdx.x, lane = tid & 63, wave = tid >> 6;
  const int wr = wave >> 2, wc = wave & 3;
  const int fr = lane & 15, fq = lane >> 4;

  __shared__ __align__(16) unsigned short Cs[128*128];
  __shared__ __align__(16) unsigned short Bs[128*128];   // aliased as P after barrier
  __shared__ __align__(16) unsigned short BTs[128*128];
  __shared__ __align__(16) unsigned short Uts[64*128];   // U^T: [p][j]
  __shared__ float clcs[128], lams[128], gs[128], wUs[128], dts[128];
  __shared__ float biasB[128], biasC[128];

  const int base = b*1024 + c*128;
  const size_t shbase = (size_t)bh * 1024;
  const float Dh = Dv[h];

  // phase 0: scalars
  if (tid < 128){
    int l = c*128 + tid;
    clcs[tid] = clcb[shbase + l];
    dts[tid]  = DTt[shbase + l];
    lams[tid] = lamt[shbase + l];
    gs[tid]   = gb[shbase + l];
    biasB[tid] = Bbias[h*128 + tid];
  } else if (tid < 256){
    biasC[tid-128] = Cbias[h*128 + tid-128];
  }
  __syncthreads();
  if (tid < 128) wUs[tid] = __expf(clcs[127] - clcs[tid]) * gs[tid];

  // phase 1: stage C/B (bias+rope), B^T, U^T  — quarters per row t
  {
    const int t = tid >> 2, q = tid & 3;
    const int grow = base + t;
    const size_t roff = (size_t)grow*128;
    if (q == 0){
      bf16x8 cc[4], sv[4];
      #pragma unroll
      for (int j = 0; j < 4; j++){
        cc[j] = *(const bf16x8*)(cosb + ((size_t)grow*64 + h)*32 + j*8);
        sv[j] = *(const bf16x8*)(sinb + ((size_t)grow*64 + h)*32 + j*8);
      }
      #pragma unroll
      for (int j = 0; j < 4; j++){
        bf16x8 vlo = *(const bf16x8*)(Cb2 + roff + j*8);
        bf16x8 vhi = *(const bf16x8*)(Cb2 + roff + 32 + j*8);
        bf16x8 olo, ohi;
        #pragma unroll
        for (int e = 0; e < 8; e++){
          float a = bf2f((unsigned short)vlo[e]) + biasC[j*8+e];
          float d = bf2f((unsigned short)vhi[e]) + biasC[32+j*8+e];
          float cf = bf2f((unsigned short)cc[j][e]);
          float sf = bf2f((unsigned short)sv[j][e]);
          olo[e] = (short)f2bf(a*cf - d*sf);
          ohi[e] = (short)f2bf(a*sf + d*cf);
        }
        ldsw_write8(Cs, t, j*8, olo);
        ldsw_write8(Cs, t, 32 + j*8, ohi);
      }
    } else if (q == 1){
      #pragma unroll
      for (int j = 0; j < 8; j++){
        bf16x8 v = *(const bf16x8*)(Cb2 + roff + 64 + j*8);
        bf16x8 o;
        #pragma unroll
        for (int e = 0; e < 8; e++) o[e] = (short)f2bf(bf2f((unsigned short)v[e]) + biasC[64+j*8+e]);
        ldsw_write8(Cs, t, 64 + j*8, o);
      }
    } else if (q == 2){
      bf16x8 cc[4], sv[4];
      #pragma unroll
      for (int j = 0; j < 4; j++){
        cc[j] = *(const bf16x8*)(cosb + ((size_t)grow*64 + h)*32 + j*8);
        sv[j] = *(const bf16x8*)(sinb + ((size_t)grow*64 + h)*32 + j*8);
      }
      #pragma unroll
      for (int j = 0; j < 4; j++){
        bf16x8 vlo = *(const bf16x8*)(Bb2 + roff + j*8);
        bf16x8 vhi = *(const bf16x8*)(Bb2 + roff + 32 + j*8);
        bf16x8 olo, ohi;
        #pragma unroll
        for (int e = 0; e < 8; e++){
          float a = bf2f((unsigned short)vlo[e]) + biasB[j*8+e];
          float d = bf2f((unsigned short)vhi[e]) + biasB[32+j*8+e];
          float cf = bf2f((unsigned short)cc[j][e]);
          float sf = bf2f((unsigned short)sv[j][e]);
          olo[e] = (short)f2bf(a*cf - d*sf);
          ohi[e] = (short)f2bf(a*sf + d*cf);
        }
        ldsw_write8(Bs, t, j*8, olo);
        ldsw_write8(Bs, t, 32 + j*8, ohi);
        #pragma unroll
        for (int e = 0; e < 8; e++){
          ldsw_write1(BTs, j*8+e, t, (unsigned short)olo[e]);
          ldsw_write1(BTs, 32+j*8+e, t, (unsigned short)ohi[e]);
        }
      }
    } else {
      #pragma unroll
      for (int j = 0; j < 8; j++){
        bf16x8 v = *(const bf16x8*)(Bb2 + roff + 64 + j*8);
        bf16x8 o;
        #pragma unroll
        for (int e = 0; e < 8; e++) o[e] = (short)f2bf(bf2f((unsigned short)v[e]) + biasB[64+j*8+e]);
        ldsw_write8(Bs, t, 64 + j*8, o);
        #pragma unroll
        for (int e = 0; e < 8; e++) ldsw_write1(BTs, 64+j*8+e, t, (unsigned short)o[e]);
      }
    }
  }
  // U^T staging: vectorized — thread handles (j = q*64 + tid>>3, p0 = (tid&7)*8)
  {
    const int jr = tid >> 3;
    const int p0 = (tid & 7) * 8;
    #pragma unroll
    for (int q = 0; q < 2; q++){
      int j = q*64 + jr;
      size_t pb = (size_t)(base + j) * 8704;
      bf16x8 v = *(const bf16x8*)(proj + pb + 4096 + h*64 + p0);
      float dj = dts[j];
      #pragma unroll
      for (int e = 0; e < 8; e++)
        ldsw_write1(Uts, p0+e, j, f2bf(bf2f((unsigned short)v[e]) * dj));
    }
  }
  __syncthreads();

  // MFMA1: scores[t][j] = C . B^T   (per wave: 64 t x 32 j)
  f32x4 acc1[4][2];
  #pragma unroll
  for (int mi = 0; mi < 4; mi++)
    #pragma unroll
    for (int ni = 0; ni < 2; ni++)
      acc1[mi][ni] = (f32x4){0.f,0.f,0.f,0.f};
  #pragma unroll
  for (int ks = 0; ks < 4; ks++){
    bf16x8 af[4], bj[2];
    #pragma unroll
    for (int mi = 0; mi < 4; mi++) af[mi] = ldsw_read8(Cs, wr*64+mi*16+fr, ks*32+fq*8);
    #pragma unroll
    for (int ni = 0; ni < 2; ni++) bj[ni] = ldsw_read8(Bs, wc*32+ni*16+fr, ks*32+fq*8);
    #pragma unroll
    for (int mi = 0; mi < 4; mi++)
      #pragma unroll
      for (int ni = 0; ni < 2; ni++)
        acc1[mi][ni] = __builtin_amdgcn_mfma_f32_16x16x32_bf16(af[mi], bj[ni], acc1[mi][ni], 0,0,0);
  }
  // MFMA4 (hoisted before P barriers): G[p][n] = (wU o U) . B   (per wave: 32 p x 32 n)
  f32x4 accS[2][2];
  #pragma unroll
  for (int mi = 0; mi < 2; mi++)
    #pragma unroll
    for (int ni = 0; ni < 2; ni++)
      accS[mi][ni] = (f32x4){0.f,0.f,0.f,0.f};
  #pragma unroll
  for (int ks = 0; ks < 4; ks++){
    bf16x8 au[2], bn[2];
    #pragma unroll
    for (int mi = 0; mi < 2; mi++){
      bf16x8 raw = ldsw_read8(Uts, wr*32+mi*16+fr, ks*32+fq*8);
      #pragma unroll
      for (int e = 0; e < 8; e++){
        float f = bf2f((unsigned short)raw[e]) * wUs[ks*32+fq*8+e];
        au[mi][e] = (short)f2bf(f);
      }
    }
    #pragma unroll
    for (int ni = 0; ni < 2; ni++) bn[ni] = ldsw_read8(BTs, wc*32+ni*16+fr, ks*32+fq*8);
    #pragma unroll
    for (int mi = 0; mi < 2; mi++)
      #pragma unroll
      for (int ni = 0; ni < 2; ni++)
        accS[mi][ni] = __builtin_amdgcn_mfma_f32_16x16x32_bf16(au[mi], bn[ni], accS[mi][ni], 0,0,0);
  }
  // G store (drains during the barriers below)
  #pragma unroll
  for (int mi = 0; mi < 2; mi++)
    #pragma unroll
    for (int ni = 0; ni < 2; ni++)
      #pragma unroll
      for (int r = 0; r < 4; r++){
        int p = wr*32+mi*16+fq*4+r;
        int n = wc*32+ni*16+fr;
        Gbuf[(size_t)blockIdx.x*8192 + p*128 + n] = f2bf(accS[mi][ni][r]);
      }
  // weight epilogue: P = W o scores
  unsigned short pr[4][2][4];
  int jj[2]; float clcj[2], gj[2];
  #pragma unroll
  for (int ni = 0; ni < 2; ni++){ jj[ni] = wc*32+ni*16+fr; clcj[ni] = clcs[jj[ni]]; gj[ni] = gs[jj[ni]]; }
  #pragma unroll
  for (int mi = 0; mi < 4; mi++){
    #pragma unroll
    for (int r = 0; r < 4; r++){
      int t = wr*64+mi*16+fq*4+r;
      float ct_ = clcs[t], lt = lams[t];
      #pragma unroll
      for (int ni = 0; ni < 2; ni++){
        int j = jj[ni];
        float w = (j < t) ? __expf(ct_ - clcj[ni])*gj[ni] : ((j == t) ? (1.f - lt) : 0.f);
        pr[mi][ni][r] = f2bf(acc1[mi][ni][r] * w);
      }
    }
  }
  __syncthreads();                     // all MFMA1 reads of Bs complete
  #pragma unroll
  for (int mi = 0; mi < 4; mi++)
    #pragma unroll
    for (int ni = 0; ni < 2; ni++)
      #pragma unroll
      for (int r = 0; r < 4; r++)
        ldsw_write1(Bs, wr*64+mi*16+fq*4+r, wc*32+ni*16+fr, pr[mi][ni][r]);
  __syncthreads();

  // MFMA2: y_intra[t][p] = P . U   (per wave: 64 t x 16 p)
  f32x4 acc2[4];
  #pragma unroll
  for (int mi = 0; mi < 4; mi++) acc2[mi] = (f32x4){0.f,0.f,0.f,0.f};
  #pragma unroll
  for (int ks = 0; ks < 4; ks++){
    bf16x8 af[4], uj;
    #pragma unroll
    for (int mi = 0; mi < 4; mi++) af[mi] = ldsw_read8(Bs, wr*64+mi*16+fr, ks*32+fq*8);
    uj = ldsw_read8(Uts, wc*16+fr, ks*32+fq*8);
    #pragma unroll
    for (int mi = 0; mi < 4; mi++)
      acc2[mi] = __builtin_amdgcn_mfma_f32_16x16x32_bf16(af[mi], uj, acc2[mi], 0,0,0);
  }

  // stores: y_intra + D*x (ungated)
  #pragma unroll
  for (int mi = 0; mi < 4; mi++){
    #pragma unroll
    for (int r = 0; r < 4; r++){
      int t = wr*64+mi*16+fq*4+r;
      int p = wc*16+fr;
      float xv = bf2f(ldsw_read1(Uts, p, t)) / fmaxf(dts[t], 1e-30f);
      float o = acc2[mi][r] + Dh*xv;
      ybf[(size_t)(base + t)*4096 + h*64 + p] = f2bf(o);
    }
  }
}

// ---------- pass C: y = (y_intra + exp(clc_t) * C_t . S_prev^T) * silu(z) ----------
// S_prev computed in-block by scanning G[0..c-1] (read-only Gbuf; replaces k_scanstate).
// hybrid: blocks >= 1024 convert wo f32->bf16 (small-ws path)
__global__ __launch_bounds__(256) void k_inter(
    const unsigned short* __restrict__ proj,
    const unsigned short* __restrict__ Cb2, const float* __restrict__ Cbias,
    const unsigned short* __restrict__ cosb, const unsigned short* __restrict__ sinb,
    const float* __restrict__ clcb, const unsigned short* __restrict__ Gbuf,
    unsigned short* __restrict__ ybf,
    const float* __restrict__ wo, unsigned short* __restrict__ wobf)
{
  if (blockIdx.x >= 1024){
    long i = (((long)blockIdx.x - 1024) * 256 + threadIdx.x) * 4;
    float4 v = *(const float4*)(wo + i);
    *(unsigned long long*)(wobf + i) = pack4(v);
    return;
  }
  const int c = blockIdx.x & 7, bh = blockIdx.x >> 3;
  const int b = bh >> 6, h = bh & 63;
  const int tid = threadIdx.x, lane = tid & 63, wave = tid >> 6;
  const int wr = wave >> 1, wc = wave & 1;
  const int fr = lane & 15, fq = lane >> 4;

  __shared__ __align__(16) unsigned short Cs[128*128];
  __shared__ __align__(16) unsigned short Ss[64*128];
  __shared__ float expclcs[128], biasC[128];

  const int base = b*1024 + c*128;

  if (tid < 128){
    expclcs[tid] = __expf(clcb[(size_t)bh*1024 + c*128 + tid]);
    biasC[tid] = Cbias[h*128 + tid];
  }
  __syncthreads();

  // S_prev scan over chunks 0..c-1 (f32; same rounding as the old Gbuf round-trip)
  {
    float S[32];
    #pragma unroll
    for (int q = 0; q < 32; q++) S[q] = 0.f;
    for (int cc = 0; cc < c; cc++){
      float decEnd = __expf(clcb[(size_t)bh*1024 + cc*128 + 127]);
      const unsigned short* p = Gbuf + (size_t)(bh*8 + cc)*8192 + (size_t)tid*32;
      #pragma unroll
      for (int q = 0; q < 4; q++){
        bf16x8 g = *(const bf16x8*)(p + q*8);
        #pragma unroll
        for (int e = 0; e < 8; e++)
          S[q*8+e] = decEnd*S[q*8+e] + bf2f((unsigned short)g[e]);
      }
    }
    #pragma unroll
    for (int q = 0; q < 4; q++){
      bf16x8 v;
      #pragma unroll
      for (int e = 0; e < 8; e++) v[e] = (short)f2bf(S[q*8+e]);
      int f = tid*32 + q*8;
      ldsw_write8(Ss, f >> 7, f & 127, v);
    }
  }
  // stage C (bias+rope)
  {
    const int t = tid >> 1, half = tid & 1;
    const int grow = base + t;
    const size_t roff = (size_t)grow*128 + half*64;
    if (half == 0){
      bf16x8 cc[4], sv[4];
      #pragma unroll
      for (int j = 0; j < 4; j++){
        cc[j] = *(const bf16x8*)(cosb + ((size_t)grow*64 + h)*32 + j*8);
        sv[j] = *(const bf16x8*)(sinb + ((size_t)grow*64 + h)*32 + j*8);
      }
      #pragma unroll
      for (int j = 0; j < 4; j++){
        bf16x8 vlo = *(const bf16x8*)(Cb2 + roff + j*8);
        bf16x8 vhi = *(const bf16x8*)(Cb2 + roff + 32 + j*8);
        bf16x8 olo, ohi;
        #pragma unroll
        for (int e = 0; e < 8; e++){
          float a = bf2f((unsigned short)vlo[e]) + biasC[j*8+e];
          float d = bf2f((unsigned short)vhi[e]) + biasC[32+j*8+e];
          float cf = bf2f((unsigned short)cc[j][e]);
          float sf = bf2f((unsigned short)sv[j][e]);
          olo[e] = (short)f2bf(a*cf - d*sf);
          ohi[e] = (short)f2bf(a*sf + d*cf);
        }
        ldsw_write8(Cs, t, j*8, olo);
        ldsw_write8(Cs, t, 32 + j*8, ohi);
      }
    } else {
      #pragma unroll
      for (int j = 0; j < 8; j++){
        bf16x8 v = *(const bf16x8*)(Cb2 + roff + j*8);
        bf16x8 o;
        #pragma unroll
        for (int e = 0; e < 8; e++) o[e] = (short)f2bf(bf2f((unsigned short)v[e]) + biasC[64+j*8+e]);
        ldsw_write8(Cs, t, 64 + j*8, o);
      }
    }
  }
  __syncthreads();

  // MFMA: Yinter[t][p] = C . S_prev^T
  f32x4 acc[4][2];
  #pragma unroll
  for (int mi = 0; mi < 4; mi++)
    #pragma unroll
    for (int ni = 0; ni < 2; ni++)
      acc[mi][ni] = (f32x4){0.f,0.f,0.f,0.f};
  #pragma unroll
  for (int ks = 0; ks < 4; ks++){
    bf16x8 af[4], sj[2];
    #pragma unroll
    for (int mi = 0; mi < 4; mi++) af[mi] = ldsw_read8(Cs, wr*64+mi*16+fr, ks*32+fq*8);
    #pragma unroll
    for (int ni = 0; ni < 2; ni++) sj[ni] = ldsw_read8(Ss, wc*32+ni*16+fr, ks*32+fq*8);
    #pragma unroll
    for (int mi = 0; mi < 4; mi++)
      #pragma unroll
      for (int ni = 0; ni < 2; ni++)
        acc[mi][ni] = __builtin_amdgcn_mfma_f32_16x16x32_bf16(af[mi], sj[ni], acc[mi][ni], 0,0,0);
  }

  // epilogue: y = (y_intra + expclc*Yinter) * silu(z)
  #pragma unroll
  for (int mi = 0; mi < 4; mi++){
    #pragma unroll
    for (int ni = 0; ni < 2; ni++){
      #pragma unroll
      for (int r = 0; r < 4; r++){
        int t = wr*64+mi*16+fq*4+r;
        int p = wc*32+ni*16+fr;
        size_t yoff = (size_t)(base + t)*4096 + h*64 + p;
        float y = bf2f(ybf[yoff]) + expclcs[t]*acc[mi][ni][r];
        float zv = bf2f(proj[(size_t)(base + t)*8704 + h*64 + p]);
        float sl = zv / (1.f + __expf(-zv));
        ybf[yoff] = f2bf(y * sl);
      }
    }
  }
}

// ---------- launch ----------
extern "C" void kernel_launch(void* const* d_in, const int* in_sizes, int n_in,
                              void* d_out, int out_size, void* d_ws, size_t ws_size,
                              hipStream_t stream)
{
  const float* hs    = (const float*)d_in[0];
  const float* w1    = (const float*)d_in[1];
  const float* dtb   = (const float*)d_in[2];
  const float* Bbias = (const float*)d_in[3];
  const float* Cbias = (const float*)d_in[4];
  const float* Bw    = (const float*)d_in[5];
  const float* Cw    = (const float*)d_in[6];
  const float* Dv    = (const float*)d_in[7];
  const float* wo    = (const float*)d_in[8];
  float* out = (float*)d_out;
  char* ws = (char*)d_ws;

  unsigned short* projbf = (unsigned short*)(ws + 0UL);
  float* gemm2part       = (float*)(ws + 0UL);                    // post-k_inter (proj dead)
  unsigned short* W1bf   = (unsigned short*)(ws + 35651584UL);
  unsigned short* Gbuf   = W1bf;                                  // post-GEMM1
  unsigned short* ybf    = (unsigned short*)(ws + 52428800UL);
  unsigned short* hsbf   = (unsigned short*)(ws + 71172096UL);
  unsigned short* cosb   = hsbf;                                  // post-GEMM1
  unsigned short* sinb   = (unsigned short*)(ws + 79560704UL);
  float* DTt    = (float*)(ws + 87949312UL);
  float* lamt   = (float*)(ws + 88997888UL);
  float* clcb   = (float*)(ws + 89522176UL);
  float* gb     = (float*)(ws + 90046464UL);
  unsigned short* Bb2 = (unsigned short*)(ws + 90570752UL);
  unsigned short* Cb2 = (unsigned short*)(ws + 91095040UL);
  if (ws_size < 91619328UL) return;

  const bool bigws = (ws_size >= 91619328UL + 16777216UL);
  unsigned short* Wobf = bigws ? (unsigned short*)(ws + 91619328UL) : W1bf;

  (void)in_sizes; (void)n_in; (void)out_size;

  // conversions (2048 elems/block): w1 (8672) + hs (2048) [+ wo (4096) if bigws]
  k_conv3<<<bigws ? 14816 : 10720, 256, 0, stream>>>(
      w1, W1bf, 8672, hs, hsbf, 2048, wo, Wobf);
  // GEMM1: tiles 16x68 @128x128; XCD partition 2x4 -> per-XCD 8rt x 17ct
  k_gemm_bt<true, 128><<<1088, 256, 0, stream>>>(hsbf, W1bf, projbf, 2048, 8672, 8704, 2, 8, 17);
  // merged prep: 128 phase blocks + 512 rmsnorm blocks (512 threads)
  k_prep<<<640, 512, 0, stream>>>(projbf, Bw, Cw, dtb, Bb2, Cb2,
                                  DTt, lamt, clcb, gb, cosb, sinb);
  k_intra<<<1024, 512, 0, stream>>>(projbf, Bb2, Cb2, Bbias, Cbias,
                                    cosb, sinb, DTt, clcb, gb, lamt, Dv, ybf, Gbuf);
  // pass C (with in-block S_prev scan); small-ws path also converts wo in trailing blocks
  k_inter<<<bigws ? 1024 : 9216, 256, 0, stream>>>(
      projbf, Cb2, Cbias, cosb, sinb, clcb, Gbuf, ybf, wo, Wobf);
  // GEMM2 split-K=2: 1024 blocks (both halves co-resident), then out += partial
  k_gemm2sk<<<1024, 256, 0, stream>>>(ybf, Wobf, out, gemm2part);
  k_addout<<<4096, 256, 0, stream>>>(out, gemm2part);
}

// Round 16
// 296.497 us; speedup vs baseline: 1.1220x; 1.0066x over previous
//
#include <hip/hip_runtime.h>
#include <hip/hip_bf16.h>
#include <cstdint>
#include <cstddef>

#define DEVINL __device__ __forceinline__

typedef __attribute__((ext_vector_type(8))) short bf16x8;
typedef __attribute__((ext_vector_type(4))) float f32x4;

// ---------- helpers ----------
DEVINL float bf2f(unsigned short u){
  union { unsigned u32; float f; } cv; cv.u32 = ((unsigned)u) << 16; return cv.f;
}
DEVINL unsigned short f2bf(float f){
  union { float f; unsigned u32; } cv; cv.f = f;
  unsigned u = cv.u32;
  return (unsigned short)((u + 0x7FFFu + ((u >> 16) & 1u)) >> 16);  // RNE
}
DEVINL float softplusf(float x){ return x > 20.f ? x : log1pf(expf(x)); }

DEVINL void g2l16(const void* gptr, void* ldsptr){
  __builtin_amdgcn_global_load_lds(
      (const __attribute__((address_space(1))) unsigned int*)gptr,
      (__attribute__((address_space(3))) unsigned int*)(uintptr_t)ldsptr,
      16, 0, 0);
}

// swizzled LDS access for 256-byte-row tiles (128 bf16 cols)
DEVINL int swzb(int row, int col){ return row*256 + ((col*2) ^ ((row&7)<<4)); }
DEVINL void ldsw_write8(unsigned short* b, int row, int col, bf16x8 v){
  *(bf16x8*)((char*)b + swzb(row,col)) = v;
}
DEVINL bf16x8 ldsw_read8(const unsigned short* b, int row, int col){
  return *(const bf16x8*)((const char*)b + swzb(row,col));
}
DEVINL void ldsw_write1(unsigned short* b, int row, int col, unsigned short v){
  *(unsigned short*)((char*)b + swzb(row,col)) = v;
}
DEVINL unsigned short ldsw_read1(const unsigned short* b, int row, int col){
  return *(const unsigned short*)((const char*)b + swzb(row,col));
}

DEVINL unsigned long long pack4(float4 v){
  return (unsigned long long)f2bf(v.x)
       | ((unsigned long long)f2bf(v.y) << 16)
       | ((unsigned long long)f2bf(v.z) << 32)
       | ((unsigned long long)f2bf(v.w) << 48);
}

// ---------- fused f32 -> bf16 conversion of up to three buffers (32B/thread) ----------
__global__ __launch_bounds__(256) void k_conv3(
    const float* __restrict__ a, unsigned short* __restrict__ oa, int nba,
    const float* __restrict__ b, unsigned short* __restrict__ ob, int nbb,
    const float* __restrict__ c, unsigned short* __restrict__ oc)
{
  const float* in; unsigned short* out; long blk;
  if ((int)blockIdx.x < nba)            { in = a; out = oa; blk = blockIdx.x; }
  else if ((int)blockIdx.x < nba + nbb) { in = b; out = ob; blk = blockIdx.x - nba; }
  else                                  { in = c; out = oc; blk = blockIdx.x - nba - nbb; }
  long i = (blk * 256 + threadIdx.x) * 8;
  float4 v0 = *(const float4*)(in + i);
  float4 v1 = *(const float4*)(in + i + 4);
  unsigned long long pk[2] = { pack4(v0), pack4(v1) };
  *(bf16x8*)(out + i) = *(const bf16x8*)pk;
}

// ---------- bf16 GEMM, both operands K-major, C = A * Bt^T ----------
template<bool OUT_BF16, int BN>
__global__ __launch_bounds__(256) void k_gemm_bt(
    const unsigned short* __restrict__ A,
    const unsigned short* __restrict__ Bt,
    void* __restrict__ Cout,
    int K, int Nrows, int Npad, int xm, int tmx, int tnx)
{
  constexpr int NB = BN / 32;
  __shared__ unsigned short Asub[128*64];
  __shared__ unsigned short Bsub[BN*64];
  const int tid = threadIdx.x;
  const int x = blockIdx.x & 7, i = blockIdx.x >> 3;
  const int rt = (x % xm) * tmx + (i % tmx);
  const int ct = (x / xm) * tnx + (i / tmx);
  const int lane = tid & 63, wave = tid >> 6;
  const int wr = wave >> 1, wc = wave & 1;
  const int fr = lane & 15;
  const int fq = lane >> 4;

  const int srow0 = tid >> 3;
  const int sgrp  = (tid & 7) ^ ((tid >> 3) & 7);
  size_t aoff[4], boff[NB];
  #pragma unroll
  for (int j = 0; j < 4; j++){
    int row = j*32 + srow0;
    aoff[j] = (size_t)(rt*128 + row) * K + sgrp*8;
  }
  #pragma unroll
  for (int j = 0; j < NB; j++){
    int row = j*32 + srow0;
    int brow = ct*BN + row; if (brow > Nrows-1) brow = Nrows-1;
    boff[j] = (size_t)brow * K + sgrp*8;
  }

  f32x4 acc[4][NB] = {};

  for (int k0 = 0; k0 < K; k0 += 64){
    #pragma unroll
    for (int j = 0; j < 4; j++)
      g2l16(A + aoff[j] + k0, (char*)Asub + (j*256 + tid)*16);
    #pragma unroll
    for (int j = 0; j < NB; j++)
      g2l16(Bt + boff[j] + k0, (char*)Bsub + (j*256 + tid)*16);
    asm volatile("s_waitcnt vmcnt(0)" ::: "memory");
    __syncthreads();

    #pragma unroll
    for (int kk = 0; kk < 2; kk++){
      bf16x8 af[4], bfr[NB];
      const int slot = (kk*4 + fq) ^ (fr & 7);
      #pragma unroll
      for (int j = 0; j < 4; j++){
        int ra = wr*64 + j*16 + fr;
        af[j] = *(const bf16x8*)((const char*)Asub + ra*128 + slot*16);
      }
      #pragma unroll
      for (int j = 0; j < NB; j++){
        int rb = wc*(BN/2) + j*16 + fr;
        bfr[j] = *(const bf16x8*)((const char*)Bsub + rb*128 + slot*16);
      }
      #pragma unroll
      for (int mi = 0; mi < 4; mi++)
        #pragma unroll
        for (int ni = 0; ni < NB; ni++)
          acc[mi][ni] = __builtin_amdgcn_mfma_f32_16x16x32_bf16(af[mi], bfr[ni], acc[mi][ni], 0, 0, 0);
    }
    __syncthreads();
  }

  const int er = (lane >> 4) * 4;
  const int ec = lane & 15;
  #pragma unroll
  for (int mi = 0; mi < 4; mi++){
    #pragma unroll
    for (int ni = 0; ni < NB; ni++){
      const int row = rt*128 + wr*64 + mi*16 + er;
      const int col = ct*BN + wc*(BN/2) + ni*16 + ec;
      #pragma unroll
      for (int r = 0; r < 4; r++){
        if (OUT_BF16)
          ((unsigned short*)Cout)[(size_t)(row+r)*Npad + col] = f2bf(acc[mi][ni][r]);
        else
          ((float*)Cout)[(size_t)(row+r)*Npad + col] = acc[mi][ni][r];
      }
    }
  }
}

// ---------- GEMM2 split-K=2: 1024 blocks; half 0 -> out, half 1 -> part ----------
__global__ __launch_bounds__(256) void k_gemm2sk(
    const unsigned short* __restrict__ A,
    const unsigned short* __restrict__ Bt,
    float* __restrict__ out, float* __restrict__ part)
{
  constexpr int K = 4096, BN = 64, NB = 2;
  __shared__ unsigned short Asub[128*64];
  __shared__ unsigned short Bsub[BN*64];
  const int tid = threadIdx.x;
  const int half = (int)(blockIdx.x >> 9);
  const int bid  = (int)(blockIdx.x & 511);
  const int kbeg = half * 2048;
  float* dst = half ? part : out;
  const int x = bid & 7, i = bid >> 3;
  const int rt = (x % 4) * 4 + (i % 4);
  const int ct = (x / 4) * 16 + (i / 4);
  const int lane = tid & 63, wave = tid >> 6;
  const int wr = wave >> 1, wc = wave & 1;
  const int fr = lane & 15;
  const int fq = lane >> 4;

  const int srow0 = tid >> 3;
  const int sgrp  = (tid & 7) ^ ((tid >> 3) & 7);
  size_t aoff[4], boff[NB];
  #pragma unroll
  for (int j = 0; j < 4; j++){
    int row = j*32 + srow0;
    aoff[j] = (size_t)(rt*128 + row) * K + sgrp*8;
  }
  #pragma unroll
  for (int j = 0; j < NB; j++){
    int row = j*32 + srow0;
    boff[j] = (size_t)(ct*BN + row) * K + sgrp*8;
  }

  f32x4 acc[4][NB] = {};

  for (int k0 = kbeg; k0 < kbeg + 2048; k0 += 64){
    #pragma unroll
    for (int j = 0; j < 4; j++)
      g2l16(A + aoff[j] + k0, (char*)Asub + (j*256 + tid)*16);
    #pragma unroll
    for (int j = 0; j < NB; j++)
      g2l16(Bt + boff[j] + k0, (char*)Bsub + (j*256 + tid)*16);
    asm volatile("s_waitcnt vmcnt(0)" ::: "memory");
    __syncthreads();

    #pragma unroll
    for (int kk = 0; kk < 2; kk++){
      bf16x8 af[4], bfr[NB];
      const int slot = (kk*4 + fq) ^ (fr & 7);
      #pragma unroll
      for (int j = 0; j < 4; j++){
        int ra = wr*64 + j*16 + fr;
        af[j] = *(const bf16x8*)((const char*)Asub + ra*128 + slot*16);
      }
      #pragma unroll
      for (int j = 0; j < NB; j++){
        int rb = wc*(BN/2) + j*16 + fr;
        bfr[j] = *(const bf16x8*)((const char*)Bsub + rb*128 + slot*16);
      }
      #pragma unroll
      for (int mi = 0; mi < 4; mi++)
        #pragma unroll
        for (int ni = 0; ni < NB; ni++)
          acc[mi][ni] = __builtin_amdgcn_mfma_f32_16x16x32_bf16(af[mi], bfr[ni], acc[mi][ni], 0, 0, 0);
    }
    __syncthreads();
  }

  const int er = (lane >> 4) * 4;
  const int ec = lane & 15;
  #pragma unroll
  for (int mi = 0; mi < 4; mi++){
    #pragma unroll
    for (int ni = 0; ni < NB; ni++){
      const int row = rt*128 + wr*64 + mi*16 + er;
      const int col = ct*BN + wc*(BN/2) + ni*16 + ec;
      #pragma unroll
      for (int r = 0; r < 4; r++)
        dst[(size_t)(row+r)*2048 + col] = acc[mi][ni][r];
    }
  }
}

// ---------- out += part (float4) ----------
__global__ __launch_bounds__(256) void k_addout(
    float* __restrict__ out, const float* __restrict__ part)
{
  long i = ((long)blockIdx.x*256 + threadIdx.x) * 4;
  float4 a = *(const float4*)(out + i);
  float4 b = *(const float4*)(part + i);
  a.x += b.x; a.y += b.y; a.z += b.z; a.w += b.w;
  *(float4*)(out + i) = a;
}

// ---------- merged prep (512 threads): phase pipeline (blocks 0..127) + rmsnorm (128..639) ----------
__global__ __launch_bounds__(512) void k_prep(
    const unsigned short* __restrict__ proj, const float* __restrict__ Bw,
    const float* __restrict__ Cw, const float* __restrict__ dtb,
    unsigned short* __restrict__ Bb2, unsigned short* __restrict__ Cb2,
    float* __restrict__ DTt, float* __restrict__ lamt,
    float* __restrict__ clcb, float* __restrict__ gb,
    unsigned short* __restrict__ cosb, unsigned short* __restrict__ sinb)
{
  const int tid = threadIdx.x;
  __shared__ float dtL[1024], lamL[1024];
  __shared__ float part[16][32];
  __shared__ float red[16];

  if (blockIdx.x >= 128){
    int row = (int)(blockIdx.x - 128)*4 + (tid >> 7);
    int n = tid & 127;
    size_t base = (size_t)row * 8704;
    float bv = bf2f(proj[base + 8192 + n]);
    float cv = bf2f(proj[base + 8320 + n]);
    float sb = bv*bv, sc = cv*cv;
    #pragma unroll
    for (int m = 1; m < 64; m <<= 1){ sb += __shfl_xor(sb, m, 64); sc += __shfl_xor(sc, m, 64); }
    int w = tid >> 6;
    if ((tid & 63) == 0){ red[w*2] = sb; red[w*2+1] = sc; }
    __syncthreads();
    int rw = (tid >> 7) * 2;
    sb = red[rw*2]   + red[rw*2+2];
    sc = red[rw*2+1] + red[rw*2+3];
    float rb = rsqrtf(sb*(1.f/128.f) + 1e-5f);
    float rc = rsqrtf(sc*(1.f/128.f) + 1e-5f);
    Bb2[row*128 + n] = f2bf(bv*rb*Bw[n]);
    Cb2[row*128 + n] = f2bf(cv*rc*Cw[n]);
    return;
  }

  const int bh = blockIdx.x, b = bh >> 6, h = bh & 63;
  const size_t sbase = (size_t)bh * 1024;
  const int lane = tid & 63;
  float ld0, ld1;
  {
    int l0 = tid*2;
    #pragma unroll
    for (int q = 0; q < 2; q++){
      int l = l0 + q;
      size_t pb = (size_t)(b*1024 + l) * 8704;
      float dd_dt = bf2f(proj[pb + 8448 + h]);
      float dd_A  = bf2f(proj[pb + 8512 + h]);
      float trap  = bf2f(proj[pb + 8576 + h]);
      float DT  = softplusf(dd_dt + dtb[h]);
      float A   = -fmaxf(softplusf(dd_A), 1e-4f);
      float lam = 1.f / (1.f + expf(-trap));
      dtL[l] = DT; lamL[l] = lam;
      if (q == 0) ld0 = A*DT; else ld1 = A*DT;
      DTt[sbase+l] = DT; lamt[sbase+l] = lam;
    }
  }
  __syncthreads();
  {
    float p1 = ld0 + ld1;
    float tot = p1;
    float incl = tot;
    #pragma unroll
    for (int off = 1; off < 64; off <<= 1){
      float u = __shfl_up(incl, off, 64);
      if (lane >= off) incl += u;
    }
    float excl = incl - tot;
    int l0 = tid*2;
    clcb[sbase+l0]   = excl + ld0;
    clcb[sbase+l0+1] = excl + p1;
    #pragma unroll
    for (int q = 0; q < 2; q++){
      int l = l0 + q;
      int ln = (l == 1023) ? 1023 : l + 1;
      gb[sbase+l] = 1.f - lamL[l] + lamL[ln];
    }
  }
  int na = tid & 31, c = tid >> 5;
  float s = 0.f;
  for (int q = 0; q < 64; q++){
    int l = c*64 + q; int row = b*1024 + l;
    float ang = bf2f(proj[(size_t)row*8704 + 8640 + na]);
    s = fmaf(ang, dtL[l], s);
  }
  part[c][na] = s;
  __syncthreads();
  float off = 0.f;
  for (int cc = 0; cc < c; cc++) off += part[cc][na];
  float ph = off;
  for (int q = 0; q < 64; q++){
    int l = c*64 + q; int row = b*1024 + l;
    float ang = bf2f(proj[(size_t)row*8704 + 8640 + na]);
    ph = fmaf(ang, dtL[l], ph);
    float sn, cs;
    __sincosf(ph, &sn, &cs);
    size_t o = ((size_t)row*64 + h)*32 + na;
    cosb[o] = f2bf(cs); sinb[o] = f2bf(sn);
  }
}

// ---------- pass A: intra-chunk y + chunk state increment G (512 threads, 8 waves) ----------
// P in dedicated LDS (no Bs alias) -> one fewer barrier; rdts precomputed.
__global__ __launch_bounds__(512, 1) void k_intra(
    const unsigned short* __restrict__ proj,
    const unsigned short* __restrict__ Bb2, const unsigned short* __restrict__ Cb2,
    const float* __restrict__ Bbias, const float* __restrict__ Cbias,
    const unsigned short* __restrict__ cosb, const unsigned short* __restrict__ sinb,
    const float* __restrict__ DTt, const float* __restrict__ clcb,
    const float* __restrict__ gb, const float* __restrict__ lamt,
    const float* __restrict__ Dv, unsigned short* __restrict__ ybf,
    unsigned short* __restrict__ Gbuf)
{
  const int c = blockIdx.x & 7, bh = blockIdx.x >> 3;
  const int b = bh >> 6, h = bh & 63;
  const int tid = threadIdx.x, lane = tid & 63, wave = tid >> 6;
  const int wr = wave >> 2, wc = wave & 3;
  const int fr = lane & 15, fq = lane >> 4;

  __shared__ __align__(16) unsigned short Cs[128*128];
  __shared__ __align__(16) unsigned short Bs[128*128];
  __shared__ __align__(16) unsigned short BTs[128*128];
  __shared__ __align__(16) unsigned short Ps[128*128];   // dedicated P buffer
  __shared__ __align__(16) unsigned short Uts[64*128];   // U^T: [p][j]
  __shared__ float clcs[128], lams[128], gs[128], wUs[128], dts[128], rdts[128];
  __shared__ float biasB[128], biasC[128];

  const int base = b*1024 + c*128;
  const size_t shbase = (size_t)bh * 1024;
  const float Dh = Dv[h];

  // phase 0: scalars
  if (tid < 128){
    int l = c*128 + tid;
    float dtv = DTt[shbase + l];
    clcs[tid] = clcb[shbase + l];
    dts[tid]  = dtv;
    rdts[tid] = 1.f / fmaxf(dtv, 1e-30f);
    lams[tid] = lamt[shbase + l];
    gs[tid]   = gb[shbase + l];
    biasB[tid] = Bbias[h*128 + tid];
  } else if (tid < 256){
    biasC[tid-128] = Cbias[h*128 + tid-128];
  }
  __syncthreads();
  if (tid < 128) wUs[tid] = __expf(clcs[127] - clcs[tid]) * gs[tid];

  // phase 1: stage C/B (bias+rope), B^T, U^T  — quarters per row t
  {
    const int t = tid >> 2, q = tid & 3;
    const int grow = base + t;
    const size_t roff = (size_t)grow*128;
    if (q == 0){
      bf16x8 cc[4], sv[4];
      #pragma unroll
      for (int j = 0; j < 4; j++){
        cc[j] = *(const bf16x8*)(cosb + ((size_t)grow*64 + h)*32 + j*8);
        sv[j] = *(const bf16x8*)(sinb + ((size_t)grow*64 + h)*32 + j*8);
      }
      #pragma unroll
      for (int j = 0; j < 4; j++){
        bf16x8 vlo = *(const bf16x8*)(Cb2 + roff + j*8);
        bf16x8 vhi = *(const bf16x8*)(Cb2 + roff + 32 + j*8);
        bf16x8 olo, ohi;
        #pragma unroll
        for (int e = 0; e < 8; e++){
          float a = bf2f((unsigned short)vlo[e]) + biasC[j*8+e];
          float d = bf2f((unsigned short)vhi[e]) + biasC[32+j*8+e];
          float cf = bf2f((unsigned short)cc[j][e]);
          float sf = bf2f((unsigned short)sv[j][e]);
          olo[e] = (short)f2bf(a*cf - d*sf);
          ohi[e] = (short)f2bf(a*sf + d*cf);
        }
        ldsw_write8(Cs, t, j*8, olo);
        ldsw_write8(Cs, t, 32 + j*8, ohi);
      }
    } else if (q == 1){
      #pragma unroll
      for (int j = 0; j < 8; j++){
        bf16x8 v = *(const bf16x8*)(Cb2 + roff + 64 + j*8);
        bf16x8 o;
        #pragma unroll
        for (int e = 0; e < 8; e++) o[e] = (short)f2bf(bf2f((unsigned short)v[e]) + biasC[64+j*8+e]);
        ldsw_write8(Cs, t, 64 + j*8, o);
      }
    } else if (q == 2){
      bf16x8 cc[4], sv[4];
      #pragma unroll
      for (int j = 0; j < 4; j++){
        cc[j] = *(const bf16x8*)(cosb + ((size_t)grow*64 + h)*32 + j*8);
        sv[j] = *(const bf16x8*)(sinb + ((size_t)grow*64 + h)*32 + j*8);
      }
      #pragma unroll
      for (int j = 0; j < 4; j++){
        bf16x8 vlo = *(const bf16x8*)(Bb2 + roff + j*8);
        bf16x8 vhi = *(const bf16x8*)(Bb2 + roff + 32 + j*8);
        bf16x8 olo, ohi;
        #pragma unroll
        for (int e = 0; e < 8; e++){
          float a = bf2f((unsigned short)vlo[e]) + biasB[j*8+e];
          float d = bf2f((unsigned short)vhi[e]) + biasB[32+j*8+e];
          float cf = bf2f((unsigned short)cc[j][e]);
          float sf = bf2f((unsigned short)sv[j][e]);
          olo[e] = (short)f2bf(a*cf - d*sf);
          ohi[e] = (short)f2bf(a*sf + d*cf);
        }
        ldsw_write8(Bs, t, j*8, olo);
        ldsw_write8(Bs, t, 32 + j*8, ohi);
        #pragma unroll
        for (int e = 0; e < 8; e++){
          ldsw_write1(BTs, j*8+e, t, (unsigned short)olo[e]);
          ldsw_write1(BTs, 32+j*8+e, t, (unsigned short)ohi[e]);
        }
      }
    } else {
      #pragma unroll
      for (int j = 0; j < 8; j++){
        bf16x8 v = *(const bf16x8*)(Bb2 + roff + 64 + j*8);
        bf16x8 o;
        #pragma unroll
        for (int e = 0; e < 8; e++) o[e] = (short)f2bf(bf2f((unsigned short)v[e]) + biasB[64+j*8+e]);
        ldsw_write8(Bs, t, 64 + j*8, o);
        #pragma unroll
        for (int e = 0; e < 8; e++) ldsw_write1(BTs, 64+j*8+e, t, (unsigned short)o[e]);
      }
    }
  }
  // U^T staging: vectorized
  {
    const int jr = tid >> 3;
    const int p0 = (tid & 7) * 8;
    #pragma unroll
    for (int q = 0; q < 2; q++){
      int j = q*64 + jr;
      size_t pb = (size_t)(base + j) * 8704;
      bf16x8 v = *(const bf16x8*)(proj + pb + 4096 + h*64 + p0);
      float dj = dts[j];
      #pragma unroll
      for (int e = 0; e < 8; e++)
        ldsw_write1(Uts, p0+e, j, f2bf(bf2f((unsigned short)v[e]) * dj));
    }
  }
  __syncthreads();

  // MFMA1: scores[t][j] = C . B^T   (per wave: 64 t x 32 j)
  f32x4 acc1[4][2];
  #pragma unroll
  for (int mi = 0; mi < 4; mi++)
    #pragma unroll
    for (int ni = 0; ni < 2; ni++)
      acc1[mi][ni] = (f32x4){0.f,0.f,0.f,0.f};
  #pragma unroll
  for (int ks = 0; ks < 4; ks++){
    bf16x8 af[4], bj[2];
    #pragma unroll
    for (int mi = 0; mi < 4; mi++) af[mi] = ldsw_read8(Cs, wr*64+mi*16+fr, ks*32+fq*8);
    #pragma unroll
    for (int ni = 0; ni < 2; ni++) bj[ni] = ldsw_read8(Bs, wc*32+ni*16+fr, ks*32+fq*8);
    #pragma unroll
    for (int mi = 0; mi < 4; mi++)
      #pragma unroll
      for (int ni = 0; ni < 2; ni++)
        acc1[mi][ni] = __builtin_amdgcn_mfma_f32_16x16x32_bf16(af[mi], bj[ni], acc1[mi][ni], 0,0,0);
  }
  // MFMA4: G[p][n] = (wU o U) . B   (per wave: 32 p x 32 n)
  f32x4 accS[2][2];
  #pragma unroll
  for (int mi = 0; mi < 2; mi++)
    #pragma unroll
    for (int ni = 0; ni < 2; ni++)
      accS[mi][ni] = (f32x4){0.f,0.f,0.f,0.f};
  #pragma unroll
  for (int ks = 0; ks < 4; ks++){
    bf16x8 au[2], bn[2];
    #pragma unroll
    for (int mi = 0; mi < 2; mi++){
      bf16x8 raw = ldsw_read8(Uts, wr*32+mi*16+fr, ks*32+fq*8);
      #pragma unroll
      for (int e = 0; e < 8; e++){
        float f = bf2f((unsigned short)raw[e]) * wUs[ks*32+fq*8+e];
        au[mi][e] = (short)f2bf(f);
      }
    }
    #pragma unroll
    for (int ni = 0; ni < 2; ni++) bn[ni] = ldsw_read8(BTs, wc*32+ni*16+fr, ks*32+fq*8);
    #pragma unroll
    for (int mi = 0; mi < 2; mi++)
      #pragma unroll
      for (int ni = 0; ni < 2; ni++)
        accS[mi][ni] = __builtin_amdgcn_mfma_f32_16x16x32_bf16(au[mi], bn[ni], accS[mi][ni], 0,0,0);
  }
  // G store (drains during the barrier below)
  #pragma unroll
  for (int mi = 0; mi < 2; mi++)
    #pragma unroll
    for (int ni = 0; ni < 2; ni++)
      #pragma unroll
      for (int r = 0; r < 4; r++){
        int p = wr*32+mi*16+fq*4+r;
        int n = wc*32+ni*16+fr;
        Gbuf[(size_t)blockIdx.x*8192 + p*128 + n] = f2bf(accS[mi][ni][r]);
      }
  // weight epilogue: P = W o scores -> Ps (no barrier needed before write)
  {
    int jj[2]; float clcj[2], gj[2];
    #pragma unroll
    for (int ni = 0; ni < 2; ni++){ jj[ni] = wc*32+ni*16+fr; clcj[ni] = clcs[jj[ni]]; gj[ni] = gs[jj[ni]]; }
    #pragma unroll
    for (int mi = 0; mi < 4; mi++){
      #pragma unroll
      for (int r = 0; r < 4; r++){
        int t = wr*64+mi*16+fq*4+r;
        float ct_ = clcs[t], lt = lams[t];
        #pragma unroll
        for (int ni = 0; ni < 2; ni++){
          int j = jj[ni];
          float w = (j < t) ? __expf(ct_ - clcj[ni])*gj[ni] : ((j == t) ? (1.f - lt) : 0.f);
          ldsw_write1(Ps, t, j, f2bf(acc1[mi][ni][r] * w));
        }
      }
    }
  }
  __syncthreads();

  // MFMA2: y_intra[t][p] = P . U   (per wave: 64 t x 16 p)
  f32x4 acc2[4];
  #pragma unroll
  for (int mi = 0; mi < 4; mi++) acc2[mi] = (f32x4){0.f,0.f,0.f,0.f};
  #pragma unroll
  for (int ks = 0; ks < 4; ks++){
    bf16x8 af[4], uj;
    #pragma unroll
    for (int mi = 0; mi < 4; mi++) af[mi] = ldsw_read8(Ps, wr*64+mi*16+fr, ks*32+fq*8);
    uj = ldsw_read8(Uts, wc*16+fr, ks*32+fq*8);
    #pragma unroll
    for (int mi = 0; mi < 4; mi++)
      acc2[mi] = __builtin_amdgcn_mfma_f32_16x16x32_bf16(af[mi], uj, acc2[mi], 0,0,0);
  }

  // stores: y_intra + D*x (ungated)
  #pragma unroll
  for (int mi = 0; mi < 4; mi++){
    #pragma unroll
    for (int r = 0; r < 4; r++){
      int t = wr*64+mi*16+fq*4+r;
      int p = wc*16+fr;
      float xv = bf2f(ldsw_read1(Uts, p, t)) * rdts[t];
      float o = acc2[mi][r] + Dh*xv;
      ybf[(size_t)(base + t)*4096 + h*64 + p] = f2bf(o);
    }
  }
}

// ---------- pass C: y = (y_intra + exp(clc_t) * C_t . S_prev^T) * silu(z) ----------
// S_prev computed in-block by scanning G[0..c-1]; c==0 blocks skip the MFMA path.
// hybrid: blocks >= 1024 convert wo f32->bf16 (small-ws path)
__global__ __launch_bounds__(256) void k_inter(
    const unsigned short* __restrict__ proj,
    const unsigned short* __restrict__ Cb2, const float* __restrict__ Cbias,
    const unsigned short* __restrict__ cosb, const unsigned short* __restrict__ sinb,
    const float* __restrict__ clcb, const unsigned short* __restrict__ Gbuf,
    unsigned short* __restrict__ ybf,
    const float* __restrict__ wo, unsigned short* __restrict__ wobf)
{
  if (blockIdx.x >= 1024){
    long i = (((long)blockIdx.x - 1024) * 256 + threadIdx.x) * 4;
    float4 v = *(const float4*)(wo + i);
    *(unsigned long long*)(wobf + i) = pack4(v);
    return;
  }
  const int c = blockIdx.x & 7, bh = blockIdx.x >> 3;
  const int b = bh >> 6, h = bh & 63;
  const int tid = threadIdx.x, lane = tid & 63, wave = tid >> 6;
  const int wr = wave >> 1, wc = wave & 1;
  const int fr = lane & 15, fq = lane >> 4;

  __shared__ __align__(16) unsigned short Cs[128*128];
  __shared__ __align__(16) unsigned short Ss[64*128];
  __shared__ float expclcs[128], biasC[128];

  const int base = b*1024 + c*128;

  f32x4 acc[4][2];
  #pragma unroll
  for (int mi = 0; mi < 4; mi++)
    #pragma unroll
    for (int ni = 0; ni < 2; ni++)
      acc[mi][ni] = (f32x4){0.f,0.f,0.f,0.f};

  if (tid < 128){
    expclcs[tid] = __expf(clcb[(size_t)bh*1024 + c*128 + tid]);
    biasC[tid] = Cbias[h*128 + tid];
  }
  __syncthreads();

  if (c > 0){
    // S_prev scan over chunks 0..c-1 (f32; same rounding as the old Gbuf round-trip)
    {
      float S[32];
      #pragma unroll
      for (int q = 0; q < 32; q++) S[q] = 0.f;
      for (int cc = 0; cc < c; cc++){
        float decEnd = __expf(clcb[(size_t)bh*1024 + cc*128 + 127]);
        const unsigned short* p = Gbuf + (size_t)(bh*8 + cc)*8192 + (size_t)tid*32;
        #pragma unroll
        for (int q = 0; q < 4; q++){
          bf16x8 g = *(const bf16x8*)(p + q*8);
          #pragma unroll
          for (int e = 0; e < 8; e++)
            S[q*8+e] = decEnd*S[q*8+e] + bf2f((unsigned short)g[e]);
        }
      }
      #pragma unroll
      for (int q = 0; q < 4; q++){
        bf16x8 v;
        #pragma unroll
        for (int e = 0; e < 8; e++) v[e] = (short)f2bf(S[q*8+e]);
        int f = tid*32 + q*8;
        ldsw_write8(Ss, f >> 7, f & 127, v);
      }
    }
    // stage C (bias+rope)
    {
      const int t = tid >> 1, half = tid & 1;
      const int grow = base + t;
      const size_t roff = (size_t)grow*128 + half*64;
      if (half == 0){
        bf16x8 cc[4], sv[4];
        #pragma unroll
        for (int j = 0; j < 4; j++){
          cc[j] = *(const bf16x8*)(cosb + ((size_t)grow*64 + h)*32 + j*8);
          sv[j] = *(const bf16x8*)(sinb + ((size_t)grow*64 + h)*32 + j*8);
        }
        #pragma unroll
        for (int j = 0; j < 4; j++){
          bf16x8 vlo = *(const bf16x8*)(Cb2 + roff + j*8);
          bf16x8 vhi = *(const bf16x8*)(Cb2 + roff + 32 + j*8);
          bf16x8 olo, ohi;
          #pragma unroll
          for (int e = 0; e < 8; e++){
            float a = bf2f((unsigned short)vlo[e]) + biasC[j*8+e];
            float d = bf2f((unsigned short)vhi[e]) + biasC[32+j*8+e];
            float cf = bf2f((unsigned short)cc[j][e]);
            float sf = bf2f((unsigned short)sv[j][e]);
            olo[e] = (short)f2bf(a*cf - d*sf);
            ohi[e] = (short)f2bf(a*sf + d*cf);
          }
          ldsw_write8(Cs, t, j*8, olo);
          ldsw_write8(Cs, t, 32 + j*8, ohi);
        }
      } else {
        #pragma unroll
        for (int j = 0; j < 8; j++){
          bf16x8 v = *(const bf16x8*)(Cb2 + roff + j*8);
          bf16x8 o;
          #pragma unroll
          for (int e = 0; e < 8; e++) o[e] = (short)f2bf(bf2f((unsigned short)v[e]) + biasC[64+j*8+e]);
          ldsw_write8(Cs, t, 64 + j*8, o);
        }
      }
    }
    __syncthreads();

    // MFMA: Yinter[t][p] = C . S_prev^T
    #pragma unroll
    for (int ks = 0; ks < 4; ks++){
      bf16x8 af[4], sj[2];
      #pragma unroll
      for (int mi = 0; mi < 4; mi++) af[mi] = ldsw_read8(Cs, wr*64+mi*16+fr, ks*32+fq*8);
      #pragma unroll
      for (int ni = 0; ni < 2; ni++) sj[ni] = ldsw_read8(Ss, wc*32+ni*16+fr, ks*32+fq*8);
      #pragma unroll
      for (int mi = 0; mi < 4; mi++)
        #pragma unroll
        for (int ni = 0; ni < 2; ni++)
          acc[mi][ni] = __builtin_amdgcn_mfma_f32_16x16x32_bf16(af[mi], sj[ni], acc[mi][ni], 0,0,0);
    }
  }

  // epilogue: y = (y_intra + expclc*Yinter) * silu(z)
  #pragma unroll
  for (int mi = 0; mi < 4; mi++){
    #pragma unroll
    for (int ni = 0; ni < 2; ni++){
      #pragma unroll
      for (int r = 0; r < 4; r++){
        int t = wr*64+mi*16+fq*4+r;
        int p = wc*32+ni*16+fr;
        size_t yoff = (size_t)(base + t)*4096 + h*64 + p;
        float y = bf2f(ybf[yoff]) + expclcs[t]*acc[mi][ni][r];
        float zv = bf2f(proj[(size_t)(base + t)*8704 + h*64 + p]);
        float sl = zv / (1.f + __expf(-zv));
        ybf[yoff] = f2bf(y * sl);
      }
    }
  }
}

// ---------- launch ----------
extern "C" void kernel_launch(void* const* d_in, const int* in_sizes, int n_in,
                              void* d_out, int out_size, void* d_ws, size_t ws_size,
                              hipStream_t stream)
{
  const float* hs    = (const float*)d_in[0];
  const float* w1    = (const float*)d_in[1];
  const float* dtb   = (const float*)d_in[2];
  const float* Bbias = (const float*)d_in[3];
  const float* Cbias = (const float*)d_in[4];
  const float* Bw    = (const float*)d_in[5];
  const float* Cw    = (const float*)d_in[6];
  const float* Dv    = (const float*)d_in[7];
  const float* wo    = (const float*)d_in[8];
  float* out = (float*)d_out;
  char* ws = (char*)d_ws;

  unsigned short* projbf = (unsigned short*)(ws + 0UL);
  float* gemm2part       = (float*)(ws + 0UL);                    // post-k_inter (proj dead)
  unsigned short* W1bf   = (unsigned short*)(ws + 35651584UL);
  unsigned short* Gbuf   = W1bf;                                  // post-GEMM1
  unsigned short* ybf    = (unsigned short*)(ws + 52428800UL);
  unsigned short* hsbf   = (unsigned short*)(ws + 71172096UL);
  unsigned short* cosb   = hsbf;                                  // post-GEMM1
  unsigned short* sinb   = (unsigned short*)(ws + 79560704UL);
  float* DTt    = (float*)(ws + 87949312UL);
  float* lamt   = (float*)(ws + 88997888UL);
  float* clcb   = (float*)(ws + 89522176UL);
  float* gb     = (float*)(ws + 90046464UL);
  unsigned short* Bb2 = (unsigned short*)(ws + 90570752UL);
  unsigned short* Cb2 = (unsigned short*)(ws + 91095040UL);
  if (ws_size < 91619328UL) return;

  const bool bigws = (ws_size >= 91619328UL + 16777216UL);
  unsigned short* Wobf = bigws ? (unsigned short*)(ws + 91619328UL) : W1bf;

  (void)in_sizes; (void)n_in; (void)out_size;

  // conversions (2048 elems/block): w1 (8672) + hs (2048) [+ wo (4096) if bigws]
  k_conv3<<<bigws ? 14816 : 10720, 256, 0, stream>>>(
      w1, W1bf, 8672, hs, hsbf, 2048, wo, Wobf);
  // GEMM1: tiles 16x68 @128x128; XCD partition 2x4 -> per-XCD 8rt x 17ct
  k_gemm_bt<true, 128><<<1088, 256, 0, stream>>>(hsbf, W1bf, projbf, 2048, 8672, 8704, 2, 8, 17);
  // merged prep: 128 phase blocks + 512 rmsnorm blocks (512 threads)
  k_prep<<<640, 512, 0, stream>>>(projbf, Bw, Cw, dtb, Bb2, Cb2,
                                  DTt, lamt, clcb, gb, cosb, sinb);
  k_intra<<<1024, 512, 0, stream>>>(projbf, Bb2, Cb2, Bbias, Cbias,
                                    cosb, sinb, DTt, clcb, gb, lamt, Dv, ybf, Gbuf);
  // pass C (with in-block S_prev scan); small-ws path also converts wo in trailing blocks
  k_inter<<<bigws ? 1024 : 9216, 256, 0, stream>>>(
      projbf, Cb2, Cbias, cosb, sinb, clcb, Gbuf, ybf, wo, Wobf);
  // GEMM2 split-K=2: 1024 blocks (both halves co-resident), then out += partial
  k_gemm2sk<<<1024, 256, 0, stream>>>(ybf, Wobf, out, gemm2part);
  k_addout<<<4096, 256, 0, stream>>>(out, gemm2part);
}